// Round 4
// baseline (1100.560 us; speedup 1.0000x reference)
//
#include <hip/hip_runtime.h>
#include <math.h>

#define BB 8
#define NN 12800
#define FF 256
#define DDIM 128
#define NBINS 100
#define BSIZE 128
#define NROT 50
#define NIDS 199
#define PTS (BB*NN)            // 102400
#define PITCH_T ((size_t)102400)

// ---- workspace layout (bytes) ----
#define OFF_FHT  ((size_t)0)            // 104857600 : FH transposed fp32 [256][102400]
#define OFF_TT   ((size_t)104857600)    // 52428800  : T transposed bf16 [256][102400]
#define OFF_OUT0 ((size_t)157286400)    // 52428800  : out0 bf16 [102400][256]
#define OFF_DMB  ((size_t)209715200)    // 26214400  : dm bf16 [800][128][128]
#define OFF_WB   ((size_t)235929600)    // 786432    : 6 weights bf16 transposed [256][256]
#define OFF_NORM ((size_t)236716032)    // 409600
#define OFF_MF   ((size_t)237125632)    // 409600
#define OFF_BIN  ((size_t)237535232)    // 409600 (int)
#define OFF_FLAT ((size_t)237944832)    // 409600 (int)
#define OFF_MSKI ((size_t)238354432)    // 409600 (int)
#define OFF_HIST ((size_t)238764032)    // 636800 (int)
#define OFF_OFFS ((size_t)239400832)    // 636800 (int)
#define OFF_FLAG ((size_t)240037632)    // 64
#define OFF_CNT  ((size_t)240037696)    // 64
#define OFF_LIST ((size_t)240037760)    // 409600 (int)
#define HISTBYTES (8*100*199*4)

using short8  = __attribute__((ext_vector_type(8))) short;
using floatx4 = __attribute__((ext_vector_type(4))) float;

__device__ __forceinline__ ushort f2b(float f) {
    unsigned u = __float_as_uint(f);
    unsigned r = (u + 0x7FFFu + ((u >> 16) & 1u)) >> 16;
    return (ushort)r;
}

// ---------- mask dtype sniffing ----------
__global__ void k_maskflag(const int* mi, int* flag) {
    __shared__ int notInt, notFloat;
    if (threadIdx.x == 0) { notInt = 0; notFloat = 0; }
    __syncthreads();
    int v = mi[threadIdx.x];
    if (v != 0 && v != 1) atomicOr(&notInt, 1);
    if (v != 0 && v != 0x3F800000) atomicOr(&notFloat, 1);
    __syncthreads();
    if (threadIdx.x == 0) flag[0] = (!notInt) ? 0 : ((!notFloat) ? 2 : 1);
}

__global__ void k_masknorm(const void* msk, const int* flag, int* mski) {
    int i = blockIdx.x * blockDim.x + threadIdx.x;
    if (i >= PTS) return;
    int f = flag[0];
    int v;
    if (f == 0)      v = ((const int*)msk)[i] != 0;
    else if (f == 2) v = ((const float*)msk)[i] != 0.0f;
    else             v = ((const unsigned char*)msk)[i] != 0;
    mski[i] = v;
}

// ---------- weight prep: fp32 [k][n] -> bf16 transposed [n][k] ----------
__global__ __launch_bounds__(256) void k_wprep(
    const float* s0, const float* s1, const float* s2,
    const float* s3, const float* s4, const float* s5,
    ushort* d0, ushort* d1, ushort* d2, ushort* d3, ushort* d4, ushort* d5)
{
    __shared__ float Ls[64 * 65];
    const float* src; ushort* dst;
    switch (blockIdx.y) {
        case 0: src = s0; dst = d0; break;
        case 1: src = s1; dst = d1; break;
        case 2: src = s2; dst = d2; break;
        case 3: src = s3; dst = d3; break;
        case 4: src = s4; dst = d4; break;
        default: src = s5; dst = d5; break;
    }
    int t = blockIdx.x;
    int kb = (t & 3) * 64, nb = (t >> 2) * 64;
    int tid = threadIdx.x;
    for (int q = 0; q < 4; ++q) {
        int g = q * 256 + tid;
        int kl = g >> 4, f4 = g & 15;
        float4 v = *(const float4*)(src + (size_t)(kb + kl) * 256 + nb + f4 * 4);
        Ls[kl * 65 + f4 * 4 + 0] = v.x;
        Ls[kl * 65 + f4 * 4 + 1] = v.y;
        Ls[kl * 65 + f4 * 4 + 2] = v.z;
        Ls[kl * 65 + f4 * 4 + 3] = v.w;
    }
    __syncthreads();
    for (int q = 0; q < 2; ++q) {
        int g = q * 256 + tid;
        int nl = g >> 3, wg = g & 7;
        ushort o[8];
        #pragma unroll
        for (int c = 0; c < 8; ++c) o[c] = f2b(Ls[(wg * 8 + c) * 65 + nl]);
        uint4 ou;
        ou.x = (unsigned)o[0] | ((unsigned)o[1] << 16);
        ou.y = (unsigned)o[2] | ((unsigned)o[3] << 16);
        ou.z = (unsigned)o[4] | ((unsigned)o[5] << 16);
        ou.w = (unsigned)o[6] | ((unsigned)o[7] << 16);
        *(uint4*)(dst + (size_t)(nb + nl) * 256 + kb + wg * 8) = ou;
    }
}

// ---------- stage 1 v2 (fp32, LDS-staged weights): LN + FFN + rot + argmax ----------
__device__ __forceinline__ void s1_stage(const float* __restrict__ src, int nfloats,
                                         float* __restrict__ dst, int tid) {
    for (int i = tid * 4; i < nfloats; i += 256 * 4) {
        float4 v = *(const float4*)(src + i);
        *(float4*)(dst + i) = v;
    }
}

__global__ __launch_bounds__(256) void k_stage1(
    const float* __restrict__ x, const float* __restrict__ g, const float* __restrict__ be,
    const float* __restrict__ w1, const float* __restrict__ b1,
    const float* __restrict__ w2, const float* __restrict__ b2,
    const float* __restrict__ rot, const int* __restrict__ mski,
    ushort* __restrict__ xn_out, float* __restrict__ xd_out, int* __restrict__ bin_out,
    int* __restrict__ fixlist, int* __restrict__ fixcnt)
{
    __shared__ float xs[16][257];      // xn, later xd  (odd pitch -> bank-clean)
    __shared__ float hs[16][129];
    __shared__ float4 wbuf4[2][1024];  // 2 x 16KB weight slab ping-pong
    float* wb0 = (float*)wbuf4[0];
    float* wb1 = (float*)wbuf4[1];
    int tid = threadIdx.x;
    int base = blockIdx.x * 16;

    // prologue: stage w1 slab 0 into buf0 (overlaps with LN)
    s1_stage(w1, 4096, wb0, tid);

    {   // phase 0: load + layernorm (16 threads per point, float4 loads)
        int pl = tid >> 4, t = tid & 15;
        int pt = base + pl;
        const float* xr = x + (size_t)pt * FF;
        float v[16];
        float s = 0.f;
        #pragma unroll
        for (int q = 0; q < 4; q++) {
            float4 f = *(const float4*)(xr + t * 4 + q * 64);
            v[q * 4 + 0] = f.x; v[q * 4 + 1] = f.y;
            v[q * 4 + 2] = f.z; v[q * 4 + 3] = f.w;
            s += f.x + f.y + f.z + f.w;
        }
        #pragma unroll
        for (int off = 1; off < 16; off <<= 1) s += __shfl_xor(s, off, 16);
        float mu = s * (1.f / 256.f);
        float s2 = 0.f;
        #pragma unroll
        for (int q = 0; q < 16; q++) { float d = v[q] - mu; s2 += d * d; }
        #pragma unroll
        for (int off = 1; off < 16; off <<= 1) s2 += __shfl_xor(s2, off, 16);
        float rs = 1.0f / sqrtf(s2 * (1.f / 256.f) + 1e-6f);
        ushort* xo = xn_out + (size_t)pt * FF;
        #pragma unroll
        for (int q = 0; q < 4; q++) {
            int i0 = t * 4 + q * 64;
            float4 gv = *(const float4*)(g + i0);
            float4 bv = *(const float4*)(be + i0);
            float xv0 = (v[q*4+0] - mu) * rs * gv.x + bv.x;
            float xv1 = (v[q*4+1] - mu) * rs * gv.y + bv.y;
            float xv2 = (v[q*4+2] - mu) * rs * gv.z + bv.z;
            float xv3 = (v[q*4+3] - mu) * rs * gv.w + bv.w;
            xs[pl][i0 + 0] = xv0; xs[pl][i0 + 1] = xv1;
            xs[pl][i0 + 2] = xv2; xs[pl][i0 + 3] = xv3;
            ushort4 ov = { f2b(xv0), f2b(xv1), f2b(xv2), f2b(xv3) };
            *(ushort4*)(xo + i0) = ov;
        }
    }
    __syncthreads();

    int pl2 = tid & 7;            // points pl2, pl2+8
    int c0  = (tid >> 3) * 4;     // 4 cols
    {   // phase 1: h = elu(xn @ w1 + b1), 8 slabs of 32 k
        float4 b1v = *(const float4*)(b1 + c0);
        float a00 = b1v.x, a01 = b1v.y, a02 = b1v.z, a03 = b1v.w;
        float a10 = b1v.x, a11 = b1v.y, a12 = b1v.z, a13 = b1v.w;
        for (int s = 0; s < 8; ++s) {
            const float* src = (s < 7) ? (w1 + (size_t)(s + 1) * 4096) : w2;
            s1_stage(src, 4096, ((s + 1) & 1) ? wb1 : wb0, tid);
            const float* wb = (s & 1) ? wb1 : wb0;
            int k0 = s * 32;
            #pragma unroll 8
            for (int kk = 0; kk < 32; ++kk) {
                float p0 = xs[pl2][k0 + kk];
                float p1 = xs[pl2 + 8][k0 + kk];
                float4 w = *(const float4*)(wb + kk * 128 + c0);
                a00 = fmaf(p0, w.x, a00); a01 = fmaf(p0, w.y, a01);
                a02 = fmaf(p0, w.z, a02); a03 = fmaf(p0, w.w, a03);
                a10 = fmaf(p1, w.x, a10); a11 = fmaf(p1, w.y, a11);
                a12 = fmaf(p1, w.z, a12); a13 = fmaf(p1, w.w, a13);
            }
            __syncthreads();
        }
        hs[pl2][c0 + 0]     = (a00 > 0.f) ? a00 : expm1f(a00);
        hs[pl2][c0 + 1]     = (a01 > 0.f) ? a01 : expm1f(a01);
        hs[pl2][c0 + 2]     = (a02 > 0.f) ? a02 : expm1f(a02);
        hs[pl2][c0 + 3]     = (a03 > 0.f) ? a03 : expm1f(a03);
        hs[pl2 + 8][c0 + 0] = (a10 > 0.f) ? a10 : expm1f(a10);
        hs[pl2 + 8][c0 + 1] = (a11 > 0.f) ? a11 : expm1f(a11);
        hs[pl2 + 8][c0 + 2] = (a12 > 0.f) ? a12 : expm1f(a12);
        hs[pl2 + 8][c0 + 3] = (a13 > 0.f) ? a13 : expm1f(a13);
    }
    __syncthreads();

    {   // phase 2: xd = h @ w2 + b2, 4 slabs of 32 k
        float4 b2v = *(const float4*)(b2 + c0);
        float a00 = b2v.x, a01 = b2v.y, a02 = b2v.z, a03 = b2v.w;
        float a10 = b2v.x, a11 = b2v.y, a12 = b2v.z, a13 = b2v.w;
        for (int s = 0; s < 4; ++s) {
            const float* src = (s < 3) ? (w2 + (size_t)(s + 1) * 4096) : rot;
            int n = (s < 3) ? 4096 : 3200;
            s1_stage(src, n, ((s + 1) & 1) ? wb1 : wb0, tid);
            const float* wb = (s & 1) ? wb1 : wb0;
            int k0 = s * 32;
            #pragma unroll 8
            for (int kk = 0; kk < 32; ++kk) {
                float p0 = hs[pl2][k0 + kk];
                float p1 = hs[pl2 + 8][k0 + kk];
                float4 w = *(const float4*)(wb + kk * 128 + c0);
                a00 = fmaf(p0, w.x, a00); a01 = fmaf(p0, w.y, a01);
                a02 = fmaf(p0, w.z, a02); a03 = fmaf(p0, w.w, a03);
                a10 = fmaf(p1, w.x, a10); a11 = fmaf(p1, w.y, a11);
                a12 = fmaf(p1, w.z, a12); a13 = fmaf(p1, w.w, a13);
            }
            __syncthreads();
        }
        // write xd into xs (reuse) + global
        xs[pl2][c0 + 0] = a00; xs[pl2][c0 + 1] = a01;
        xs[pl2][c0 + 2] = a02; xs[pl2][c0 + 3] = a03;
        xs[pl2 + 8][c0 + 0] = a10; xs[pl2 + 8][c0 + 1] = a11;
        xs[pl2 + 8][c0 + 2] = a12; xs[pl2 + 8][c0 + 3] = a13;
        float4 o0 = { a00, a01, a02, a03 };
        float4 o1 = { a10, a11, a12, a13 };
        *(float4*)(xd_out + (size_t)(base + pl2) * DDIM + c0) = o0;
        *(float4*)(xd_out + (size_t)(base + pl2 + 8) * DDIM + c0) = o1;
    }
    __syncthreads();

    {   // phase 3: mul = xd @ rot[:, :50]; top-2 argmax; 4 slabs of 32 k
        int wv = tid >> 6, c = tid & 63;
        float mm[4] = { 0.f, 0.f, 0.f, 0.f };
        for (int s = 0; s < 4; ++s) {
            if (s < 3) s1_stage(rot + (size_t)(s + 1) * 3200, 3200,
                                ((s + 1) & 1) ? wb1 : wb0, tid);
            const float* rb = (s & 1) ? wb1 : wb0;
            int k0 = s * 32;
            if (c < NROT) {
                #pragma unroll
                for (int r = 0; r < 4; ++r) {
                    float acc = 0.f;
                    #pragma unroll 8
                    for (int kk = 0; kk < 32; ++kk)
                        acc = fmaf(xs[wv * 4 + r][k0 + kk], rb[kk * 100 + c], acc);
                    mm[r] += acc;
                }
            }
            __syncthreads();
        }
        for (int r = 0; r < 4; ++r) {
            int p = wv * 4 + r;
            float v1, v2 = -1e30f; int i1;
            float m = mm[r];
            if (c < NROT) {
                if (m >= 0.f) { v1 = m; i1 = c; } else { v1 = -m; i1 = 50 + c; }
            } else { v1 = -1e30f; i1 = 1 << 29; }
            #pragma unroll
            for (int off = 1; off < 64; off <<= 1) {
                float o1 = __shfl_xor(v1, off, 64);
                int   oi = __shfl_xor(i1, off, 64);
                float o2 = __shfl_xor(v2, off, 64);
                bool take = (o1 > v1) || (o1 == v1 && oi < i1);
                float loser = take ? v1 : o1;
                if (take) { v1 = o1; i1 = oi; }
                v2 = fmaxf(fmaxf(v2, o2), loser);
            }
            if (c == 0) {
                int pt = base + p;
                bin_out[pt] = i1 + (mski[pt] ? 0 : (NBINS - 1));
                float tau = 2e-4f + 1e-3f * v1;
                if (v1 - v2 < tau) {
                    int pos = atomicAdd(fixcnt, 1);
                    fixlist[pos] = pt;
                }
            }
        }
    }
}

// ---------- fp64 fixup for margin-flagged points (one wave per point) ----------
__global__ __launch_bounds__(64) void k_fixup(
    const float* __restrict__ x, const float* __restrict__ g, const float* __restrict__ be,
    const float* __restrict__ w1, const float* __restrict__ b1,
    const float* __restrict__ w2, const float* __restrict__ b2,
    const float* __restrict__ rot, const int* __restrict__ mski,
    const int* __restrict__ fixlist, const int* __restrict__ fixcnt,
    int* __restrict__ bin_out)
{
    __shared__ double xn_s[256];
    __shared__ double h_s[128];
    __shared__ double xd_s[128];
    int lane = threadIdx.x;
    int n = fixcnt[0];
    for (int e = blockIdx.x; e < n; e += gridDim.x) {
        int pt = fixlist[e];
        const float* xr = x + (size_t)pt * FF;
        double s = 0.0, xv[4];
        #pragma unroll
        for (int q = 0; q < 4; q++) { xv[q] = (double)xr[lane + q * 64]; s += xv[q]; }
        #pragma unroll
        for (int off = 1; off < 64; off <<= 1) s += __shfl_xor(s, off, 64);
        double mu = s * (1.0 / 256.0);
        double s2 = 0.0;
        #pragma unroll
        for (int q = 0; q < 4; q++) { double d = xv[q] - mu; s2 += d * d; }
        #pragma unroll
        for (int off = 1; off < 64; off <<= 1) s2 += __shfl_xor(s2, off, 64);
        double rs = 1.0 / sqrt(s2 * (1.0 / 256.0) + 1e-6);
        #pragma unroll
        for (int q = 0; q < 4; q++) {
            int i = lane + q * 64;
            xn_s[i] = (xv[q] - mu) * rs * (double)g[i] + (double)be[i];
        }
        __syncthreads();
        #pragma unroll
        for (int q = 0; q < 2; q++) {
            int j = lane + q * 64;
            double a = (double)b1[j];
            for (int k = 0; k < FF; k++) a += xn_s[k] * (double)w1[k * DDIM + j];
            h_s[j] = (a > 0.0) ? a : expm1(a);
        }
        __syncthreads();
        #pragma unroll
        for (int q = 0; q < 2; q++) {
            int j = lane + q * 64;
            double a = (double)b2[j];
            for (int k = 0; k < DDIM; k++) a += h_s[k] * (double)w2[k * DDIM + j];
            xd_s[j] = a;
        }
        __syncthreads();
        double v; int idx;
        if (lane < NROT) {
            double m = 0.0;
            for (int k = 0; k < DDIM; k++) m += xd_s[k] * (double)rot[k * 100 + lane];
            if (m >= 0.0) { v = m; idx = lane; } else { v = -m; idx = 50 + lane; }
        } else { v = -1e300; idx = 1 << 29; }
        #pragma unroll
        for (int off = 1; off < 64; off <<= 1) {
            double ov = __shfl_xor(v, off, 64);
            int oi = __shfl_xor(idx, off, 64);
            if (ov > v || (ov == v && oi < idx)) { v = ov; idx = oi; }
        }
        if (lane == 0) bin_out[pt] = idx + (mski[pt] ? 0 : (NBINS - 1));
        __syncthreads();
    }
}

// ---------- binning: stable counting sort ----------
__global__ void k_count(const int* __restrict__ bin, int* __restrict__ hist) {
    int c = blockIdx.x % 100, b = blockIdx.x / 100;
    int t = threadIdx.x;
    int v = bin[b * NN + c * BSIZE + t];
    atomicAdd(&hist[(b * 100 + c) * NIDS + v], 1);
}

__global__ void k_offsets(const int* __restrict__ hist, int* __restrict__ offs) {
    __shared__ int tot[NIDS];
    __shared__ int start[NIDS];
    int b = blockIdx.x, v = threadIdx.x;
    if (v < NIDS) {
        int s = 0;
        for (int c = 0; c < 100; c++) s += hist[(b * 100 + c) * NIDS + v];
        tot[v] = s;
    }
    __syncthreads();
    if (threadIdx.x == 0) {
        int run = 0;
        for (int i = 0; i < NIDS; i++) { start[i] = run; run += tot[i]; }
    }
    __syncthreads();
    if (v < NIDS) {
        int run = start[v];
        for (int c = 0; c < 100; c++) {
            offs[(b * 100 + c) * NIDS + v] = run;
            run += hist[(b * 100 + c) * NIDS + v];
        }
    }
}

__global__ void k_scatter(const int* __restrict__ bin, const int* __restrict__ offs,
                          const int* __restrict__ mski, int* __restrict__ flat,
                          float* __restrict__ mf) {
    __shared__ int sv[BSIZE];
    int c = blockIdx.x % 100, b = blockIdx.x / 100;
    int t = threadIdx.x;
    int n = c * BSIZE + t;
    int v = bin[b * NN + n];
    sv[t] = v;
    __syncthreads();
    int rank = 0;
    for (int u = 0; u < t; u++) rank += (sv[u] == v);
    int r = offs[(b * 100 + c) * NIDS + v] + rank;
    flat[b * NN + r] = b * NN + n;
    mf[b * NN + r] = mski[b * NN + n] ? 1.0f : 0.0f;
}

// ---------- per-bin pairwise kernel matrix (fp32 tiled), fused deg/norm ----------
__global__ __launch_bounds__(256) void k_dm(const float* __restrict__ xd, const int* __restrict__ flat,
                                            const float* __restrict__ mf, ushort* __restrict__ dmb,
                                            float* __restrict__ norm) {
    __shared__ float Xs[128 * 64];
    __shared__ float na[128];
    __shared__ float ml[128];
    __shared__ float ps[128 * 16];
    int g = blockIdx.x, tid = threadIdx.x;
    int tx = tid & 15, ty = tid >> 4;
    int rowbase = g * 128;
    if (tid < 128) ml[tid] = mf[rowbase + tid];
    float acc[8][8];
    #pragma unroll
    for (int i = 0; i < 8; i++)
        #pragma unroll
        for (int j = 0; j < 8; j++) acc[i][j] = 0.f;
    float nap[8];
    #pragma unroll
    for (int j = 0; j < 8; j++) nap[j] = 0.f;

    for (int kh = 0; kh < 2; ++kh) {
        __syncthreads();
        for (int q = 0; q < 8; ++q) {
            int gg = q * 256 + tid;
            int row = gg >> 4, f4 = gg & 15;
            int srow = flat[rowbase + row];
            float4 v = *(const float4*)(xd + (size_t)srow * DDIM + kh * 64 + f4 * 4);
            int f4s = f4 ^ ((row >> 3) & 7);
            *(float4*)(Xs + row * 64 + f4s * 4) = v;
        }
        __syncthreads();
        for (int k4 = 0; k4 < 16; ++k4) {
            int sa = (k4 ^ (ty & 7)) << 2;
            int sb = (k4 ^ (tx & 7)) << 2;
            float4 av[8], bv[8];
            #pragma unroll
            for (int i = 0; i < 8; i++) av[i] = *(const float4*)(Xs + (ty * 8 + i) * 64 + sa);
            #pragma unroll
            for (int j = 0; j < 8; j++) bv[j] = *(const float4*)(Xs + (tx * 8 + j) * 64 + sb);
            if (ty == 0) {
                #pragma unroll
                for (int j = 0; j < 8; j++)
                    nap[j] += bv[j].x * bv[j].x + bv[j].y * bv[j].y + bv[j].z * bv[j].z + bv[j].w * bv[j].w;
            }
            #pragma unroll
            for (int i = 0; i < 8; i++)
                #pragma unroll
                for (int j = 0; j < 8; j++)
                    acc[i][j] += av[i].x * bv[j].x + av[i].y * bv[j].y + av[i].z * bv[j].z + av[i].w * bv[j].w;
        }
    }
    if (ty == 0) {
        #pragma unroll
        for (int j = 0; j < 8; j++) na[tx * 8 + j] = nap[j];
    }
    __syncthreads();
    #pragma unroll
    for (int i = 0; i < 8; ++i) {
        int r = ty * 8 + i;
        float nai = na[r], mi = ml[r];
        float rs = 0.f;
        ushort o[8];
        #pragma unroll
        for (int j = 0; j < 8; ++j) {
            int c = tx * 8 + j;
            float D2 = nai - 2.f * acc[i][j] + na[c];
            float dv = expf(-0.1f * sqrtf(fmaxf(D2, 1e-6f)));
            dv *= mi * ml[c];
            rs += dv;
            o[j] = f2b(dv);
        }
        uint4 ou;
        ou.x = (unsigned)o[0] | ((unsigned)o[1] << 16);
        ou.y = (unsigned)o[2] | ((unsigned)o[3] << 16);
        ou.z = (unsigned)o[4] | ((unsigned)o[5] << 16);
        ou.w = (unsigned)o[6] | ((unsigned)o[7] << 16);
        *(uint4*)(dmb + (size_t)g * 16384 + r * 128 + tx * 8) = ou;
        ps[r * 16 + tx] = rs;
    }
    __syncthreads();
    if (tid < 128) {
        float deg = 0.f;
        for (int t2 = 0; t2 < 16; ++t2) deg += ps[tid * 16 + t2];
        deg = fminf(deg, 1000.0f);
        float nv = 1.0f / sqrtf(deg + 1e-6f);
        norm[rowbase + tid] = nv * ml[tid];
    }
}

// ---------- MFMA helpers ----------
__device__ __forceinline__ void stage_bf16(const ushort* __restrict__ src, size_t pitch,
                                           const int* __restrict__ rowmap, int rowbase, size_t kbase,
                                           ushort* lds, int nrows, int tid, int nthr) {
    int total = nrows * 8;
    for (int g = tid; g < total; g += nthr) {
        int row = g >> 3, wg = g & 7;
        size_t srow = rowmap ? (size_t)rowmap[rowbase + row] : (size_t)(rowbase + row);
        uint4 v = *(const uint4*)(src + srow * pitch + kbase + wg * 8);
        int w0 = (wg * 4) ^ ((row & 7) << 2);
        *(uint4*)((char*)lds + row * 128 + w0 * 4) = v;
    }
}

__device__ __forceinline__ short8 frag_ld(const ushort* lds, int row, int kc, int lane) {
    int w0 = (kc * 16 + ((lane >> 4) << 2)) ^ ((row & 7) << 2);
    return *(const short8*)((const char*)lds + row * 128 + w0 * 4);
}

// ---------- T = (A @ W) * norm, stored transposed bf16 [c][row] ----------
__global__ __launch_bounds__(256) void k_proj(const ushort* __restrict__ A, const int* __restrict__ rowmap,
                                              const ushort* __restrict__ Wt, const float* __restrict__ norm,
                                              ushort* __restrict__ Tt) {
    __shared__ ushort lA[128 * 64];
    __shared__ ushort lB[128 * 64];
    int tid = threadIdx.x, lane = tid & 63, wid = tid >> 6;
    int rowbase = blockIdx.x * 128, nbase = blockIdx.y * 128;
    int wm = (wid >> 1) * 64, wn = (wid & 1) * 64;
    int l15 = lane & 15;
    floatx4 zf = {0.f, 0.f, 0.f, 0.f};
    floatx4 acc[4][4];
    #pragma unroll
    for (int m = 0; m < 4; m++)
        #pragma unroll
        for (int n = 0; n < 4; n++) acc[m][n] = zf;
    for (int kb = 0; kb < 4; ++kb) {
        __syncthreads();
        stage_bf16(A, 256, rowmap, rowbase, (size_t)kb * 64, lA, 128, tid, 256);
        stage_bf16(Wt, 256, nullptr, nbase, (size_t)kb * 64, lB, 128, tid, 256);
        __syncthreads();
        #pragma unroll
        for (int kc = 0; kc < 2; ++kc) {
            short8 a[4], b[4];
            #pragma unroll
            for (int m = 0; m < 4; m++) a[m] = frag_ld(lA, wm + m * 16 + l15, kc, lane);
            #pragma unroll
            for (int n = 0; n < 4; n++) b[n] = frag_ld(lB, wn + n * 16 + l15, kc, lane);
            #pragma unroll
            for (int m = 0; m < 4; m++)
                #pragma unroll
                for (int n = 0; n < 4; n++)
                    acc[m][n] = __builtin_amdgcn_mfma_f32_16x16x32_bf16(a[m], b[n], acc[m][n], 0, 0, 0);
        }
    }
    int r4 = (lane >> 4) * 4;
    #pragma unroll
    for (int m = 0; m < 4; m++) {
        int r0 = rowbase + wm + m * 16 + r4;
        float4 nv = *(const float4*)(norm + r0);
        #pragma unroll
        for (int n = 0; n < 4; n++) {
            int cg = nbase + wn + n * 16 + l15;
            ushort4 o;
            o.x = f2b(acc[m][n][0] * nv.x);
            o.y = f2b(acc[m][n][1] * nv.y);
            o.z = f2b(acc[m][n][2] * nv.z);
            o.w = f2b(acc[m][n][3] * nv.w);
            *(ushort4*)(Tt + (size_t)cg * PITCH_T + r0) = o;
        }
    }
}

// ---------- FH = (dm @ T) * norm, stored transposed fp32 [c][row] ----------
__global__ __launch_bounds__(512) void k_adj(const ushort* __restrict__ dmb, const ushort* __restrict__ Tt,
                                             const float* __restrict__ norm, float* __restrict__ FHt) {
    __shared__ ushort lA[128 * 64];
    __shared__ ushort lB[256 * 64];
    int g = blockIdx.x;
    int tid = threadIdx.x, lane = tid & 63, wid = tid >> 6;
    int wm = (wid >> 2) * 64, wn = (wid & 3) * 64;
    int l15 = lane & 15;
    const ushort* dmg = dmb + (size_t)g * 16384;
    floatx4 zf = {0.f, 0.f, 0.f, 0.f};
    floatx4 acc[4][4];
    #pragma unroll
    for (int m = 0; m < 4; m++)
        #pragma unroll
        for (int n = 0; n < 4; n++) acc[m][n] = zf;
    for (int kb = 0; kb < 2; ++kb) {
        __syncthreads();
        stage_bf16(dmg, 128, nullptr, 0, (size_t)kb * 64, lA, 128, tid, 512);
        stage_bf16(Tt, PITCH_T, nullptr, 0, (size_t)g * 128 + kb * 64, lB, 256, tid, 512);
        __syncthreads();
        #pragma unroll
        for (int kc = 0; kc < 2; ++kc) {
            short8 a[4], b[4];
            #pragma unroll
            for (int m = 0; m < 4; m++) a[m] = frag_ld(lA, wm + m * 16 + l15, kc, lane);
            #pragma unroll
            for (int n = 0; n < 4; n++) b[n] = frag_ld(lB, wn + n * 16 + l15, kc, lane);
            #pragma unroll
            for (int m = 0; m < 4; m++)
                #pragma unroll
                for (int n = 0; n < 4; n++)
                    acc[m][n] = __builtin_amdgcn_mfma_f32_16x16x32_bf16(a[m], b[n], acc[m][n], 0, 0, 0);
        }
    }
    int r4 = (lane >> 4) * 4;
    #pragma unroll
    for (int m = 0; m < 4; m++) {
        int r0l = wm + m * 16 + r4;
        float4 nv = *(const float4*)(norm + g * 128 + r0l);
        #pragma unroll
        for (int n = 0; n < 4; n++) {
            int cg = wn + n * 16 + l15;
            float4 o;
            o.x = acc[m][n][0] * nv.x;
            o.y = acc[m][n][1] * nv.y;
            o.z = acc[m][n][2] * nv.z;
            o.w = acc[m][n][3] * nv.w;
            *(float4*)(FHt + (size_t)cg * PITCH_T + g * 128 + r0l) = o;
        }
    }
}

// ---------- combine: dual GEMM (wh, wt) + gate/elu epilogue ----------
template<int LAYER>
__global__ __launch_bounds__(512) void k_comb(const ushort* __restrict__ A, const int* __restrict__ rowmap,
                                              const ushort* __restrict__ WhT, const ushort* __restrict__ WtT,
                                              const float* __restrict__ bt, const float* __restrict__ FHt,
                                              const float* __restrict__ mf,
                                              ushort* __restrict__ outb, float* __restrict__ outf,
                                              const int* __restrict__ flatscat) {
    __shared__ ushort lA[128 * 64];
    __shared__ ushort lH[128 * 64];
    __shared__ ushort lG[128 * 64];
    int tid = threadIdx.x, lane = tid & 63, wid = tid >> 6;
    int rowbase = blockIdx.x * 128, nbase = blockIdx.y * 128;
    int wm = (wid >> 2) * 64, wn = (wid & 3) * 32;
    int l15 = lane & 15;
    floatx4 zf = {0.f, 0.f, 0.f, 0.f};
    floatx4 accH[4][2], accG[4][2];
    #pragma unroll
    for (int m = 0; m < 4; m++)
        #pragma unroll
        for (int n = 0; n < 2; n++) { accH[m][n] = zf; accG[m][n] = zf; }
    for (int kb = 0; kb < 4; ++kb) {
        __syncthreads();
        stage_bf16(A, 256, rowmap, rowbase, (size_t)kb * 64, lA, 128, tid, 512);
        stage_bf16(WhT, 256, nullptr, nbase, (size_t)kb * 64, lH, 128, tid, 512);
        stage_bf16(WtT, 256, nullptr, nbase, (size_t)kb * 64, lG, 128, tid, 512);
        __syncthreads();
        #pragma unroll
        for (int kc = 0; kc < 2; ++kc) {
            short8 a[4], bh[2], bg[2];
            #pragma unroll
            for (int m = 0; m < 4; m++) a[m] = frag_ld(lA, wm + m * 16 + l15, kc, lane);
            #pragma unroll
            for (int n = 0; n < 2; n++) {
                bh[n] = frag_ld(lH, wn + n * 16 + l15, kc, lane);
                bg[n] = frag_ld(lG, wn + n * 16 + l15, kc, lane);
            }
            #pragma unroll
            for (int m = 0; m < 4; m++)
                #pragma unroll
                for (int n = 0; n < 2; n++) {
                    accH[m][n] = __builtin_amdgcn_mfma_f32_16x16x32_bf16(a[m], bh[n], accH[m][n], 0, 0, 0);
                    accG[m][n] = __builtin_amdgcn_mfma_f32_16x16x32_bf16(a[m], bg[n], accG[m][n], 0, 0, 0);
                }
        }
    }
    int r4 = (lane >> 4) * 4;
    int base = wid * 512;
    for (int m = 0; m < 4; m++) {
        int r0l = wm + m * 16 + r4;
        int r0g = rowbase + r0l;
        float4 mv = *(const float4*)(mf + r0g);
        float mvv[4] = {mv.x, mv.y, mv.z, mv.w};
        float vals[2][4];
        #pragma unroll
        for (int n = 0; n < 2; n++) {
            int cg = nbase + wn + n * 16 + l15;
            float btc = bt[cg];
            float4 fh = *(const float4*)(FHt + (size_t)cg * PITCH_T + r0g);
            float fhv[4] = {fh.x, fh.y, fh.z, fh.w};
            #pragma unroll
            for (int i = 0; i < 4; i++) {
                float gate = 1.f / (1.f + expf(-(accG[m][n][i] + btc)));
                float het = mvv[i] * accH[m][n][i];
                float o = gate * fhv[i] + (1.f - gate) * het;
                o = (o > 0.f) ? o : expm1f(o);
                vals[n][i] = o * mvv[i];
            }
        }
        __syncthreads();
        if (LAYER == 0) {
            ushort* Ls = lA;
            #pragma unroll
            for (int n = 0; n < 2; n++)
                #pragma unroll
                for (int i = 0; i < 4; i++)
                    Ls[base + (r4 + i) * 32 + n * 16 + l15] = f2b(vals[n][i]);
            __syncthreads();
            #pragma unroll
            for (int it = 0; it < 2; ++it) {
                int lr = (lane >> 3) + it * 8;
                int lc4 = (lane & 7) * 4;
                ushort4 tv = *(const ushort4*)(Ls + base + lr * 32 + lc4);
                int rg = rowbase + wm + m * 16 + lr;
                *(ushort4*)(outb + (size_t)rg * 256 + nbase + wn + lc4) = tv;
            }
        } else {
            float* Ls = (float*)lA;
            #pragma unroll
            for (int n = 0; n < 2; n++)
                #pragma unroll
                for (int i = 0; i < 4; i++)
                    Ls[base + (r4 + i) * 32 + n * 16 + l15] = vals[n][i];
            __syncthreads();
            #pragma unroll
            for (int it = 0; it < 2; ++it) {
                int lr = (lane >> 3) + it * 8;
                int lc4 = (lane & 7) * 4;
                float4 tv = *(const float4*)(Ls + base + lr * 32 + lc4);
                int rg = rowbase + wm + m * 16 + lr;
                int dst = flatscat[rg];
                *(float4*)(outf + (size_t)dst * 256 + nbase + wn + lc4) = tv;
            }
        }
    }
}

extern "C" void kernel_launch(void* const* d_in, const int* in_sizes, int n_in,
                              void* d_out, int out_size, void* d_ws, size_t ws_size,
                              hipStream_t stream) {
    const float* x    = (const float*)d_in[0];
    const void*  msk  = d_in[1];
    const float* ln_g = (const float*)d_in[2];
    const float* ln_b = (const float*)d_in[3];
    const float* w1   = (const float*)d_in[4];
    const float* b1   = (const float*)d_in[5];
    const float* w2   = (const float*)d_in[6];
    const float* b2   = (const float*)d_in[7];
    const float* rot  = (const float*)d_in[8];
    const float* th0  = (const float*)d_in[9];
    const float* wh0  = (const float*)d_in[10];
    const float* wt0  = (const float*)d_in[11];
    const float* bt0  = (const float*)d_in[12];
    const float* th1  = (const float*)d_in[13];
    const float* wh1  = (const float*)d_in[14];
    const float* wt1  = (const float*)d_in[15];
    const float* bt1  = (const float*)d_in[16];

    char* ws = (char*)d_ws;
    float*  FHt  = (float*)(ws + OFF_FHT);
    ushort* Tt   = (ushort*)(ws + OFF_TT);
    ushort* out0 = (ushort*)(ws + OFF_OUT0);
    ushort* dmb  = (ushort*)(ws + OFF_DMB);
    ushort* wb   = (ushort*)(ws + OFF_WB);
    ushort* wbth0 = wb + 0 * 65536;
    ushort* wbwh0 = wb + 1 * 65536;
    ushort* wbwt0 = wb + 2 * 65536;
    ushort* wbth1 = wb + 3 * 65536;
    ushort* wbwh1 = wb + 4 * 65536;
    ushort* wbwt1 = wb + 5 * 65536;
    float* norm = (float*)(ws + OFF_NORM);
    float* mf   = (float*)(ws + OFF_MF);
    int*   bin  = (int*)(ws + OFF_BIN);
    int*   flat = (int*)(ws + OFF_FLAT);
    int*   mski = (int*)(ws + OFF_MSKI);
    int*   hist = (int*)(ws + OFF_HIST);
    int*   offs = (int*)(ws + OFF_OFFS);
    int*   flag = (int*)(ws + OFF_FLAG);
    int*   fixcnt = (int*)(ws + OFF_CNT);
    int*   fixlist = (int*)(ws + OFF_LIST);
    float*  xd  = (float*)d_out;
    ushort* xnb = (ushort*)((char*)d_out + (size_t)PTS * DDIM * 4);

    hipMemsetAsync(hist, 0, HISTBYTES, stream);
    hipMemsetAsync(fixcnt, 0, 4, stream);
    k_maskflag<<<1, 256, 0, stream>>>((const int*)msk, flag);
    k_masknorm<<<PTS / 256, 256, 0, stream>>>(msk, flag, mski);
    k_wprep<<<dim3(16, 6), 256, 0, stream>>>(th0, wh0, wt0, th1, wh1, wt1,
                                             wbth0, wbwh0, wbwt0, wbth1, wbwh1, wbwt1);
    k_stage1<<<PTS / 16, 256, 0, stream>>>(x, ln_g, ln_b, w1, b1, w2, b2, rot, mski,
                                           xnb, xd, bin, fixlist, fixcnt);
    k_fixup<<<2048, 64, 0, stream>>>(x, ln_g, ln_b, w1, b1, w2, b2, rot, mski,
                                     fixlist, fixcnt, bin);
    k_count<<<800, 128, 0, stream>>>(bin, hist);
    k_offsets<<<8, 256, 0, stream>>>(hist, offs);
    k_scatter<<<800, 128, 0, stream>>>(bin, offs, mski, flat, mf);
    k_dm<<<800, 256, 0, stream>>>(xd, flat, mf, dmb, norm);
    // layer 0
    k_proj<<<dim3(800, 2), 256, 0, stream>>>(xnb, flat, wbth0, norm, Tt);
    k_adj<<<800, 512, 0, stream>>>(dmb, Tt, norm, FHt);
    k_comb<0><<<dim3(800, 2), 512, 0, stream>>>(xnb, flat, wbwh0, wbwt0, bt0, FHt, mf, out0, nullptr, nullptr);
    // layer 1
    k_proj<<<dim3(800, 2), 256, 0, stream>>>(out0, nullptr, wbth1, norm, Tt);
    k_adj<<<800, 512, 0, stream>>>(dmb, Tt, norm, FHt);
    k_comb<1><<<dim3(800, 2), 512, 0, stream>>>(out0, nullptr, wbwh1, wbwt1, bt1, FHt, mf, nullptr, (float*)d_out, flat);
}

// Round 5
// 883.495 us; speedup vs baseline: 1.2457x; 1.2457x over previous
//
#include <hip/hip_runtime.h>
#include <math.h>

#define BB 8
#define NN 12800
#define FF 256
#define DDIM 128
#define NBINS 100
#define BSIZE 128
#define NROT 50
#define NIDS 199
#define PTS (BB*NN)            // 102400
#define PITCH_T ((size_t)102400)

// ---- workspace layout (bytes) ----
#define OFF_FHT  ((size_t)0)            // 104857600 : FH transposed fp32 [256][102400]
#define OFF_TT   ((size_t)104857600)    // 52428800  : T transposed bf16 [256][102400]
#define OFF_OUT0 ((size_t)157286400)    // 52428800  : out0 bf16 [102400][256]
#define OFF_DMB  ((size_t)209715200)    // 26214400  : dm bf16 [800][128][128]
#define OFF_WB   ((size_t)235929600)    // 786432    : 6 weights bf16 transposed [256][256]
#define OFF_NORM ((size_t)236716032)    // 409600
#define OFF_MF   ((size_t)237125632)    // 409600
#define OFF_BIN  ((size_t)237535232)    // 409600 (int)
#define OFF_FLAT ((size_t)237944832)    // 409600 (int)
#define OFF_MSKI ((size_t)238354432)    // 409600 (int)
#define OFF_HIST ((size_t)238764032)    // 636800 (int)
#define OFF_OFFS ((size_t)239400832)    // 636800 (int)
#define OFF_FLAG ((size_t)240037632)    // 64
#define OFF_CNT  ((size_t)240037696)    // 64
#define OFF_LIST ((size_t)240037760)    // 409600 (int)
#define OFF_W1H  ((size_t)240447360)    // 65536 : w1^T hi bf16 [128][256]
#define OFF_W1L  ((size_t)240512896)    // 65536
#define OFF_W2H  ((size_t)240578432)    // 32768 : w2^T hi bf16 [128][128]
#define OFF_W2L  ((size_t)240611200)    // 32768
#define OFF_RH   ((size_t)240643968)    // 16384 : rot^T hi bf16 [64][128]
#define OFF_RL   ((size_t)240660352)    // 16384
#define HISTBYTES (8*100*199*4)

using short8  = __attribute__((ext_vector_type(8))) short;
using floatx4 = __attribute__((ext_vector_type(4))) float;

__device__ __forceinline__ ushort f2b(float f) {
    unsigned u = __float_as_uint(f);
    unsigned r = (u + 0x7FFFu + ((u >> 16) & 1u)) >> 16;
    return (ushort)r;
}
__device__ __forceinline__ float b2f(ushort h) {
    return __uint_as_float(((unsigned)h) << 16);
}
__device__ __forceinline__ uint4 pack8(const ushort* o) {
    uint4 u;
    u.x = (unsigned)o[0] | ((unsigned)o[1] << 16);
    u.y = (unsigned)o[2] | ((unsigned)o[3] << 16);
    u.z = (unsigned)o[4] | ((unsigned)o[5] << 16);
    u.w = (unsigned)o[6] | ((unsigned)o[7] << 16);
    return u;
}

// ---------- mask dtype sniffing ----------
__global__ void k_maskflag(const int* mi, int* flag) {
    __shared__ int notInt, notFloat;
    if (threadIdx.x == 0) { notInt = 0; notFloat = 0; }
    __syncthreads();
    int v = mi[threadIdx.x];
    if (v != 0 && v != 1) atomicOr(&notInt, 1);
    if (v != 0 && v != 0x3F800000) atomicOr(&notFloat, 1);
    __syncthreads();
    if (threadIdx.x == 0) flag[0] = (!notInt) ? 0 : ((!notFloat) ? 2 : 1);
}

__global__ void k_masknorm(const void* msk, const int* flag, int* mski) {
    int i = blockIdx.x * blockDim.x + threadIdx.x;
    if (i >= PTS) return;
    int f = flag[0];
    int v;
    if (f == 0)      v = ((const int*)msk)[i] != 0;
    else if (f == 2) v = ((const float*)msk)[i] != 0.0f;
    else             v = ((const unsigned char*)msk)[i] != 0;
    mski[i] = v;
}

// ---------- weight prep: fp32 [k][n] -> bf16 transposed [n][k] (GHConv weights) ----------
__global__ __launch_bounds__(256) void k_wprep(
    const float* s0, const float* s1, const float* s2,
    const float* s3, const float* s4, const float* s5,
    ushort* d0, ushort* d1, ushort* d2, ushort* d3, ushort* d4, ushort* d5)
{
    __shared__ float Ls[64 * 65];
    const float* src; ushort* dst;
    switch (blockIdx.y) {
        case 0: src = s0; dst = d0; break;
        case 1: src = s1; dst = d1; break;
        case 2: src = s2; dst = d2; break;
        case 3: src = s3; dst = d3; break;
        case 4: src = s4; dst = d4; break;
        default: src = s5; dst = d5; break;
    }
    int t = blockIdx.x;
    int kb = (t & 3) * 64, nb = (t >> 2) * 64;
    int tid = threadIdx.x;
    for (int q = 0; q < 4; ++q) {
        int g = q * 256 + tid;
        int kl = g >> 4, f4 = g & 15;
        float4 v = *(const float4*)(src + (size_t)(kb + kl) * 256 + nb + f4 * 4);
        Ls[kl * 65 + f4 * 4 + 0] = v.x;
        Ls[kl * 65 + f4 * 4 + 1] = v.y;
        Ls[kl * 65 + f4 * 4 + 2] = v.z;
        Ls[kl * 65 + f4 * 4 + 3] = v.w;
    }
    __syncthreads();
    for (int q = 0; q < 2; ++q) {
        int g = q * 256 + tid;
        int nl = g >> 3, wg = g & 7;
        ushort o[8];
        #pragma unroll
        for (int c = 0; c < 8; ++c) o[c] = f2b(Ls[(wg * 8 + c) * 65 + nl]);
        *(uint4*)(dst + (size_t)(nb + nl) * 256 + kb + wg * 8) = pack8(o);
    }
}

// ---------- split-weight prep: fp32 [K][srcN] -> hi/lo bf16 transposed [N][K] ----------
__global__ __launch_bounds__(256) void k_wsplit(const float* __restrict__ src, int K, int N,
                                               int srcN, int nvalid,
                                               ushort* __restrict__ dh, ushort* __restrict__ dl) {
    __shared__ float Ls[64 * 65];
    int tilesN = N >> 6;
    int kb = (blockIdx.x / tilesN) * 64, nb = (blockIdx.x % tilesN) * 64;
    int tid = threadIdx.x;
    for (int q = 0; q < 4; ++q) {
        int g = q * 256 + tid;
        int kl = g >> 4, c4 = (g & 15) * 4;
        #pragma unroll
        for (int j = 0; j < 4; ++j) {
            int n = nb + c4 + j;
            float v = (n < nvalid) ? src[(size_t)(kb + kl) * srcN + n] : 0.f;
            Ls[kl * 65 + c4 + j] = v;
        }
    }
    __syncthreads();
    for (int q = 0; q < 2; ++q) {
        int g = q * 256 + tid;
        int nl = g >> 3, wg = g & 7;
        ushort oh[8], ol[8];
        #pragma unroll
        for (int c = 0; c < 8; ++c) {
            float v = Ls[(wg * 8 + c) * 65 + nl];
            ushort h = f2b(v);
            oh[c] = h;
            ol[c] = f2b(v - b2f(h));
        }
        *(uint4*)(dh + (size_t)(nb + nl) * K + kb + wg * 8) = pack8(oh);
        *(uint4*)(dl + (size_t)(nb + nl) * K + kb + wg * 8) = pack8(ol);
    }
}

// ---------- MFMA LDS helpers (layout verified in rounds 2-3) ----------
__device__ __forceinline__ void stage_bf16(const ushort* __restrict__ src, size_t pitch,
                                           const int* __restrict__ rowmap, int rowbase, size_t kbase,
                                           ushort* lds, int nrows, int tid, int nthr) {
    int total = nrows * 8;
    for (int g = tid; g < total; g += nthr) {
        int row = g >> 3, wg = g & 7;
        size_t srow = rowmap ? (size_t)rowmap[rowbase + row] : (size_t)(rowbase + row);
        uint4 v = *(const uint4*)(src + srow * pitch + kbase + wg * 8);
        int w0 = (wg * 4) ^ ((row & 7) << 2);
        *(uint4*)((char*)lds + row * 128 + w0 * 4) = v;
    }
}

__device__ __forceinline__ short8 frag_ld(const ushort* lds, int row, int kc, int lane) {
    int w0 = (kc * 16 + ((lane >> 4) << 2)) ^ ((row & 7) << 2);
    return *(const short8*)((const char*)lds + row * 128 + w0 * 4);
}

// ---------- stage 1 v3: fused LN + FFN + rot via split-bf16 MFMA ----------
// 64 points/block, 512 threads, 128KB LDS. Chain accuracy ~fp32 (3-MFMA split);
// marginal bins re-decided in fp64 by k_fixup.
__global__ __launch_bounds__(512) void k_stage1(
    const float* __restrict__ x, const float* __restrict__ g, const float* __restrict__ be,
    const float* __restrict__ b1, const float* __restrict__ b2,
    const ushort* __restrict__ w1h, const ushort* __restrict__ w1l,
    const ushort* __restrict__ w2h, const ushort* __restrict__ w2l,
    const ushort* __restrict__ rth, const ushort* __restrict__ rtl,
    const int* __restrict__ mski,
    ushort* __restrict__ xn_out, float* __restrict__ xd_out, int* __restrict__ bin_out,
    int* __restrict__ fixlist, int* __restrict__ fixcnt)
{
    __shared__ ushort lXh[4 * 64 * 64];    // 32KB: A slabs (xn; later h in 0-1, xd in 2-3)
    __shared__ ushort lXl[4 * 64 * 64];    // 32KB: lo parts
    __shared__ ushort lWh[2][128 * 64];    // 32KB: B hi ping-pong
    __shared__ ushort lWl[2][128 * 64];    // 32KB: B lo ping-pong
    int tid = threadIdx.x, lane = tid & 63, wid = tid >> 6;
    int base = blockIdx.x * 64;
    int l15 = lane & 15;
    int r4 = (lane >> 4) * 4;

    // prologue: stage w1 slab 0 (overlaps LN)
    stage_bf16(w1h, 256, nullptr, 0, 0, lWh[0], 128, tid, 512);
    stage_bf16(w1l, 256, nullptr, 0, 0, lWl[0], 128, tid, 512);

    {   // ---- phase 0: LN (8 threads/point) ----
        int row = tid >> 3, sub = tid & 7;
        const float* xr = x + (size_t)(base + row) * FF + sub * 32;
        float v[32];
        float s = 0.f;
        #pragma unroll
        for (int q = 0; q < 8; ++q) {
            float4 f = *(const float4*)(xr + q * 4);
            v[q*4+0] = f.x; v[q*4+1] = f.y; v[q*4+2] = f.z; v[q*4+3] = f.w;
            s += f.x + f.y + f.z + f.w;
        }
        s += __shfl_xor(s, 1, 8); s += __shfl_xor(s, 2, 8); s += __shfl_xor(s, 4, 8);
        float mu = s * (1.f / 256.f);
        float s2 = 0.f;
        #pragma unroll
        for (int q = 0; q < 32; ++q) { float d = v[q] - mu; s2 += d * d; }
        s2 += __shfl_xor(s2, 1, 8); s2 += __shfl_xor(s2, 2, 8); s2 += __shfl_xor(s2, 4, 8);
        float rs = 1.0f / sqrtf(s2 * (1.f / 256.f) + 1e-6f);
        int kb = sub >> 1;
        ushort* xo = xn_out + (size_t)(base + row) * FF + sub * 32;
        #pragma unroll
        for (int j = 0; j < 4; ++j) {
            int i0 = sub * 32 + j * 8;
            float4 g0 = *(const float4*)(g + i0);
            float4 g1 = *(const float4*)(g + i0 + 4);
            float4 e0 = *(const float4*)(be + i0);
            float4 e1 = *(const float4*)(be + i0 + 4);
            float gv[8] = {g0.x,g0.y,g0.z,g0.w,g1.x,g1.y,g1.z,g1.w};
            float ev[8] = {e0.x,e0.y,e0.z,e0.w,e1.x,e1.y,e1.z,e1.w};
            ushort hh[8], ll[8];
            #pragma unroll
            for (int c = 0; c < 8; ++c) {
                float xv = (v[j*8+c] - mu) * rs * gv[c] + ev[c];
                ushort h = f2b(xv);
                hh[c] = h;
                ll[c] = f2b(xv - b2f(h));
            }
            uint4 uh = pack8(hh), ul = pack8(ll);
            *(uint4*)(xo + j * 8) = uh;
            int wg = (sub & 1) * 4 + j;
            int w0 = (wg * 4) ^ ((row & 7) << 2);
            *(uint4*)((char*)lXh + kb * 8192 + row * 128 + w0 * 4) = uh;
            *(uint4*)((char*)lXl + kb * 8192 + row * 128 + w0 * 4) = ul;
        }
    }
    __syncthreads();

    int wm = (wid >> 2) * 32, wn = (wid & 3) * 32;
    floatx4 zf = {0.f, 0.f, 0.f, 0.f};

    // ---- GEMM1: h = elu(xn @ w1 + b1), M=64 N=128 K=256, split-bf16 ----
    floatx4 acc[2][2];
    #pragma unroll
    for (int m = 0; m < 2; m++)
        #pragma unroll
        for (int n = 0; n < 2; n++) acc[m][n] = zf;
    for (int kb = 0; kb < 4; ++kb) {
        if (kb < 3) {
            stage_bf16(w1h, 256, nullptr, 0, (size_t)(kb + 1) * 64, lWh[(kb + 1) & 1], 128, tid, 512);
            stage_bf16(w1l, 256, nullptr, 0, (size_t)(kb + 1) * 64, lWl[(kb + 1) & 1], 128, tid, 512);
        }
        #pragma unroll
        for (int kc = 0; kc < 2; ++kc) {
            short8 ah[2], al[2], bh[2], bl[2];
            #pragma unroll
            for (int m = 0; m < 2; m++) {
                ah[m] = frag_ld(lXh + kb * 4096, wm + m * 16 + l15, kc, lane);
                al[m] = frag_ld(lXl + kb * 4096, wm + m * 16 + l15, kc, lane);
            }
            #pragma unroll
            for (int n = 0; n < 2; n++) {
                bh[n] = frag_ld(lWh[kb & 1], wn + n * 16 + l15, kc, lane);
                bl[n] = frag_ld(lWl[kb & 1], wn + n * 16 + l15, kc, lane);
            }
            #pragma unroll
            for (int m = 0; m < 2; m++)
                #pragma unroll
                for (int n = 0; n < 2; n++) {
                    acc[m][n] = __builtin_amdgcn_mfma_f32_16x16x32_bf16(ah[m], bh[n], acc[m][n], 0, 0, 0);
                    acc[m][n] = __builtin_amdgcn_mfma_f32_16x16x32_bf16(ah[m], bl[n], acc[m][n], 0, 0, 0);
                    acc[m][n] = __builtin_amdgcn_mfma_f32_16x16x32_bf16(al[m], bh[n], acc[m][n], 0, 0, 0);
                }
        }
        __syncthreads();
    }
    // epilogue1: +b1, elu, split -> lX slabs 0-1 ; stage w2 slab0
    stage_bf16(w2h, 128, nullptr, 0, 0, lWh[0], 128, tid, 512);
    stage_bf16(w2l, 128, nullptr, 0, 0, lWl[0], 128, tid, 512);
    {
        #pragma unroll
        for (int n = 0; n < 2; n++) {
            int cg = wn + n * 16 + l15;
            float b1v = b1[cg];
            int slab = cg >> 6, c64 = cg & 63;
            int wg = c64 >> 3, e = c64 & 7;
            #pragma unroll
            for (int m = 0; m < 2; m++) {
                #pragma unroll
                for (int i = 0; i < 4; i++) {
                    int r = wm + m * 16 + r4 + i;
                    float hv = acc[m][n][i] + b1v;
                    hv = (hv > 0.f) ? hv : expm1f(hv);
                    ushort h = f2b(hv);
                    int w0 = (wg * 4) ^ ((r & 7) << 2);
                    int idx = slab * 4096 + r * 64 + w0 * 2 + e;
                    lXh[idx] = h;
                    lXl[idx] = f2b(hv - b2f(h));
                }
            }
        }
    }
    __syncthreads();

    // ---- GEMM2: xd = h @ w2 + b2, M=64 N=128 K=128 ----
    floatx4 acc2[2][2];
    #pragma unroll
    for (int m = 0; m < 2; m++)
        #pragma unroll
        for (int n = 0; n < 2; n++) acc2[m][n] = zf;
    for (int kb = 0; kb < 2; ++kb) {
        if (kb == 0) {
            stage_bf16(w2h, 128, nullptr, 0, 64, lWh[1], 128, tid, 512);
            stage_bf16(w2l, 128, nullptr, 0, 64, lWl[1], 128, tid, 512);
        }
        #pragma unroll
        for (int kc = 0; kc < 2; ++kc) {
            short8 ah[2], al[2], bh[2], bl[2];
            #pragma unroll
            for (int m = 0; m < 2; m++) {
                ah[m] = frag_ld(lXh + kb * 4096, wm + m * 16 + l15, kc, lane);
                al[m] = frag_ld(lXl + kb * 4096, wm + m * 16 + l15, kc, lane);
            }
            #pragma unroll
            for (int n = 0; n < 2; n++) {
                bh[n] = frag_ld(lWh[kb], wn + n * 16 + l15, kc, lane);
                bl[n] = frag_ld(lWl[kb], wn + n * 16 + l15, kc, lane);
            }
            #pragma unroll
            for (int m = 0; m < 2; m++)
                #pragma unroll
                for (int n = 0; n < 2; n++) {
                    acc2[m][n] = __builtin_amdgcn_mfma_f32_16x16x32_bf16(ah[m], bh[n], acc2[m][n], 0, 0, 0);
                    acc2[m][n] = __builtin_amdgcn_mfma_f32_16x16x32_bf16(ah[m], bl[n], acc2[m][n], 0, 0, 0);
                    acc2[m][n] = __builtin_amdgcn_mfma_f32_16x16x32_bf16(al[m], bh[n], acc2[m][n], 0, 0, 0);
                }
        }
        __syncthreads();
    }
    // epilogue2: +b2 -> xd fp32 global + split bf16 -> lX slabs 2-3 ; stage rot
    stage_bf16(rth, 128, nullptr, 0, 0, lWh[0], 64, tid, 512);
    stage_bf16(rtl, 128, nullptr, 0, 0, lWl[0], 64, tid, 512);
    stage_bf16(rth, 128, nullptr, 0, 64, lWh[1], 64, tid, 512);
    stage_bf16(rtl, 128, nullptr, 0, 64, lWl[1], 64, tid, 512);
    {
        #pragma unroll
        for (int n = 0; n < 2; n++) {
            int cg = wn + n * 16 + l15;
            float b2v = b2[cg];
            int slab = 2 + (cg >> 6), c64 = cg & 63;
            int wg = c64 >> 3, e = c64 & 7;
            #pragma unroll
            for (int m = 0; m < 2; m++) {
                #pragma unroll
                for (int i = 0; i < 4; i++) {
                    int r = wm + m * 16 + r4 + i;
                    float xv = acc2[m][n][i] + b2v;
                    xd_out[(size_t)(base + r) * DDIM + cg] = xv;
                    ushort h = f2b(xv);
                    int w0 = (wg * 4) ^ ((r & 7) << 2);
                    int idx = slab * 4096 + r * 64 + w0 * 2 + e;
                    lXh[idx] = h;
                    lXl[idx] = f2b(xv - b2f(h));
                }
            }
        }
    }
    __syncthreads();

    // ---- GEMM3: mul = xd @ rot, M=64 N=64 K=128 ----
    floatx4 acc3[2];
    acc3[0] = zf; acc3[1] = zf;
    int wm3 = (wid >> 2) * 32, wn3 = (wid & 3) * 16;
    for (int kb = 0; kb < 2; ++kb) {
        #pragma unroll
        for (int kc = 0; kc < 2; ++kc) {
            short8 ah[2], al[2], bh, bl;
            #pragma unroll
            for (int m = 0; m < 2; m++) {
                ah[m] = frag_ld(lXh + (2 + kb) * 4096, wm3 + m * 16 + l15, kc, lane);
                al[m] = frag_ld(lXl + (2 + kb) * 4096, wm3 + m * 16 + l15, kc, lane);
            }
            bh = frag_ld(lWh[kb], wn3 + l15, kc, lane);
            bl = frag_ld(lWl[kb], wn3 + l15, kc, lane);
            #pragma unroll
            for (int m = 0; m < 2; m++) {
                acc3[m] = __builtin_amdgcn_mfma_f32_16x16x32_bf16(ah[m], bh, acc3[m], 0, 0, 0);
                acc3[m] = __builtin_amdgcn_mfma_f32_16x16x32_bf16(ah[m], bl, acc3[m], 0, 0, 0);
                acc3[m] = __builtin_amdgcn_mfma_f32_16x16x32_bf16(al[m], bh, acc3[m], 0, 0, 0);
            }
        }
    }
    __syncthreads();
    // mul -> LDS (alias lWh region), pitch 65
    float* lMul = (float*)(&lWh[0][0]);
    {
        #pragma unroll
        for (int m = 0; m < 2; m++)
            #pragma unroll
            for (int i = 0; i < 4; i++) {
                int r = wm3 + m * 16 + r4 + i;
                lMul[r * 65 + wn3 + l15] = acc3[m][i];
            }
    }
    __syncthreads();

    // ---- top-2 argmax over [mul, -mul], margin flag ----
    {
        int p = tid >> 3, q = tid & 7;
        float v1 = -1e30f, v2 = -1e30f; int i1 = 1 << 29;
        #pragma unroll
        for (int j = 0; j < 8; ++j) {
            int c = q * 8 + j;
            if (c < 50) {
                float m = lMul[p * 65 + c];
                float wv, lv; int wi, li;
                if (m >= 0.f) { wv = m; wi = c; lv = -m; li = 50 + c; }
                else          { wv = -m; wi = 50 + c; lv = m; li = c; }
                if (wv > v1 || (wv == v1 && wi < i1)) { v2 = v1; v1 = wv; i1 = wi; }
                else if (wv > v2) v2 = wv;
                if (lv > v1 || (lv == v1 && li < i1)) { v2 = v1; v1 = lv; i1 = li; }
                else if (lv > v2) v2 = lv;
            }
        }
        #pragma unroll
        for (int off = 1; off < 8; off <<= 1) {
            float o1 = __shfl_xor(v1, off, 8);
            int   oi = __shfl_xor(i1, off, 8);
            float o2 = __shfl_xor(v2, off, 8);
            bool take = (o1 > v1) || (o1 == v1 && oi < i1);
            float small = take ? v1 : o1;
            if (take) { v1 = o1; i1 = oi; }
            v2 = fmaxf(fmaxf(v2, o2), small);
        }
        if (q == 0) {
            int pt = base + p;
            bin_out[pt] = i1 + (mski[pt] ? 0 : (NBINS - 1));
            float tau = 3e-4f + 1.5e-3f * v1;
            if (v1 - v2 < tau) {
                int pos = atomicAdd(fixcnt, 1);
                fixlist[pos] = pt;
            }
        }
    }
}

// ---------- fp64 fixup for margin-flagged points (one wave per point) ----------
__global__ __launch_bounds__(64) void k_fixup(
    const float* __restrict__ x, const float* __restrict__ g, const float* __restrict__ be,
    const float* __restrict__ w1, const float* __restrict__ b1,
    const float* __restrict__ w2, const float* __restrict__ b2,
    const float* __restrict__ rot, const int* __restrict__ mski,
    const int* __restrict__ fixlist, const int* __restrict__ fixcnt,
    int* __restrict__ bin_out)
{
    __shared__ double xn_s[256];
    __shared__ double h_s[128];
    __shared__ double xd_s[128];
    int lane = threadIdx.x;
    int n = fixcnt[0];
    for (int e = blockIdx.x; e < n; e += gridDim.x) {
        int pt = fixlist[e];
        const float* xr = x + (size_t)pt * FF;
        double s = 0.0, xv[4];
        #pragma unroll
        for (int q = 0; q < 4; q++) { xv[q] = (double)xr[lane + q * 64]; s += xv[q]; }
        #pragma unroll
        for (int off = 1; off < 64; off <<= 1) s += __shfl_xor(s, off, 64);
        double mu = s * (1.0 / 256.0);
        double s2 = 0.0;
        #pragma unroll
        for (int q = 0; q < 4; q++) { double d = xv[q] - mu; s2 += d * d; }
        #pragma unroll
        for (int off = 1; off < 64; off <<= 1) s2 += __shfl_xor(s2, off, 64);
        double rs = 1.0 / sqrt(s2 * (1.0 / 256.0) + 1e-6);
        #pragma unroll
        for (int q = 0; q < 4; q++) {
            int i = lane + q * 64;
            xn_s[i] = (xv[q] - mu) * rs * (double)g[i] + (double)be[i];
        }
        __syncthreads();
        #pragma unroll
        for (int q = 0; q < 2; q++) {
            int j = lane + q * 64;
            double a0 = 0.0, a1 = 0.0;
            for (int k = 0; k < FF; k += 2) {
                a0 += xn_s[k] * (double)w1[k * DDIM + j];
                a1 += xn_s[k + 1] * (double)w1[(k + 1) * DDIM + j];
            }
            double a = (double)b1[j] + a0 + a1;
            h_s[j] = (a > 0.0) ? a : expm1(a);
        }
        __syncthreads();
        #pragma unroll
        for (int q = 0; q < 2; q++) {
            int j = lane + q * 64;
            double a0 = 0.0, a1 = 0.0;
            for (int k = 0; k < DDIM; k += 2) {
                a0 += h_s[k] * (double)w2[k * DDIM + j];
                a1 += h_s[k + 1] * (double)w2[(k + 1) * DDIM + j];
            }
            xd_s[j] = (double)b2[j] + a0 + a1;
        }
        __syncthreads();
        double v; int idx;
        if (lane < NROT) {
            double m = 0.0;
            for (int k = 0; k < DDIM; k++) m += xd_s[k] * (double)rot[k * 100 + lane];
            if (m >= 0.0) { v = m; idx = lane; } else { v = -m; idx = 50 + lane; }
        } else { v = -1e300; idx = 1 << 29; }
        #pragma unroll
        for (int off = 1; off < 64; off <<= 1) {
            double ov = __shfl_xor(v, off, 64);
            int oi = __shfl_xor(idx, off, 64);
            if (ov > v || (ov == v && oi < idx)) { v = ov; idx = oi; }
        }
        if (lane == 0) bin_out[pt] = idx + (mski[pt] ? 0 : (NBINS - 1));
        __syncthreads();
    }
}

// ---------- binning: stable counting sort ----------
__global__ void k_count(const int* __restrict__ bin, int* __restrict__ hist) {
    int c = blockIdx.x % 100, b = blockIdx.x / 100;
    int t = threadIdx.x;
    int v = bin[b * NN + c * BSIZE + t];
    atomicAdd(&hist[(b * 100 + c) * NIDS + v], 1);
}

__global__ void k_offsets(const int* __restrict__ hist, int* __restrict__ offs) {
    __shared__ int tot[NIDS];
    __shared__ int start[NIDS];
    int b = blockIdx.x, v = threadIdx.x;
    if (v < NIDS) {
        int s = 0;
        for (int c = 0; c < 100; c++) s += hist[(b * 100 + c) * NIDS + v];
        tot[v] = s;
    }
    __syncthreads();
    if (threadIdx.x == 0) {
        int run = 0;
        for (int i = 0; i < NIDS; i++) { start[i] = run; run += tot[i]; }
    }
    __syncthreads();
    if (v < NIDS) {
        int run = start[v];
        for (int c = 0; c < 100; c++) {
            offs[(b * 100 + c) * NIDS + v] = run;
            run += hist[(b * 100 + c) * NIDS + v];
        }
    }
}

__global__ void k_scatter(const int* __restrict__ bin, const int* __restrict__ offs,
                          const int* __restrict__ mski, int* __restrict__ flat,
                          float* __restrict__ mf) {
    __shared__ int sv[BSIZE];
    int c = blockIdx.x % 100, b = blockIdx.x / 100;
    int t = threadIdx.x;
    int n = c * BSIZE + t;
    int v = bin[b * NN + n];
    sv[t] = v;
    __syncthreads();
    int rank = 0;
    for (int u = 0; u < t; u++) rank += (sv[u] == v);
    int r = offs[(b * 100 + c) * NIDS + v] + rank;
    flat[b * NN + r] = b * NN + n;
    mf[b * NN + r] = mski[b * NN + n] ? 1.0f : 0.0f;
}

// ---------- per-bin pairwise kernel matrix (fp32 tiled), fused deg/norm ----------
__global__ __launch_bounds__(256) void k_dm(const float* __restrict__ xd, const int* __restrict__ flat,
                                            const float* __restrict__ mf, ushort* __restrict__ dmb,
                                            float* __restrict__ norm) {
    __shared__ float Xs[128 * 64];
    __shared__ float na[128];
    __shared__ float ml[128];
    __shared__ float ps[128 * 16];
    int g = blockIdx.x, tid = threadIdx.x;
    int tx = tid & 15, ty = tid >> 4;
    int rowbase = g * 128;
    if (tid < 128) ml[tid] = mf[rowbase + tid];
    float acc[8][8];
    #pragma unroll
    for (int i = 0; i < 8; i++)
        #pragma unroll
        for (int j = 0; j < 8; j++) acc[i][j] = 0.f;
    float nap[8];
    #pragma unroll
    for (int j = 0; j < 8; j++) nap[j] = 0.f;

    for (int kh = 0; kh < 2; ++kh) {
        __syncthreads();
        for (int q = 0; q < 8; ++q) {
            int gg = q * 256 + tid;
            int row = gg >> 4, f4 = gg & 15;
            int srow = flat[rowbase + row];
            float4 v = *(const float4*)(xd + (size_t)srow * DDIM + kh * 64 + f4 * 4);
            int f4s = f4 ^ ((row >> 3) & 7);
            *(float4*)(Xs + row * 64 + f4s * 4) = v;
        }
        __syncthreads();
        for (int k4 = 0; k4 < 16; ++k4) {
            int sa = (k4 ^ (ty & 7)) << 2;
            int sb = (k4 ^ (tx & 7)) << 2;
            float4 av[8], bv[8];
            #pragma unroll
            for (int i = 0; i < 8; i++) av[i] = *(const float4*)(Xs + (ty * 8 + i) * 64 + sa);
            #pragma unroll
            for (int j = 0; j < 8; j++) bv[j] = *(const float4*)(Xs + (tx * 8 + j) * 64 + sb);
            if (ty == 0) {
                #pragma unroll
                for (int j = 0; j < 8; j++)
                    nap[j] += bv[j].x * bv[j].x + bv[j].y * bv[j].y + bv[j].z * bv[j].z + bv[j].w * bv[j].w;
            }
            #pragma unroll
            for (int i = 0; i < 8; i++)
                #pragma unroll
                for (int j = 0; j < 8; j++)
                    acc[i][j] += av[i].x * bv[j].x + av[i].y * bv[j].y + av[i].z * bv[j].z + av[i].w * bv[j].w;
        }
    }
    if (ty == 0) {
        #pragma unroll
        for (int j = 0; j < 8; j++) na[tx * 8 + j] = nap[j];
    }
    __syncthreads();
    #pragma unroll
    for (int i = 0; i < 8; ++i) {
        int r = ty * 8 + i;
        float nai = na[r], mi = ml[r];
        float rs = 0.f;
        ushort o[8];
        #pragma unroll
        for (int j = 0; j < 8; ++j) {
            int c = tx * 8 + j;
            float D2 = nai - 2.f * acc[i][j] + na[c];
            float dv = expf(-0.1f * sqrtf(fmaxf(D2, 1e-6f)));
            dv *= mi * ml[c];
            rs += dv;
            o[j] = f2b(dv);
        }
        *(uint4*)(dmb + (size_t)g * 16384 + r * 128 + tx * 8) = pack8(o);
        ps[r * 16 + tx] = rs;
    }
    __syncthreads();
    if (tid < 128) {
        float deg = 0.f;
        for (int t2 = 0; t2 < 16; ++t2) deg += ps[tid * 16 + t2];
        deg = fminf(deg, 1000.0f);
        float nv = 1.0f / sqrtf(deg + 1e-6f);
        norm[rowbase + tid] = nv * ml[tid];
    }
}

// ---------- T = (A @ W) * norm, stored transposed bf16 [c][row] ----------
__global__ __launch_bounds__(256) void k_proj(const ushort* __restrict__ A, const int* __restrict__ rowmap,
                                              const ushort* __restrict__ Wt, const float* __restrict__ norm,
                                              ushort* __restrict__ Tt) {
    __shared__ ushort lA[128 * 64];
    __shared__ ushort lB[128 * 64];
    int tid = threadIdx.x, lane = tid & 63, wid = tid >> 6;
    int rowbase = blockIdx.x * 128, nbase = blockIdx.y * 128;
    int wm = (wid >> 1) * 64, wn = (wid & 1) * 64;
    int l15 = lane & 15;
    floatx4 zf = {0.f, 0.f, 0.f, 0.f};
    floatx4 acc[4][4];
    #pragma unroll
    for (int m = 0; m < 4; m++)
        #pragma unroll
        for (int n = 0; n < 4; n++) acc[m][n] = zf;
    for (int kb = 0; kb < 4; ++kb) {
        __syncthreads();
        stage_bf16(A, 256, rowmap, rowbase, (size_t)kb * 64, lA, 128, tid, 256);
        stage_bf16(Wt, 256, nullptr, nbase, (size_t)kb * 64, lB, 128, tid, 256);
        __syncthreads();
        #pragma unroll
        for (int kc = 0; kc < 2; ++kc) {
            short8 a[4], b[4];
            #pragma unroll
            for (int m = 0; m < 4; m++) a[m] = frag_ld(lA, wm + m * 16 + l15, kc, lane);
            #pragma unroll
            for (int n = 0; n < 4; n++) b[n] = frag_ld(lB, wn + n * 16 + l15, kc, lane);
            #pragma unroll
            for (int m = 0; m < 4; m++)
                #pragma unroll
                for (int n = 0; n < 4; n++)
                    acc[m][n] = __builtin_amdgcn_mfma_f32_16x16x32_bf16(a[m], b[n], acc[m][n], 0, 0, 0);
        }
    }
    int r4 = (lane >> 4) * 4;
    #pragma unroll
    for (int m = 0; m < 4; m++) {
        int r0 = rowbase + wm + m * 16 + r4;
        float4 nv = *(const float4*)(norm + r0);
        #pragma unroll
        for (int n = 0; n < 4; n++) {
            int cg = nbase + wn + n * 16 + l15;
            ushort4 o;
            o.x = f2b(acc[m][n][0] * nv.x);
            o.y = f2b(acc[m][n][1] * nv.y);
            o.z = f2b(acc[m][n][2] * nv.z);
            o.w = f2b(acc[m][n][3] * nv.w);
            *(ushort4*)(Tt + (size_t)cg * PITCH_T + r0) = o;
        }
    }
}

// ---------- FH = (dm @ T) * norm, stored transposed fp32 [c][row] ----------
__global__ __launch_bounds__(512) void k_adj(const ushort* __restrict__ dmb, const ushort* __restrict__ Tt,
                                             const float* __restrict__ norm, float* __restrict__ FHt) {
    __shared__ ushort lA[128 * 64];
    __shared__ ushort lB[256 * 64];
    int g = blockIdx.x;
    int tid = threadIdx.x, lane = tid & 63, wid = tid >> 6;
    int wm = (wid >> 2) * 64, wn = (wid & 3) * 64;
    int l15 = lane & 15;
    const ushort* dmg = dmb + (size_t)g * 16384;
    floatx4 zf = {0.f, 0.f, 0.f, 0.f};
    floatx4 acc[4][4];
    #pragma unroll
    for (int m = 0; m < 4; m++)
        #pragma unroll
        for (int n = 0; n < 4; n++) acc[m][n] = zf;
    for (int kb = 0; kb < 2; ++kb) {
        __syncthreads();
        stage_bf16(dmg, 128, nullptr, 0, (size_t)kb * 64, lA, 128, tid, 512);
        stage_bf16(Tt, PITCH_T, nullptr, 0, (size_t)g * 128 + kb * 64, lB, 256, tid, 512);
        __syncthreads();
        #pragma unroll
        for (int kc = 0; kc < 2; ++kc) {
            short8 a[4], b[4];
            #pragma unroll
            for (int m = 0; m < 4; m++) a[m] = frag_ld(lA, wm + m * 16 + l15, kc, lane);
            #pragma unroll
            for (int n = 0; n < 4; n++) b[n] = frag_ld(lB, wn + n * 16 + l15, kc, lane);
            #pragma unroll
            for (int m = 0; m < 4; m++)
                #pragma unroll
                for (int n = 0; n < 4; n++)
                    acc[m][n] = __builtin_amdgcn_mfma_f32_16x16x32_bf16(a[m], b[n], acc[m][n], 0, 0, 0);
        }
    }
    int r4 = (lane >> 4) * 4;
    #pragma unroll
    for (int m = 0; m < 4; m++) {
        int r0l = wm + m * 16 + r4;
        float4 nv = *(const float4*)(norm + g * 128 + r0l);
        #pragma unroll
        for (int n = 0; n < 4; n++) {
            int cg = wn + n * 16 + l15;
            float4 o;
            o.x = acc[m][n][0] * nv.x;
            o.y = acc[m][n][1] * nv.y;
            o.z = acc[m][n][2] * nv.z;
            o.w = acc[m][n][3] * nv.w;
            *(float4*)(FHt + (size_t)cg * PITCH_T + g * 128 + r0l) = o;
        }
    }
}

// ---------- combine: dual GEMM (wh, wt) + gate/elu epilogue ----------
template<int LAYER>
__global__ __launch_bounds__(512) void k_comb(const ushort* __restrict__ A, const int* __restrict__ rowmap,
                                              const ushort* __restrict__ WhT, const ushort* __restrict__ WtT,
                                              const float* __restrict__ bt, const float* __restrict__ FHt,
                                              const float* __restrict__ mf,
                                              ushort* __restrict__ outb, float* __restrict__ outf,
                                              const int* __restrict__ flatscat) {
    __shared__ ushort lA[128 * 64];
    __shared__ ushort lH[128 * 64];
    __shared__ ushort lG[128 * 64];
    int tid = threadIdx.x, lane = tid & 63, wid = tid >> 6;
    int rowbase = blockIdx.x * 128, nbase = blockIdx.y * 128;
    int wm = (wid >> 2) * 64, wn = (wid & 3) * 32;
    int l15 = lane & 15;
    floatx4 zf = {0.f, 0.f, 0.f, 0.f};
    floatx4 accH[4][2], accG[4][2];
    #pragma unroll
    for (int m = 0; m < 4; m++)
        #pragma unroll
        for (int n = 0; n < 2; n++) { accH[m][n] = zf; accG[m][n] = zf; }
    for (int kb = 0; kb < 4; ++kb) {
        __syncthreads();
        stage_bf16(A, 256, rowmap, rowbase, (size_t)kb * 64, lA, 128, tid, 512);
        stage_bf16(WhT, 256, nullptr, nbase, (size_t)kb * 64, lH, 128, tid, 512);
        stage_bf16(WtT, 256, nullptr, nbase, (size_t)kb * 64, lG, 128, tid, 512);
        __syncthreads();
        #pragma unroll
        for (int kc = 0; kc < 2; ++kc) {
            short8 a[4], bh[2], bg[2];
            #pragma unroll
            for (int m = 0; m < 4; m++) a[m] = frag_ld(lA, wm + m * 16 + l15, kc, lane);
            #pragma unroll
            for (int n = 0; n < 2; n++) {
                bh[n] = frag_ld(lH, wn + n * 16 + l15, kc, lane);
                bg[n] = frag_ld(lG, wn + n * 16 + l15, kc, lane);
            }
            #pragma unroll
            for (int m = 0; m < 4; m++)
                #pragma unroll
                for (int n = 0; n < 2; n++) {
                    accH[m][n] = __builtin_amdgcn_mfma_f32_16x16x32_bf16(a[m], bh[n], accH[m][n], 0, 0, 0);
                    accG[m][n] = __builtin_amdgcn_mfma_f32_16x16x32_bf16(a[m], bg[n], accG[m][n], 0, 0, 0);
                }
        }
    }
    int r4 = (lane >> 4) * 4;
    int base = wid * 512;
    for (int m = 0; m < 4; m++) {
        int r0l = wm + m * 16 + r4;
        int r0g = rowbase + r0l;
        float4 mv = *(const float4*)(mf + r0g);
        float mvv[4] = {mv.x, mv.y, mv.z, mv.w};
        float vals[2][4];
        #pragma unroll
        for (int n = 0; n < 2; n++) {
            int cg = nbase + wn + n * 16 + l15;
            float btc = bt[cg];
            float4 fh = *(const float4*)(FHt + (size_t)cg * PITCH_T + r0g);
            float fhv[4] = {fh.x, fh.y, fh.z, fh.w};
            #pragma unroll
            for (int i = 0; i < 4; i++) {
                float gate = 1.f / (1.f + expf(-(accG[m][n][i] + btc)));
                float het = mvv[i] * accH[m][n][i];
                float o = gate * fhv[i] + (1.f - gate) * het;
                o = (o > 0.f) ? o : expm1f(o);
                vals[n][i] = o * mvv[i];
            }
        }
        __syncthreads();
        if (LAYER == 0) {
            ushort* Ls = lA;
            #pragma unroll
            for (int n = 0; n < 2; n++)
                #pragma unroll
                for (int i = 0; i < 4; i++)
                    Ls[base + (r4 + i) * 32 + n * 16 + l15] = f2b(vals[n][i]);
            __syncthreads();
            #pragma unroll
            for (int it = 0; it < 2; ++it) {
                int lr = (lane >> 3) + it * 8;
                int lc4 = (lane & 7) * 4;
                ushort4 tv = *(const ushort4*)(Ls + base + lr * 32 + lc4);
                int rg = rowbase + wm + m * 16 + lr;
                *(ushort4*)(outb + (size_t)rg * 256 + nbase + wn + lc4) = tv;
            }
        } else {
            float* Ls = (float*)lA;
            #pragma unroll
            for (int n = 0; n < 2; n++)
                #pragma unroll
                for (int i = 0; i < 4; i++)
                    Ls[base + (r4 + i) * 32 + n * 16 + l15] = vals[n][i];
            __syncthreads();
            #pragma unroll
            for (int it = 0; it < 2; ++it) {
                int lr = (lane >> 3) + it * 8;
                int lc4 = (lane & 7) * 4;
                float4 tv = *(const float4*)(Ls + base + lr * 32 + lc4);
                int rg = rowbase + wm + m * 16 + lr;
                int dst = flatscat[rg];
                *(float4*)(outf + (size_t)dst * 256 + nbase + wn + lc4) = tv;
            }
        }
    }
}

extern "C" void kernel_launch(void* const* d_in, const int* in_sizes, int n_in,
                              void* d_out, int out_size, void* d_ws, size_t ws_size,
                              hipStream_t stream) {
    const float* x    = (const float*)d_in[0];
    const void*  msk  = d_in[1];
    const float* ln_g = (const float*)d_in[2];
    const float* ln_b = (const float*)d_in[3];
    const float* w1   = (const float*)d_in[4];
    const float* b1   = (const float*)d_in[5];
    const float* w2   = (const float*)d_in[6];
    const float* b2   = (const float*)d_in[7];
    const float* rot  = (const float*)d_in[8];
    const float* th0  = (const float*)d_in[9];
    const float* wh0  = (const float*)d_in[10];
    const float* wt0  = (const float*)d_in[11];
    const float* bt0  = (const float*)d_in[12];
    const float* th1  = (const float*)d_in[13];
    const float* wh1  = (const float*)d_in[14];
    const float* wt1  = (const float*)d_in[15];
    const float* bt1  = (const float*)d_in[16];

    char* ws = (char*)d_ws;
    float*  FHt  = (float*)(ws + OFF_FHT);
    ushort* Tt   = (ushort*)(ws + OFF_TT);
    ushort* out0 = (ushort*)(ws + OFF_OUT0);
    ushort* dmb  = (ushort*)(ws + OFF_DMB);
    ushort* wb   = (ushort*)(ws + OFF_WB);
    ushort* wbth0 = wb + 0 * 65536;
    ushort* wbwh0 = wb + 1 * 65536;
    ushort* wbwt0 = wb + 2 * 65536;
    ushort* wbth1 = wb + 3 * 65536;
    ushort* wbwh1 = wb + 4 * 65536;
    ushort* wbwt1 = wb + 5 * 65536;
    float* norm = (float*)(ws + OFF_NORM);
    float* mf   = (float*)(ws + OFF_MF);
    int*   bin  = (int*)(ws + OFF_BIN);
    int*   flat = (int*)(ws + OFF_FLAT);
    int*   mski = (int*)(ws + OFF_MSKI);
    int*   hist = (int*)(ws + OFF_HIST);
    int*   offs = (int*)(ws + OFF_OFFS);
    int*   flag = (int*)(ws + OFF_FLAG);
    int*   fixcnt = (int*)(ws + OFF_CNT);
    int*   fixlist = (int*)(ws + OFF_LIST);
    ushort* w1h = (ushort*)(ws + OFF_W1H);
    ushort* w1l = (ushort*)(ws + OFF_W1L);
    ushort* w2h = (ushort*)(ws + OFF_W2H);
    ushort* w2l = (ushort*)(ws + OFF_W2L);
    ushort* rth = (ushort*)(ws + OFF_RH);
    ushort* rtl = (ushort*)(ws + OFF_RL);
    float*  xd  = (float*)d_out;
    ushort* xnb = (ushort*)((char*)d_out + (size_t)PTS * DDIM * 4);

    hipMemsetAsync(hist, 0, HISTBYTES, stream);
    hipMemsetAsync(fixcnt, 0, 4, stream);
    k_maskflag<<<1, 256, 0, stream>>>((const int*)msk, flag);
    k_masknorm<<<PTS / 256, 256, 0, stream>>>(msk, flag, mski);
    k_wprep<<<dim3(16, 6), 256, 0, stream>>>(th0, wh0, wt0, th1, wh1, wt1,
                                             wbth0, wbwh0, wbwt0, wbth1, wbwh1, wbwt1);
    k_wsplit<<<8, 256, 0, stream>>>(w1, 256, 128, 128, 128, w1h, w1l);
    k_wsplit<<<4, 256, 0, stream>>>(w2, 128, 128, 128, 128, w2h, w2l);
    k_wsplit<<<2, 256, 0, stream>>>(rot, 128, 64, 100, 50, rth, rtl);
    k_stage1<<<PTS / 64, 512, 0, stream>>>(x, ln_g, ln_b, b1, b2,
                                           w1h, w1l, w2h, w2l, rth, rtl, mski,
                                           xnb, xd, bin, fixlist, fixcnt);
    k_fixup<<<4096, 64, 0, stream>>>(x, ln_g, ln_b, w1, b1, w2, b2, rot, mski,
                                     fixlist, fixcnt, bin);
    k_count<<<800, 128, 0, stream>>>(bin, hist);
    k_offsets<<<8, 256, 0, stream>>>(hist, offs);
    k_scatter<<<800, 128, 0, stream>>>(bin, offs, mski, flat, mf);
    k_dm<<<800, 256, 0, stream>>>(xd, flat, mf, dmb, norm);
    // layer 0
    k_proj<<<dim3(800, 2), 256, 0, stream>>>(xnb, flat, wbth0, norm, Tt);
    k_adj<<<800, 512, 0, stream>>>(dmb, Tt, norm, FHt);
    k_comb<0><<<dim3(800, 2), 512, 0, stream>>>(xnb, flat, wbwh0, wbwt0, bt0, FHt, mf, out0, nullptr, nullptr);
    // layer 1
    k_proj<<<dim3(800, 2), 256, 0, stream>>>(out0, nullptr, wbth1, norm, Tt);
    k_adj<<<800, 512, 0, stream>>>(dmb, Tt, norm, FHt);
    k_comb<1><<<dim3(800, 2), 512, 0, stream>>>(out0, nullptr, wbwh1, wbwt1, bt1, FHt, mf, nullptr, (float*)d_out, flat);
}

// Round 6
// 712.582 us; speedup vs baseline: 1.5445x; 1.2399x over previous
//
#include <hip/hip_runtime.h>
#include <math.h>

#define BB 8
#define NN 12800
#define FF 256
#define DDIM 128
#define NBINS 100
#define BSIZE 128
#define NROT 50
#define NIDS 199
#define PTS (BB*NN)            // 102400

// ---- workspace layout (bytes) ----
#define OFF_OUT0 ((size_t)157286400)    // 52428800  : out0 bf16 [102400][256]
#define OFF_DMB  ((size_t)209715200)    // 26214400  : dm bf16 [800][128][128]
#define OFF_WB   ((size_t)235929600)    // 786432    : 6 weights bf16 transposed [256][256]
#define OFF_NORM ((size_t)236716032)    // 409600
#define OFF_MF   ((size_t)237125632)    // 409600
#define OFF_BIN  ((size_t)237535232)    // 409600 (int)
#define OFF_FLAT ((size_t)237944832)    // 409600 (int)
#define OFF_MSKI ((size_t)238354432)    // 409600 (int)
#define OFF_HIST ((size_t)238764032)    // 636800 (int)
#define OFF_OFFS ((size_t)239400832)    // 636800 (int)
#define OFF_FLAG ((size_t)240037632)    // 64
#define OFF_CNT  ((size_t)240037696)    // 64
#define OFF_LIST ((size_t)240037760)    // 409600 (int)
#define OFF_W1H  ((size_t)240447360)    // 65536 : w1^T hi bf16 [128][256]
#define OFF_W1L  ((size_t)240512896)    // 65536
#define OFF_W2H  ((size_t)240578432)    // 32768 : w2^T hi bf16 [128][128]
#define OFF_W2L  ((size_t)240611200)    // 32768
#define OFF_RH   ((size_t)240643968)    // 16384 : rot^T hi bf16 [64][128]
#define OFF_RL   ((size_t)240660352)    // 16384
#define HISTBYTES (8*100*199*4)

using short8  = __attribute__((ext_vector_type(8))) short;
using floatx4 = __attribute__((ext_vector_type(4))) float;

__device__ __forceinline__ ushort f2b(float f) {
    unsigned u = __float_as_uint(f);
    unsigned r = (u + 0x7FFFu + ((u >> 16) & 1u)) >> 16;
    return (ushort)r;
}
__device__ __forceinline__ float b2f(ushort h) {
    return __uint_as_float(((unsigned)h) << 16);
}
__device__ __forceinline__ uint4 pack8(const ushort* o) {
    uint4 u;
    u.x = (unsigned)o[0] | ((unsigned)o[1] << 16);
    u.y = (unsigned)o[2] | ((unsigned)o[3] << 16);
    u.z = (unsigned)o[4] | ((unsigned)o[5] << 16);
    u.w = (unsigned)o[6] | ((unsigned)o[7] << 16);
    return u;
}

// ---------- mask dtype sniffing ----------
__global__ void k_maskflag(const int* mi, int* flag) {
    __shared__ int notInt, notFloat;
    if (threadIdx.x == 0) { notInt = 0; notFloat = 0; }
    __syncthreads();
    int v = mi[threadIdx.x];
    if (v != 0 && v != 1) atomicOr(&notInt, 1);
    if (v != 0 && v != 0x3F800000) atomicOr(&notFloat, 1);
    __syncthreads();
    if (threadIdx.x == 0) flag[0] = (!notInt) ? 0 : ((!notFloat) ? 2 : 1);
}

__global__ void k_masknorm(const void* msk, const int* flag, int* mski) {
    int i = blockIdx.x * blockDim.x + threadIdx.x;
    if (i >= PTS) return;
    int f = flag[0];
    int v;
    if (f == 0)      v = ((const int*)msk)[i] != 0;
    else if (f == 2) v = ((const float*)msk)[i] != 0.0f;
    else             v = ((const unsigned char*)msk)[i] != 0;
    mski[i] = v;
}

// ---------- weight prep: fp32 [k][n] -> bf16 transposed [n][k] (GHConv weights) ----------
__global__ __launch_bounds__(256) void k_wprep(
    const float* s0, const float* s1, const float* s2,
    const float* s3, const float* s4, const float* s5,
    ushort* d0, ushort* d1, ushort* d2, ushort* d3, ushort* d4, ushort* d5)
{
    __shared__ float Ls[64 * 65];
    const float* src; ushort* dst;
    switch (blockIdx.y) {
        case 0: src = s0; dst = d0; break;
        case 1: src = s1; dst = d1; break;
        case 2: src = s2; dst = d2; break;
        case 3: src = s3; dst = d3; break;
        case 4: src = s4; dst = d4; break;
        default: src = s5; dst = d5; break;
    }
    int t = blockIdx.x;
    int kb = (t & 3) * 64, nb = (t >> 2) * 64;
    int tid = threadIdx.x;
    for (int q = 0; q < 4; ++q) {
        int g = q * 256 + tid;
        int kl = g >> 4, f4 = g & 15;
        float4 v = *(const float4*)(src + (size_t)(kb + kl) * 256 + nb + f4 * 4);
        Ls[kl * 65 + f4 * 4 + 0] = v.x;
        Ls[kl * 65 + f4 * 4 + 1] = v.y;
        Ls[kl * 65 + f4 * 4 + 2] = v.z;
        Ls[kl * 65 + f4 * 4 + 3] = v.w;
    }
    __syncthreads();
    for (int q = 0; q < 2; ++q) {
        int g = q * 256 + tid;
        int nl = g >> 3, wg = g & 7;
        ushort o[8];
        #pragma unroll
        for (int c = 0; c < 8; ++c) o[c] = f2b(Ls[(wg * 8 + c) * 65 + nl]);
        *(uint4*)(dst + (size_t)(nb + nl) * 256 + kb + wg * 8) = pack8(o);
    }
}

// ---------- split-weight prep: fp32 [K][srcN] -> hi/lo bf16 transposed [N][K] ----------
__global__ __launch_bounds__(256) void k_wsplit(const float* __restrict__ src, int K, int N,
                                               int srcN, int nvalid,
                                               ushort* __restrict__ dh, ushort* __restrict__ dl) {
    __shared__ float Ls[64 * 65];
    int tilesN = N >> 6;
    int kb = (blockIdx.x / tilesN) * 64, nb = (blockIdx.x % tilesN) * 64;
    int tid = threadIdx.x;
    for (int q = 0; q < 4; ++q) {
        int g = q * 256 + tid;
        int kl = g >> 4, c4 = (g & 15) * 4;
        #pragma unroll
        for (int j = 0; j < 4; ++j) {
            int n = nb + c4 + j;
            float v = (n < nvalid) ? src[(size_t)(kb + kl) * srcN + n] : 0.f;
            Ls[kl * 65 + c4 + j] = v;
        }
    }
    __syncthreads();
    for (int q = 0; q < 2; ++q) {
        int g = q * 256 + tid;
        int nl = g >> 3, wg = g & 7;
        ushort oh[8], ol[8];
        #pragma unroll
        for (int c = 0; c < 8; ++c) {
            float v = Ls[(wg * 8 + c) * 65 + nl];
            ushort h = f2b(v);
            oh[c] = h;
            ol[c] = f2b(v - b2f(h));
        }
        *(uint4*)(dh + (size_t)(nb + nl) * K + kb + wg * 8) = pack8(oh);
        *(uint4*)(dl + (size_t)(nb + nl) * K + kb + wg * 8) = pack8(ol);
    }
}

// ---------- MFMA LDS helpers (layout verified in rounds 2-5) ----------
__device__ __forceinline__ void stage_bf16(const ushort* __restrict__ src, size_t pitch,
                                           const int* __restrict__ rowmap, int rowbase, size_t kbase,
                                           ushort* lds, int nrows, int tid, int nthr) {
    int total = nrows * 8;
    for (int g = tid; g < total; g += nthr) {
        int row = g >> 3, wg = g & 7;
        size_t srow = rowmap ? (size_t)rowmap[rowbase + row] : (size_t)(rowbase + row);
        uint4 v = *(const uint4*)(src + srow * pitch + kbase + wg * 8);
        int w0 = (wg * 4) ^ ((row & 7) << 2);
        *(uint4*)((char*)lds + row * 128 + w0 * 4) = v;
    }
}

__device__ __forceinline__ short8 frag_ld(const ushort* lds, int row, int kc, int lane) {
    int w0 = (kc * 16 + ((lane >> 4) << 2)) ^ ((row & 7) << 2);
    return *(const short8*)((const char*)lds + row * 128 + w0 * 4);
}

// ---------- stage 1 v3: fused LN + FFN + rot via split-bf16 MFMA ----------
__global__ __launch_bounds__(512) void k_stage1(
    const float* __restrict__ x, const float* __restrict__ g, const float* __restrict__ be,
    const float* __restrict__ b1, const float* __restrict__ b2,
    const ushort* __restrict__ w1h, const ushort* __restrict__ w1l,
    const ushort* __restrict__ w2h, const ushort* __restrict__ w2l,
    const ushort* __restrict__ rth, const ushort* __restrict__ rtl,
    const int* __restrict__ mski,
    ushort* __restrict__ xn_out, float* __restrict__ xd_out, int* __restrict__ bin_out,
    int* __restrict__ fixlist, int* __restrict__ fixcnt)
{
    __shared__ ushort lXh[4 * 64 * 64];
    __shared__ ushort lXl[4 * 64 * 64];
    __shared__ ushort lWh[2][128 * 64];
    __shared__ ushort lWl[2][128 * 64];
    int tid = threadIdx.x, lane = tid & 63, wid = tid >> 6;
    int base = blockIdx.x * 64;
    int l15 = lane & 15;
    int r4 = (lane >> 4) * 4;

    stage_bf16(w1h, 256, nullptr, 0, 0, lWh[0], 128, tid, 512);
    stage_bf16(w1l, 256, nullptr, 0, 0, lWl[0], 128, tid, 512);

    {   // phase 0: LN (8 threads/point)
        int row = tid >> 3, sub = tid & 7;
        const float* xr = x + (size_t)(base + row) * FF + sub * 32;
        float v[32];
        float s = 0.f;
        #pragma unroll
        for (int q = 0; q < 8; ++q) {
            float4 f = *(const float4*)(xr + q * 4);
            v[q*4+0] = f.x; v[q*4+1] = f.y; v[q*4+2] = f.z; v[q*4+3] = f.w;
            s += f.x + f.y + f.z + f.w;
        }
        s += __shfl_xor(s, 1, 8); s += __shfl_xor(s, 2, 8); s += __shfl_xor(s, 4, 8);
        float mu = s * (1.f / 256.f);
        float s2 = 0.f;
        #pragma unroll
        for (int q = 0; q < 32; ++q) { float d = v[q] - mu; s2 += d * d; }
        s2 += __shfl_xor(s2, 1, 8); s2 += __shfl_xor(s2, 2, 8); s2 += __shfl_xor(s2, 4, 8);
        float rs = 1.0f / sqrtf(s2 * (1.f / 256.f) + 1e-6f);
        int kb = sub >> 1;
        ushort* xo = xn_out + (size_t)(base + row) * FF + sub * 32;
        #pragma unroll
        for (int j = 0; j < 4; ++j) {
            int i0 = sub * 32 + j * 8;
            float4 g0 = *(const float4*)(g + i0);
            float4 g1 = *(const float4*)(g + i0 + 4);
            float4 e0 = *(const float4*)(be + i0);
            float4 e1 = *(const float4*)(be + i0 + 4);
            float gv[8] = {g0.x,g0.y,g0.z,g0.w,g1.x,g1.y,g1.z,g1.w};
            float ev[8] = {e0.x,e0.y,e0.z,e0.w,e1.x,e1.y,e1.z,e1.w};
            ushort hh[8], ll[8];
            #pragma unroll
            for (int c = 0; c < 8; ++c) {
                float xv = (v[j*8+c] - mu) * rs * gv[c] + ev[c];
                ushort h = f2b(xv);
                hh[c] = h;
                ll[c] = f2b(xv - b2f(h));
            }
            uint4 uh = pack8(hh), ul = pack8(ll);
            *(uint4*)(xo + j * 8) = uh;
            int wg = (sub & 1) * 4 + j;
            int w0 = (wg * 4) ^ ((row & 7) << 2);
            *(uint4*)((char*)lXh + kb * 8192 + row * 128 + w0 * 4) = uh;
            *(uint4*)((char*)lXl + kb * 8192 + row * 128 + w0 * 4) = ul;
        }
    }
    __syncthreads();

    int wm = (wid >> 2) * 32, wn = (wid & 3) * 32;
    floatx4 zf = {0.f, 0.f, 0.f, 0.f};

    // GEMM1: h = elu(xn @ w1 + b1)
    floatx4 acc[2][2];
    #pragma unroll
    for (int m = 0; m < 2; m++)
        #pragma unroll
        for (int n = 0; n < 2; n++) acc[m][n] = zf;
    for (int kb = 0; kb < 4; ++kb) {
        if (kb < 3) {
            stage_bf16(w1h, 256, nullptr, 0, (size_t)(kb + 1) * 64, lWh[(kb + 1) & 1], 128, tid, 512);
            stage_bf16(w1l, 256, nullptr, 0, (size_t)(kb + 1) * 64, lWl[(kb + 1) & 1], 128, tid, 512);
        }
        #pragma unroll
        for (int kc = 0; kc < 2; ++kc) {
            short8 ah[2], al[2], bh[2], bl[2];
            #pragma unroll
            for (int m = 0; m < 2; m++) {
                ah[m] = frag_ld(lXh + kb * 4096, wm + m * 16 + l15, kc, lane);
                al[m] = frag_ld(lXl + kb * 4096, wm + m * 16 + l15, kc, lane);
            }
            #pragma unroll
            for (int n = 0; n < 2; n++) {
                bh[n] = frag_ld(lWh[kb & 1], wn + n * 16 + l15, kc, lane);
                bl[n] = frag_ld(lWl[kb & 1], wn + n * 16 + l15, kc, lane);
            }
            #pragma unroll
            for (int m = 0; m < 2; m++)
                #pragma unroll
                for (int n = 0; n < 2; n++) {
                    acc[m][n] = __builtin_amdgcn_mfma_f32_16x16x32_bf16(ah[m], bh[n], acc[m][n], 0, 0, 0);
                    acc[m][n] = __builtin_amdgcn_mfma_f32_16x16x32_bf16(ah[m], bl[n], acc[m][n], 0, 0, 0);
                    acc[m][n] = __builtin_amdgcn_mfma_f32_16x16x32_bf16(al[m], bh[n], acc[m][n], 0, 0, 0);
                }
        }
        __syncthreads();
    }
    stage_bf16(w2h, 128, nullptr, 0, 0, lWh[0], 128, tid, 512);
    stage_bf16(w2l, 128, nullptr, 0, 0, lWl[0], 128, tid, 512);
    {
        #pragma unroll
        for (int n = 0; n < 2; n++) {
            int cg = wn + n * 16 + l15;
            float b1v = b1[cg];
            int slab = cg >> 6, c64 = cg & 63;
            int wg = c64 >> 3, e = c64 & 7;
            #pragma unroll
            for (int m = 0; m < 2; m++) {
                #pragma unroll
                for (int i = 0; i < 4; i++) {
                    int r = wm + m * 16 + r4 + i;
                    float hv = acc[m][n][i] + b1v;
                    hv = (hv > 0.f) ? hv : expm1f(hv);
                    ushort h = f2b(hv);
                    int w0 = (wg * 4) ^ ((r & 7) << 2);
                    int idx = slab * 4096 + r * 64 + w0 * 2 + e;
                    lXh[idx] = h;
                    lXl[idx] = f2b(hv - b2f(h));
                }
            }
        }
    }
    __syncthreads();

    // GEMM2: xd = h @ w2 + b2
    floatx4 acc2[2][2];
    #pragma unroll
    for (int m = 0; m < 2; m++)
        #pragma unroll
        for (int n = 0; n < 2; n++) acc2[m][n] = zf;
    for (int kb = 0; kb < 2; ++kb) {
        if (kb == 0) {
            stage_bf16(w2h, 128, nullptr, 0, 64, lWh[1], 128, tid, 512);
            stage_bf16(w2l, 128, nullptr, 0, 64, lWl[1], 128, tid, 512);
        }
        #pragma unroll
        for (int kc = 0; kc < 2; ++kc) {
            short8 ah[2], al[2], bh[2], bl[2];
            #pragma unroll
            for (int m = 0; m < 2; m++) {
                ah[m] = frag_ld(lXh + kb * 4096, wm + m * 16 + l15, kc, lane);
                al[m] = frag_ld(lXl + kb * 4096, wm + m * 16 + l15, kc, lane);
            }
            #pragma unroll
            for (int n = 0; n < 2; n++) {
                bh[n] = frag_ld(lWh[kb], wn + n * 16 + l15, kc, lane);
                bl[n] = frag_ld(lWl[kb], wn + n * 16 + l15, kc, lane);
            }
            #pragma unroll
            for (int m = 0; m < 2; m++)
                #pragma unroll
                for (int n = 0; n < 2; n++) {
                    acc2[m][n] = __builtin_amdgcn_mfma_f32_16x16x32_bf16(ah[m], bh[n], acc2[m][n], 0, 0, 0);
                    acc2[m][n] = __builtin_amdgcn_mfma_f32_16x16x32_bf16(ah[m], bl[n], acc2[m][n], 0, 0, 0);
                    acc2[m][n] = __builtin_amdgcn_mfma_f32_16x16x32_bf16(al[m], bh[n], acc2[m][n], 0, 0, 0);
                }
        }
        __syncthreads();
    }
    stage_bf16(rth, 128, nullptr, 0, 0, lWh[0], 64, tid, 512);
    stage_bf16(rtl, 128, nullptr, 0, 0, lWl[0], 64, tid, 512);
    stage_bf16(rth, 128, nullptr, 0, 64, lWh[1], 64, tid, 512);
    stage_bf16(rtl, 128, nullptr, 0, 64, lWl[1], 64, tid, 512);
    {
        #pragma unroll
        for (int n = 0; n < 2; n++) {
            int cg = wn + n * 16 + l15;
            float b2v = b2[cg];
            int slab = 2 + (cg >> 6), c64 = cg & 63;
            int wg = c64 >> 3, e = c64 & 7;
            #pragma unroll
            for (int m = 0; m < 2; m++) {
                #pragma unroll
                for (int i = 0; i < 4; i++) {
                    int r = wm + m * 16 + r4 + i;
                    float xv = acc2[m][n][i] + b2v;
                    xd_out[(size_t)(base + r) * DDIM + cg] = xv;
                    ushort h = f2b(xv);
                    int w0 = (wg * 4) ^ ((r & 7) << 2);
                    int idx = slab * 4096 + r * 64 + w0 * 2 + e;
                    lXh[idx] = h;
                    lXl[idx] = f2b(xv - b2f(h));
                }
            }
        }
    }
    __syncthreads();

    // GEMM3: mul = xd @ rot
    floatx4 acc3[2];
    acc3[0] = zf; acc3[1] = zf;
    int wm3 = (wid >> 2) * 32, wn3 = (wid & 3) * 16;
    for (int kb = 0; kb < 2; ++kb) {
        #pragma unroll
        for (int kc = 0; kc < 2; ++kc) {
            short8 ah[2], al[2], bh, bl;
            #pragma unroll
            for (int m = 0; m < 2; m++) {
                ah[m] = frag_ld(lXh + (2 + kb) * 4096, wm3 + m * 16 + l15, kc, lane);
                al[m] = frag_ld(lXl + (2 + kb) * 4096, wm3 + m * 16 + l15, kc, lane);
            }
            bh = frag_ld(lWh[kb], wn3 + l15, kc, lane);
            bl = frag_ld(lWl[kb], wn3 + l15, kc, lane);
            #pragma unroll
            for (int m = 0; m < 2; m++) {
                acc3[m] = __builtin_amdgcn_mfma_f32_16x16x32_bf16(ah[m], bh, acc3[m], 0, 0, 0);
                acc3[m] = __builtin_amdgcn_mfma_f32_16x16x32_bf16(ah[m], bl, acc3[m], 0, 0, 0);
                acc3[m] = __builtin_amdgcn_mfma_f32_16x16x32_bf16(al[m], bh, acc3[m], 0, 0, 0);
            }
        }
    }
    __syncthreads();
    float* lMul = (float*)(&lWh[0][0]);
    {
        #pragma unroll
        for (int m = 0; m < 2; m++)
            #pragma unroll
            for (int i = 0; i < 4; i++) {
                int r = wm3 + m * 16 + r4 + i;
                lMul[r * 65 + wn3 + l15] = acc3[m][i];
            }
    }
    __syncthreads();

    {   // top-2 argmax over [mul, -mul], margin flag
        int p = tid >> 3, q = tid & 7;
        float v1 = -1e30f, v2 = -1e30f; int i1 = 1 << 29;
        #pragma unroll
        for (int j = 0; j < 8; ++j) {
            int c = q * 8 + j;
            if (c < 50) {
                float m = lMul[p * 65 + c];
                float wv, lv; int wi, li;
                if (m >= 0.f) { wv = m; wi = c; lv = -m; li = 50 + c; }
                else          { wv = -m; wi = 50 + c; lv = m; li = c; }
                if (wv > v1 || (wv == v1 && wi < i1)) { v2 = v1; v1 = wv; i1 = wi; }
                else if (wv > v2) v2 = wv;
                if (lv > v1 || (lv == v1 && li < i1)) { v2 = v1; v1 = lv; i1 = li; }
                else if (lv > v2) v2 = lv;
            }
        }
        #pragma unroll
        for (int off = 1; off < 8; off <<= 1) {
            float o1 = __shfl_xor(v1, off, 8);
            int   oi = __shfl_xor(i1, off, 8);
            float o2 = __shfl_xor(v2, off, 8);
            bool take = (o1 > v1) || (o1 == v1 && oi < i1);
            float small = take ? v1 : o1;
            if (take) { v1 = o1; i1 = oi; }
            v2 = fmaxf(fmaxf(v2, o2), small);
        }
        if (q == 0) {
            int pt = base + p;
            bin_out[pt] = i1 + (mski[pt] ? 0 : (NBINS - 1));
            float tau = 3e-4f + 1.5e-3f * v1;
            if (v1 - v2 < tau) {
                int pos = atomicAdd(fixcnt, 1);
                fixlist[pos] = pt;
            }
        }
    }
}

// ---------- fp64 fixup for margin-flagged points ----------
__global__ __launch_bounds__(64) void k_fixup(
    const float* __restrict__ x, const float* __restrict__ g, const float* __restrict__ be,
    const float* __restrict__ w1, const float* __restrict__ b1,
    const float* __restrict__ w2, const float* __restrict__ b2,
    const float* __restrict__ rot, const int* __restrict__ mski,
    const int* __restrict__ fixlist, const int* __restrict__ fixcnt,
    int* __restrict__ bin_out)
{
    __shared__ double xn_s[256];
    __shared__ double h_s[128];
    __shared__ double xd_s[128];
    int lane = threadIdx.x;
    int n = fixcnt[0];
    for (int e = blockIdx.x; e < n; e += gridDim.x) {
        int pt = fixlist[e];
        const float* xr = x + (size_t)pt * FF;
        double s = 0.0, xv[4];
        #pragma unroll
        for (int q = 0; q < 4; q++) { xv[q] = (double)xr[lane + q * 64]; s += xv[q]; }
        #pragma unroll
        for (int off = 1; off < 64; off <<= 1) s += __shfl_xor(s, off, 64);
        double mu = s * (1.0 / 256.0);
        double s2 = 0.0;
        #pragma unroll
        for (int q = 0; q < 4; q++) { double d = xv[q] - mu; s2 += d * d; }
        #pragma unroll
        for (int off = 1; off < 64; off <<= 1) s2 += __shfl_xor(s2, off, 64);
        double rs = 1.0 / sqrt(s2 * (1.0 / 256.0) + 1e-6);
        #pragma unroll
        for (int q = 0; q < 4; q++) {
            int i = lane + q * 64;
            xn_s[i] = (xv[q] - mu) * rs * (double)g[i] + (double)be[i];
        }
        __syncthreads();
        #pragma unroll
        for (int q = 0; q < 2; q++) {
            int j = lane + q * 64;
            double a0 = 0.0, a1 = 0.0;
            for (int k = 0; k < FF; k += 2) {
                a0 += xn_s[k] * (double)w1[k * DDIM + j];
                a1 += xn_s[k + 1] * (double)w1[(k + 1) * DDIM + j];
            }
            double a = (double)b1[j] + a0 + a1;
            h_s[j] = (a > 0.0) ? a : expm1(a);
        }
        __syncthreads();
        #pragma unroll
        for (int q = 0; q < 2; q++) {
            int j = lane + q * 64;
            double a0 = 0.0, a1 = 0.0;
            for (int k = 0; k < DDIM; k += 2) {
                a0 += h_s[k] * (double)w2[k * DDIM + j];
                a1 += h_s[k + 1] * (double)w2[(k + 1) * DDIM + j];
            }
            xd_s[j] = (double)b2[j] + a0 + a1;
        }
        __syncthreads();
        double v; int idx;
        if (lane < NROT) {
            double m = 0.0;
            for (int k = 0; k < DDIM; k++) m += xd_s[k] * (double)rot[k * 100 + lane];
            if (m >= 0.0) { v = m; idx = lane; } else { v = -m; idx = 50 + lane; }
        } else { v = -1e300; idx = 1 << 29; }
        #pragma unroll
        for (int off = 1; off < 64; off <<= 1) {
            double ov = __shfl_xor(v, off, 64);
            int oi = __shfl_xor(idx, off, 64);
            if (ov > v || (ov == v && oi < idx)) { v = ov; idx = oi; }
        }
        if (lane == 0) bin_out[pt] = idx + (mski[pt] ? 0 : (NBINS - 1));
        __syncthreads();
    }
}

// ---------- binning: stable counting sort ----------
__global__ void k_count(const int* __restrict__ bin, int* __restrict__ hist) {
    int c = blockIdx.x % 100, b = blockIdx.x / 100;
    int t = threadIdx.x;
    int v = bin[b * NN + c * BSIZE + t];
    atomicAdd(&hist[(b * 100 + c) * NIDS + v], 1);
}

__global__ void k_offsets(const int* __restrict__ hist, int* __restrict__ offs) {
    __shared__ int tot[NIDS];
    __shared__ int start[NIDS];
    int b = blockIdx.x, v = threadIdx.x;
    if (v < NIDS) {
        int s = 0;
        for (int c = 0; c < 100; c++) s += hist[(b * 100 + c) * NIDS + v];
        tot[v] = s;
    }
    __syncthreads();
    if (threadIdx.x == 0) {
        int run = 0;
        for (int i = 0; i < NIDS; i++) { start[i] = run; run += tot[i]; }
    }
    __syncthreads();
    if (v < NIDS) {
        int run = start[v];
        for (int c = 0; c < 100; c++) {
            offs[(b * 100 + c) * NIDS + v] = run;
            run += hist[(b * 100 + c) * NIDS + v];
        }
    }
}

__global__ void k_scatter(const int* __restrict__ bin, const int* __restrict__ offs,
                          const int* __restrict__ mski, int* __restrict__ flat,
                          float* __restrict__ mf) {
    __shared__ int sv[BSIZE];
    int c = blockIdx.x % 100, b = blockIdx.x / 100;
    int t = threadIdx.x;
    int n = c * BSIZE + t;
    int v = bin[b * NN + n];
    sv[t] = v;
    __syncthreads();
    int rank = 0;
    for (int u = 0; u < t; u++) rank += (sv[u] == v);
    int r = offs[(b * 100 + c) * NIDS + v] + rank;
    flat[b * NN + r] = b * NN + n;
    mf[b * NN + r] = mski[b * NN + n] ? 1.0f : 0.0f;
}

// ---------- per-bin pairwise kernel matrix (fp32 tiled), fused deg/norm ----------
__global__ __launch_bounds__(256) void k_dm(const float* __restrict__ xd, const int* __restrict__ flat,
                                            const float* __restrict__ mf, ushort* __restrict__ dmb,
                                            float* __restrict__ norm) {
    __shared__ float Xs[128 * 64];
    __shared__ float na[128];
    __shared__ float ml[128];
    __shared__ float ps[128 * 16];
    int g = blockIdx.x, tid = threadIdx.x;
    int tx = tid & 15, ty = tid >> 4;
    int rowbase = g * 128;
    if (tid < 128) ml[tid] = mf[rowbase + tid];
    float acc[8][8];
    #pragma unroll
    for (int i = 0; i < 8; i++)
        #pragma unroll
        for (int j = 0; j < 8; j++) acc[i][j] = 0.f;
    float nap[8];
    #pragma unroll
    for (int j = 0; j < 8; j++) nap[j] = 0.f;

    for (int kh = 0; kh < 2; ++kh) {
        __syncthreads();
        for (int q = 0; q < 8; ++q) {
            int gg = q * 256 + tid;
            int row = gg >> 4, f4 = gg & 15;
            int srow = flat[rowbase + row];
            float4 v = *(const float4*)(xd + (size_t)srow * DDIM + kh * 64 + f4 * 4);
            int f4s = f4 ^ ((row >> 3) & 7);
            *(float4*)(Xs + row * 64 + f4s * 4) = v;
        }
        __syncthreads();
        for (int k4 = 0; k4 < 16; ++k4) {
            int sa = (k4 ^ (ty & 7)) << 2;
            int sb = (k4 ^ (tx & 7)) << 2;
            float4 av[8], bv[8];
            #pragma unroll
            for (int i = 0; i < 8; i++) av[i] = *(const float4*)(Xs + (ty * 8 + i) * 64 + sa);
            #pragma unroll
            for (int j = 0; j < 8; j++) bv[j] = *(const float4*)(Xs + (tx * 8 + j) * 64 + sb);
            if (ty == 0) {
                #pragma unroll
                for (int j = 0; j < 8; j++)
                    nap[j] += bv[j].x * bv[j].x + bv[j].y * bv[j].y + bv[j].z * bv[j].z + bv[j].w * bv[j].w;
            }
            #pragma unroll
            for (int i = 0; i < 8; i++)
                #pragma unroll
                for (int j = 0; j < 8; j++)
                    acc[i][j] += av[i].x * bv[j].x + av[i].y * bv[j].y + av[i].z * bv[j].z + av[i].w * bv[j].w;
        }
    }
    if (ty == 0) {
        #pragma unroll
        for (int j = 0; j < 8; j++) na[tx * 8 + j] = nap[j];
    }
    __syncthreads();
    #pragma unroll
    for (int i = 0; i < 8; ++i) {
        int r = ty * 8 + i;
        float nai = na[r], mi = ml[r];
        float rs = 0.f;
        ushort o[8];
        #pragma unroll
        for (int j = 0; j < 8; ++j) {
            int c = tx * 8 + j;
            float D2 = nai - 2.f * acc[i][j] + na[c];
            float dv = expf(-0.1f * sqrtf(fmaxf(D2, 1e-6f)));
            dv *= mi * ml[c];
            rs += dv;
            o[j] = f2b(dv);
        }
        *(uint4*)(dmb + (size_t)g * 16384 + r * 128 + tx * 8) = pack8(o);
        ps[r * 16 + tx] = rs;
    }
    __syncthreads();
    if (tid < 128) {
        float deg = 0.f;
        for (int t2 = 0; t2 < 16; ++t2) deg += ps[tid * 16 + t2];
        deg = fminf(deg, 1000.0f);
        float nv = 1.0f / sqrtf(deg + 1e-6f);
        norm[rowbase + tid] = nv * ml[tid];
    }
}

// ---------- fused per-layer graph conv: T=(A@Th)*norm ; FH=(dm@T)*norm ; comb ----------
// block = (bin g, n-half). 512 threads, 8 warps (2 row-groups x 4 col-groups of 32).
template<int LAYER>
__global__ __launch_bounds__(512) void k_layer(
    const ushort* __restrict__ A, const int* __restrict__ rowmap,
    const ushort* __restrict__ ThT, const ushort* __restrict__ WhT, const ushort* __restrict__ WtT,
    const float* __restrict__ bt, const ushort* __restrict__ dmb,
    const float* __restrict__ norm, const float* __restrict__ mf,
    ushort* __restrict__ outb, float* __restrict__ outf, const int* __restrict__ flatscat)
{
    __shared__ ushort lT[2 * 8192];      // 32KB : T^T [c][j] swizzled, 2 j-slabs
    __shared__ ushort lA[2][8192];       // 32KB : A slabs ping
    __shared__ ushort lW[4][8192];       // 64KB : P: th ping in [0],[2], dm in [1],[3]; C: wh [0],[1], wt [2],[3]
    int tid = threadIdx.x, lane = tid & 63, wid = tid >> 6;
    int g = blockIdx.x, nh = blockIdx.y;
    int rowbase = g * 128, nbase = nh * 128;
    int l15 = lane & 15;
    int r4 = (lane >> 4) * 4;
    int wm = (wid >> 2) * 64, wn = (wid & 3) * 32;
    const ushort* dmg = dmb + (size_t)g * 16384;
    floatx4 zf = {0.f, 0.f, 0.f, 0.f};

    // prologue staging: A slab0, th slab0, dm (both slabs)
    stage_bf16(A, 256, rowmap, rowbase, 0, lA[0], 128, tid, 512);
    stage_bf16(ThT, 256, nullptr, nbase, 0, lW[0], 128, tid, 512);
    stage_bf16(dmg, 128, nullptr, 0, 0, lW[1], 128, tid, 512);
    stage_bf16(dmg, 128, nullptr, 0, 64, lW[3], 128, tid, 512);
    __syncthreads();

    // ---- phase P: T = (A@Th)*norm, M=128 N=128 K=256 ----
    floatx4 accP[4][2];
    #pragma unroll
    for (int m = 0; m < 4; m++) { accP[m][0] = zf; accP[m][1] = zf; }
    for (int kb = 0; kb < 4; ++kb) {
        if (kb < 3) {
            stage_bf16(A, 256, rowmap, rowbase, (size_t)(kb + 1) * 64, lA[(kb + 1) & 1], 128, tid, 512);
            stage_bf16(ThT, 256, nullptr, nbase, (size_t)(kb + 1) * 64, lW[((kb + 1) & 1) * 2], 128, tid, 512);
        }
        #pragma unroll
        for (int kc = 0; kc < 2; ++kc) {
            short8 a[4], b[2];
            #pragma unroll
            for (int m = 0; m < 4; m++) a[m] = frag_ld(lA[kb & 1], wm + m * 16 + l15, kc, lane);
            #pragma unroll
            for (int n = 0; n < 2; n++) b[n] = frag_ld(lW[(kb & 1) * 2], wn + n * 16 + l15, kc, lane);
            #pragma unroll
            for (int m = 0; m < 4; m++)
                #pragma unroll
                for (int n = 0; n < 2; n++)
                    accP[m][n] = __builtin_amdgcn_mfma_f32_16x16x32_bf16(a[m], b[n], accP[m][n], 0, 0, 0);
        }
        __syncthreads();
    }
    // epilogue P: T^T (bf16, frag-swizzled) into lT; prefetch phase-C slab0s
    {
        #pragma unroll
        for (int m = 0; m < 4; m++) {
            float4 nv = *(const float4*)(norm + rowbase + wm + m * 16 + r4);
            float nvv[4] = {nv.x, nv.y, nv.z, nv.w};
            #pragma unroll
            for (int n = 0; n < 2; n++) {
                int cloc = wn + n * 16 + l15;
                #pragma unroll
                for (int i = 0; i < 4; i++) {
                    int jloc = wm + m * 16 + r4 + i;
                    ushort tv = f2b(accP[m][n][i] * nvv[i]);
                    int jb = jloc >> 6, jj = jloc & 63;
                    int sw = (jj >> 1) ^ ((cloc & 7) << 2);
                    *(ushort*)((char*)lT + jb * 16384 + cloc * 128 + sw * 4 + (jj & 1) * 2) = tv;
                }
            }
        }
    }
    stage_bf16(WhT, 256, nullptr, nbase, 0, lW[0], 128, tid, 512);
    stage_bf16(WtT, 256, nullptr, nbase, 0, lW[2], 128, tid, 512);
    stage_bf16(A, 256, rowmap, rowbase, 0, lA[0], 128, tid, 512);
    __syncthreads();

    // ---- phase A: FH = dm @ T, M=128 N=128 K=128 (dm in lW[1],[3]) ----
    floatx4 accFH[4][2];
    #pragma unroll
    for (int m = 0; m < 4; m++) { accFH[m][0] = zf; accFH[m][1] = zf; }
    for (int kb = 0; kb < 2; ++kb) {
        #pragma unroll
        for (int kc = 0; kc < 2; ++kc) {
            short8 a[4], b[2];
            #pragma unroll
            for (int m = 0; m < 4; m++) a[m] = frag_ld(lW[1 + kb * 2], wm + m * 16 + l15, kc, lane);
            #pragma unroll
            for (int n = 0; n < 2; n++) b[n] = frag_ld(lT + kb * 8192, wn + n * 16 + l15, kc, lane);
            #pragma unroll
            for (int m = 0; m < 4; m++)
                #pragma unroll
                for (int n = 0; n < 2; n++)
                    accFH[m][n] = __builtin_amdgcn_mfma_f32_16x16x32_bf16(a[m], b[n], accFH[m][n], 0, 0, 0);
        }
    }
    __syncthreads();

    // ---- phase C: H = A@Wh, G = A@Wt, M=128 N=128 K=256 ----
    floatx4 accH[4][2], accG[4][2];
    #pragma unroll
    for (int m = 0; m < 4; m++) {
        accH[m][0] = zf; accH[m][1] = zf;
        accG[m][0] = zf; accG[m][1] = zf;
    }
    for (int kb = 0; kb < 4; ++kb) {
        if (kb < 3) {
            stage_bf16(A, 256, rowmap, rowbase, (size_t)(kb + 1) * 64, lA[(kb + 1) & 1], 128, tid, 512);
            stage_bf16(WhT, 256, nullptr, nbase, (size_t)(kb + 1) * 64, lW[(kb + 1) & 1], 128, tid, 512);
            stage_bf16(WtT, 256, nullptr, nbase, (size_t)(kb + 1) * 64, lW[2 + ((kb + 1) & 1)], 128, tid, 512);
        }
        #pragma unroll
        for (int kc = 0; kc < 2; ++kc) {
            short8 a[4], bh[2], bg[2];
            #pragma unroll
            for (int m = 0; m < 4; m++) a[m] = frag_ld(lA[kb & 1], wm + m * 16 + l15, kc, lane);
            #pragma unroll
            for (int n = 0; n < 2; n++) {
                bh[n] = frag_ld(lW[kb & 1], wn + n * 16 + l15, kc, lane);
                bg[n] = frag_ld(lW[2 + (kb & 1)], wn + n * 16 + l15, kc, lane);
            }
            #pragma unroll
            for (int m = 0; m < 4; m++)
                #pragma unroll
                for (int n = 0; n < 2; n++) {
                    accH[m][n] = __builtin_amdgcn_mfma_f32_16x16x32_bf16(a[m], bh[n], accH[m][n], 0, 0, 0);
                    accG[m][n] = __builtin_amdgcn_mfma_f32_16x16x32_bf16(a[m], bg[n], accG[m][n], 0, 0, 0);
                }
        }
        __syncthreads();
    }

    // ---- epilogue: gate/elu combine + coalesced store (bounce via lA) ----
    int bbase = wid * 512;
    for (int m = 0; m < 4; m++) {
        int r0l = wm + m * 16 + r4;
        int r0g = rowbase + r0l;
        float4 mv = *(const float4*)(mf + r0g);
        float4 nv = *(const float4*)(norm + r0g);
        float mvv[4] = {mv.x, mv.y, mv.z, mv.w};
        float nvv[4] = {nv.x, nv.y, nv.z, nv.w};
        float vals[2][4];
        #pragma unroll
        for (int n = 0; n < 2; n++) {
            int cg = nbase + wn + n * 16 + l15;
            float btc = bt[cg];
            #pragma unroll
            for (int i = 0; i < 4; i++) {
                float gate = 1.f / (1.f + expf(-(accG[m][n][i] + btc)));
                float fh = accFH[m][n][i] * nvv[i];
                float het = mvv[i] * accH[m][n][i];
                float o = gate * fh + (1.f - gate) * het;
                o = (o > 0.f) ? o : expm1f(o);
                vals[n][i] = o * mvv[i];
            }
        }
        __syncthreads();
        if (LAYER == 0) {
            ushort* Ls = &lA[0][0];
            #pragma unroll
            for (int n = 0; n < 2; n++)
                #pragma unroll
                for (int i = 0; i < 4; i++)
                    Ls[bbase + (r4 + i) * 32 + n * 16 + l15] = f2b(vals[n][i]);
            __syncthreads();
            #pragma unroll
            for (int it = 0; it < 2; ++it) {
                int lr = (lane >> 3) + it * 8;
                int lc4 = (lane & 7) * 4;
                ushort4 tv = *(const ushort4*)(Ls + bbase + lr * 32 + lc4);
                int rg = rowbase + wm + m * 16 + lr;
                *(ushort4*)(outb + (size_t)rg * 256 + nbase + wn + lc4) = tv;
            }
        } else {
            float* Ls = (float*)&lA[0][0];
            #pragma unroll
            for (int n = 0; n < 2; n++)
                #pragma unroll
                for (int i = 0; i < 4; i++)
                    Ls[bbase + (r4 + i) * 32 + n * 16 + l15] = vals[n][i];
            __syncthreads();
            #pragma unroll
            for (int it = 0; it < 2; ++it) {
                int lr = (lane >> 3) + it * 8;
                int lc4 = (lane & 7) * 4;
                float4 tv = *(const float4*)(Ls + bbase + lr * 32 + lc4);
                int rg = rowbase + wm + m * 16 + lr;
                int dst = flatscat[rg];
                *(float4*)(outf + (size_t)dst * 256 + nbase + wn + lc4) = tv;
            }
        }
    }
}

extern "C" void kernel_launch(void* const* d_in, const int* in_sizes, int n_in,
                              void* d_out, int out_size, void* d_ws, size_t ws_size,
                              hipStream_t stream) {
    const float* x    = (const float*)d_in[0];
    const void*  msk  = d_in[1];
    const float* ln_g = (const float*)d_in[2];
    const float* ln_b = (const float*)d_in[3];
    const float* w1   = (const float*)d_in[4];
    const float* b1   = (const float*)d_in[5];
    const float* w2   = (const float*)d_in[6];
    const float* b2   = (const float*)d_in[7];
    const float* rot  = (const float*)d_in[8];
    const float* th0  = (const float*)d_in[9];
    const float* wh0  = (const float*)d_in[10];
    const float* wt0  = (const float*)d_in[11];
    const float* bt0  = (const float*)d_in[12];
    const float* th1  = (const float*)d_in[13];
    const float* wh1  = (const float*)d_in[14];
    const float* wt1  = (const float*)d_in[15];
    const float* bt1  = (const float*)d_in[16];

    char* ws = (char*)d_ws;
    ushort* out0 = (ushort*)(ws + OFF_OUT0);
    ushort* dmb  = (ushort*)(ws + OFF_DMB);
    ushort* wb   = (ushort*)(ws + OFF_WB);
    ushort* wbth0 = wb + 0 * 65536;
    ushort* wbwh0 = wb + 1 * 65536;
    ushort* wbwt0 = wb + 2 * 65536;
    ushort* wbth1 = wb + 3 * 65536;
    ushort* wbwh1 = wb + 4 * 65536;
    ushort* wbwt1 = wb + 5 * 65536;
    float* norm = (float*)(ws + OFF_NORM);
    float* mf   = (float*)(ws + OFF_MF);
    int*   bin  = (int*)(ws + OFF_BIN);
    int*   flat = (int*)(ws + OFF_FLAT);
    int*   mski = (int*)(ws + OFF_MSKI);
    int*   hist = (int*)(ws + OFF_HIST);
    int*   offs = (int*)(ws + OFF_OFFS);
    int*   flag = (int*)(ws + OFF_FLAG);
    int*   fixcnt = (int*)(ws + OFF_CNT);
    int*   fixlist = (int*)(ws + OFF_LIST);
    ushort* w1h = (ushort*)(ws + OFF_W1H);
    ushort* w1l = (ushort*)(ws + OFF_W1L);
    ushort* w2h = (ushort*)(ws + OFF_W2H);
    ushort* w2l = (ushort*)(ws + OFF_W2L);
    ushort* rth = (ushort*)(ws + OFF_RH);
    ushort* rtl = (ushort*)(ws + OFF_RL);
    float*  xd  = (float*)d_out;
    ushort* xnb = (ushort*)((char*)d_out + (size_t)PTS * DDIM * 4);

    hipMemsetAsync(hist, 0, HISTBYTES, stream);
    hipMemsetAsync(fixcnt, 0, 4, stream);
    k_maskflag<<<1, 256, 0, stream>>>((const int*)msk, flag);
    k_masknorm<<<PTS / 256, 256, 0, stream>>>(msk, flag, mski);
    k_wprep<<<dim3(16, 6), 256, 0, stream>>>(th0, wh0, wt0, th1, wh1, wt1,
                                             wbth0, wbwh0, wbwt0, wbth1, wbwh1, wbwt1);
    k_wsplit<<<8, 256, 0, stream>>>(w1, 256, 128, 128, 128, w1h, w1l);
    k_wsplit<<<4, 256, 0, stream>>>(w2, 128, 128, 128, 128, w2h, w2l);
    k_wsplit<<<2, 256, 0, stream>>>(rot, 128, 64, 100, 50, rth, rtl);
    k_stage1<<<PTS / 64, 512, 0, stream>>>(x, ln_g, ln_b, b1, b2,
                                           w1h, w1l, w2h, w2l, rth, rtl, mski,
                                           xnb, xd, bin, fixlist, fixcnt);
    k_fixup<<<4096, 64, 0, stream>>>(x, ln_g, ln_b, w1, b1, w2, b2, rot, mski,
                                     fixlist, fixcnt, bin);
    k_count<<<800, 128, 0, stream>>>(bin, hist);
    k_offsets<<<8, 256, 0, stream>>>(hist, offs);
    k_scatter<<<800, 128, 0, stream>>>(bin, offs, mski, flat, mf);
    k_dm<<<800, 256, 0, stream>>>(xd, flat, mf, dmb, norm);
    // layer 0 (fully fused)
    k_layer<0><<<dim3(800, 2), 512, 0, stream>>>(xnb, flat, wbth0, wbwh0, wbwt0, bt0,
                                                 dmb, norm, mf, out0, nullptr, nullptr);
    // layer 1 (fully fused, scattered fp32 output)
    k_layer<1><<<dim3(800, 2), 512, 0, stream>>>(out0, nullptr, wbth1, wbwh1, wbwt1, bt1,
                                                 dmb, norm, mf, nullptr, (float*)d_out, flat);
}

// Round 7
// 592.901 us; speedup vs baseline: 1.8562x; 1.2019x over previous
//
#include <hip/hip_runtime.h>
#include <math.h>

#define BB 8
#define NN 12800
#define FF 256
#define DDIM 128
#define NBINS 100
#define BSIZE 128
#define NROT 50
#define NIDS 199
#define PTS (BB*NN)            // 102400

// ---- workspace layout (bytes) ----
#define OFF_OUT0 ((size_t)157286400)    // 52428800  : out0 bf16 [102400][256]
#define OFF_DMB  ((size_t)209715200)    // 26214400  : dm bf16 [800][128][128]
#define OFF_WB   ((size_t)235929600)    // 786432    : 6 weights bf16 transposed [256][256]
#define OFF_NORM ((size_t)236716032)    // 409600
#define OFF_MF   ((size_t)237125632)    // 409600
#define OFF_BIN  ((size_t)237535232)    // 409600 (int)
#define OFF_FLAT ((size_t)237944832)    // 409600 (int)
#define OFF_MSKI ((size_t)238354432)    // 409600 (int)
#define OFF_HIST ((size_t)238764032)    // 636800 (int)
#define OFF_OFFS ((size_t)239400832)    // 636800 (int)
#define OFF_FLAG ((size_t)240037632)    // 64
#define OFF_CNT  ((size_t)240037696)    // 64
#define OFF_LIST ((size_t)240037760)    // 409600 (int)
#define OFF_W1H  ((size_t)240447360)    // 65536 : w1^T hi bf16 [128][256]
#define OFF_W1L  ((size_t)240512896)    // 65536
#define OFF_W2H  ((size_t)240578432)    // 32768 : w2^T hi bf16 [128][128]
#define OFF_W2L  ((size_t)240611200)    // 32768
#define OFF_RH   ((size_t)240643968)    // 16384 : rot^T hi bf16 [64][128]
#define OFF_RL   ((size_t)240660352)    // 16384
#define HISTBYTES (8*100*199*4)

using short8  = __attribute__((ext_vector_type(8))) short;
using floatx4 = __attribute__((ext_vector_type(4))) float;

__device__ __forceinline__ ushort f2b(float f) {
    unsigned u = __float_as_uint(f);
    unsigned r = (u + 0x7FFFu + ((u >> 16) & 1u)) >> 16;
    return (ushort)r;
}
__device__ __forceinline__ float b2f(ushort h) {
    return __uint_as_float(((unsigned)h) << 16);
}
__device__ __forceinline__ uint4 pack8(const ushort* o) {
    uint4 u;
    u.x = (unsigned)o[0] | ((unsigned)o[1] << 16);
    u.y = (unsigned)o[2] | ((unsigned)o[3] << 16);
    u.z = (unsigned)o[4] | ((unsigned)o[5] << 16);
    u.w = (unsigned)o[6] | ((unsigned)o[7] << 16);
    return u;
}

// ---------- mask dtype sniffing ----------
__global__ void k_maskflag(const int* mi, int* flag) {
    __shared__ int notInt, notFloat;
    if (threadIdx.x == 0) { notInt = 0; notFloat = 0; }
    __syncthreads();
    int v = mi[threadIdx.x];
    if (v != 0 && v != 1) atomicOr(&notInt, 1);
    if (v != 0 && v != 0x3F800000) atomicOr(&notFloat, 1);
    __syncthreads();
    if (threadIdx.x == 0) flag[0] = (!notInt) ? 0 : ((!notFloat) ? 2 : 1);
}

__global__ void k_masknorm(const void* msk, const int* flag, int* mski) {
    int i = blockIdx.x * blockDim.x + threadIdx.x;
    if (i >= PTS) return;
    int f = flag[0];
    int v;
    if (f == 0)      v = ((const int*)msk)[i] != 0;
    else if (f == 2) v = ((const float*)msk)[i] != 0.0f;
    else             v = ((const unsigned char*)msk)[i] != 0;
    mski[i] = v;
}

// ---------- weight prep: fp32 [k][n] -> bf16 transposed [n][k] (GHConv weights) ----------
__global__ __launch_bounds__(256) void k_wprep(
    const float* s0, const float* s1, const float* s2,
    const float* s3, const float* s4, const float* s5,
    ushort* d0, ushort* d1, ushort* d2, ushort* d3, ushort* d4, ushort* d5)
{
    __shared__ float Ls[64 * 65];
    const float* src; ushort* dst;
    switch (blockIdx.y) {
        case 0: src = s0; dst = d0; break;
        case 1: src = s1; dst = d1; break;
        case 2: src = s2; dst = d2; break;
        case 3: src = s3; dst = d3; break;
        case 4: src = s4; dst = d4; break;
        default: src = s5; dst = d5; break;
    }
    int t = blockIdx.x;
    int kb = (t & 3) * 64, nb = (t >> 2) * 64;
    int tid = threadIdx.x;
    for (int q = 0; q < 4; ++q) {
        int g = q * 256 + tid;
        int kl = g >> 4, f4 = g & 15;
        float4 v = *(const float4*)(src + (size_t)(kb + kl) * 256 + nb + f4 * 4);
        Ls[kl * 65 + f4 * 4 + 0] = v.x;
        Ls[kl * 65 + f4 * 4 + 1] = v.y;
        Ls[kl * 65 + f4 * 4 + 2] = v.z;
        Ls[kl * 65 + f4 * 4 + 3] = v.w;
    }
    __syncthreads();
    for (int q = 0; q < 2; ++q) {
        int g = q * 256 + tid;
        int nl = g >> 3, wg = g & 7;
        ushort o[8];
        #pragma unroll
        for (int c = 0; c < 8; ++c) o[c] = f2b(Ls[(wg * 8 + c) * 65 + nl]);
        *(uint4*)(dst + (size_t)(nb + nl) * 256 + kb + wg * 8) = pack8(o);
    }
}

// ---------- split-weight prep: fp32 [K][srcN] -> hi/lo bf16 transposed [N][K] ----------
__global__ __launch_bounds__(256) void k_wsplit(const float* __restrict__ src, int K, int N,
                                               int srcN, int nvalid,
                                               ushort* __restrict__ dh, ushort* __restrict__ dl) {
    __shared__ float Ls[64 * 65];
    int tilesN = N >> 6;
    int kb = (blockIdx.x / tilesN) * 64, nb = (blockIdx.x % tilesN) * 64;
    int tid = threadIdx.x;
    for (int q = 0; q < 4; ++q) {
        int g = q * 256 + tid;
        int kl = g >> 4, c4 = (g & 15) * 4;
        #pragma unroll
        for (int j = 0; j < 4; ++j) {
            int n = nb + c4 + j;
            float v = (n < nvalid) ? src[(size_t)(kb + kl) * srcN + n] : 0.f;
            Ls[kl * 65 + c4 + j] = v;
        }
    }
    __syncthreads();
    for (int q = 0; q < 2; ++q) {
        int g = q * 256 + tid;
        int nl = g >> 3, wg = g & 7;
        ushort oh[8], ol[8];
        #pragma unroll
        for (int c = 0; c < 8; ++c) {
            float v = Ls[(wg * 8 + c) * 65 + nl];
            ushort h = f2b(v);
            oh[c] = h;
            ol[c] = f2b(v - b2f(h));
        }
        *(uint4*)(dh + (size_t)(nb + nl) * K + kb + wg * 8) = pack8(oh);
        *(uint4*)(dl + (size_t)(nb + nl) * K + kb + wg * 8) = pack8(ol);
    }
}

// ---------- MFMA LDS helpers (layout verified in rounds 2-6) ----------
__device__ __forceinline__ void stage_bf16(const ushort* __restrict__ src, size_t pitch,
                                           const int* __restrict__ rowmap, int rowbase, size_t kbase,
                                           ushort* lds, int nrows, int tid, int nthr) {
    int total = nrows * 8;
    for (int g = tid; g < total; g += nthr) {
        int row = g >> 3, wg = g & 7;
        size_t srow = rowmap ? (size_t)rowmap[rowbase + row] : (size_t)(rowbase + row);
        uint4 v = *(const uint4*)(src + srow * pitch + kbase + wg * 8);
        int w0 = (wg * 4) ^ ((row & 7) << 2);
        *(uint4*)((char*)lds + row * 128 + w0 * 4) = v;
    }
}

// async staging: linear LDS dest (wave-uniform base + lane*16) with the XOR
// swizzle folded into the per-lane GLOBAL source chunk (involution: dst = src^(row&7)).
// Produces a bit-identical LDS image to stage_bf16. 512 threads fixed.
__device__ __forceinline__ void stage_async(const ushort* __restrict__ src, size_t pitch,
                                            const int* __restrict__ rowmap, int rowbase, size_t kbase,
                                            ushort* lds, int nrows, int tid) {
    int lane = tid & 63, wid = tid >> 6;
    int total = nrows * 8;
    for (int b0 = 0; b0 < total; b0 += 512) {
        int g = b0 + wid * 64 + lane;
        int row = g >> 3;
        int ck = (g & 7) ^ (row & 7);
        size_t srow = rowmap ? (size_t)rowmap[rowbase + row] : (size_t)(rowbase + row);
        const ushort* gp = src + srow * pitch + kbase + ck * 8;
        ushort* lp = lds + (size_t)(b0 + wid * 64) * 8;   // wave-uniform
        __builtin_amdgcn_global_load_lds(
            (const __attribute__((address_space(1))) unsigned int*)gp,
            (__attribute__((address_space(3))) unsigned int*)lp, 16, 0, 0);
    }
}

__device__ __forceinline__ short8 frag_ld(const ushort* lds, int row, int kc, int lane) {
    int w0 = (kc * 16 + ((lane >> 4) << 2)) ^ ((row & 7) << 2);
    return *(const short8*)((const char*)lds + row * 128 + w0 * 4);
}

// ---------- stage 1 v3: fused LN + FFN + rot via split-bf16 MFMA ----------
__global__ __launch_bounds__(512) void k_stage1(
    const float* __restrict__ x, const float* __restrict__ g, const float* __restrict__ be,
    const float* __restrict__ b1, const float* __restrict__ b2,
    const ushort* __restrict__ w1h, const ushort* __restrict__ w1l,
    const ushort* __restrict__ w2h, const ushort* __restrict__ w2l,
    const ushort* __restrict__ rth, const ushort* __restrict__ rtl,
    const int* __restrict__ mski,
    ushort* __restrict__ xn_out, float* __restrict__ xd_out, int* __restrict__ bin_out,
    int* __restrict__ fixlist, int* __restrict__ fixcnt)
{
    __shared__ ushort lXh[4 * 64 * 64];
    __shared__ ushort lXl[4 * 64 * 64];
    __shared__ ushort lWh[2][128 * 64];
    __shared__ ushort lWl[2][128 * 64];
    int tid = threadIdx.x, lane = tid & 63, wid = tid >> 6;
    int base = blockIdx.x * 64;
    int l15 = lane & 15;
    int r4 = (lane >> 4) * 4;

    stage_async(w1h, 256, nullptr, 0, 0, lWh[0], 128, tid);
    stage_async(w1l, 256, nullptr, 0, 0, lWl[0], 128, tid);

    {   // phase 0: LN (8 threads/point)
        int row = tid >> 3, sub = tid & 7;
        const float* xr = x + (size_t)(base + row) * FF + sub * 32;
        float v[32];
        float s = 0.f;
        #pragma unroll
        for (int q = 0; q < 8; ++q) {
            float4 f = *(const float4*)(xr + q * 4);
            v[q*4+0] = f.x; v[q*4+1] = f.y; v[q*4+2] = f.z; v[q*4+3] = f.w;
            s += f.x + f.y + f.z + f.w;
        }
        s += __shfl_xor(s, 1, 8); s += __shfl_xor(s, 2, 8); s += __shfl_xor(s, 4, 8);
        float mu = s * (1.f / 256.f);
        float s2 = 0.f;
        #pragma unroll
        for (int q = 0; q < 32; ++q) { float d = v[q] - mu; s2 += d * d; }
        s2 += __shfl_xor(s2, 1, 8); s2 += __shfl_xor(s2, 2, 8); s2 += __shfl_xor(s2, 4, 8);
        float rs = 1.0f / sqrtf(s2 * (1.f / 256.f) + 1e-6f);
        int kb = sub >> 1;
        ushort* xo = xn_out + (size_t)(base + row) * FF + sub * 32;
        #pragma unroll
        for (int j = 0; j < 4; ++j) {
            int i0 = sub * 32 + j * 8;
            float4 g0 = *(const float4*)(g + i0);
            float4 g1 = *(const float4*)(g + i0 + 4);
            float4 e0 = *(const float4*)(be + i0);
            float4 e1 = *(const float4*)(be + i0 + 4);
            float gv[8] = {g0.x,g0.y,g0.z,g0.w,g1.x,g1.y,g1.z,g1.w};
            float ev[8] = {e0.x,e0.y,e0.z,e0.w,e1.x,e1.y,e1.z,e1.w};
            ushort hh[8], ll[8];
            #pragma unroll
            for (int c = 0; c < 8; ++c) {
                float xv = (v[j*8+c] - mu) * rs * gv[c] + ev[c];
                ushort h = f2b(xv);
                hh[c] = h;
                ll[c] = f2b(xv - b2f(h));
            }
            uint4 uh = pack8(hh), ul = pack8(ll);
            *(uint4*)(xo + j * 8) = uh;
            int wg = (sub & 1) * 4 + j;
            int w0 = (wg * 4) ^ ((row & 7) << 2);
            *(uint4*)((char*)lXh + kb * 8192 + row * 128 + w0 * 4) = uh;
            *(uint4*)((char*)lXl + kb * 8192 + row * 128 + w0 * 4) = ul;
        }
    }
    __syncthreads();

    int wm = (wid >> 2) * 32, wn = (wid & 3) * 32;
    floatx4 zf = {0.f, 0.f, 0.f, 0.f};

    // GEMM1: h = elu(xn @ w1 + b1)
    floatx4 acc[2][2];
    #pragma unroll
    for (int m = 0; m < 2; m++)
        #pragma unroll
        for (int n = 0; n < 2; n++) acc[m][n] = zf;
    for (int kb = 0; kb < 4; ++kb) {
        if (kb < 3) {
            stage_async(w1h, 256, nullptr, 0, (size_t)(kb + 1) * 64, lWh[(kb + 1) & 1], 128, tid);
            stage_async(w1l, 256, nullptr, 0, (size_t)(kb + 1) * 64, lWl[(kb + 1) & 1], 128, tid);
        }
        #pragma unroll
        for (int kc = 0; kc < 2; ++kc) {
            short8 ah[2], al[2], bh[2], bl[2];
            #pragma unroll
            for (int m = 0; m < 2; m++) {
                ah[m] = frag_ld(lXh + kb * 4096, wm + m * 16 + l15, kc, lane);
                al[m] = frag_ld(lXl + kb * 4096, wm + m * 16 + l15, kc, lane);
            }
            #pragma unroll
            for (int n = 0; n < 2; n++) {
                bh[n] = frag_ld(lWh[kb & 1], wn + n * 16 + l15, kc, lane);
                bl[n] = frag_ld(lWl[kb & 1], wn + n * 16 + l15, kc, lane);
            }
            #pragma unroll
            for (int m = 0; m < 2; m++)
                #pragma unroll
                for (int n = 0; n < 2; n++) {
                    acc[m][n] = __builtin_amdgcn_mfma_f32_16x16x32_bf16(ah[m], bh[n], acc[m][n], 0, 0, 0);
                    acc[m][n] = __builtin_amdgcn_mfma_f32_16x16x32_bf16(ah[m], bl[n], acc[m][n], 0, 0, 0);
                    acc[m][n] = __builtin_amdgcn_mfma_f32_16x16x32_bf16(al[m], bh[n], acc[m][n], 0, 0, 0);
                }
        }
        __syncthreads();
    }
    stage_async(w2h, 128, nullptr, 0, 0, lWh[0], 128, tid);
    stage_async(w2l, 128, nullptr, 0, 0, lWl[0], 128, tid);
    {
        #pragma unroll
        for (int n = 0; n < 2; n++) {
            int cg = wn + n * 16 + l15;
            float b1v = b1[cg];
            int slab = cg >> 6, c64 = cg & 63;
            int wg = c64 >> 3, e = c64 & 7;
            #pragma unroll
            for (int m = 0; m < 2; m++) {
                #pragma unroll
                for (int i = 0; i < 4; i++) {
                    int r = wm + m * 16 + r4 + i;
                    float hv = acc[m][n][i] + b1v;
                    hv = (hv > 0.f) ? hv : expm1f(hv);
                    ushort h = f2b(hv);
                    int w0 = (wg * 4) ^ ((r & 7) << 2);
                    int idx = slab * 4096 + r * 64 + w0 * 2 + e;
                    lXh[idx] = h;
                    lXl[idx] = f2b(hv - b2f(h));
                }
            }
        }
    }
    __syncthreads();

    // GEMM2: xd = h @ w2 + b2
    floatx4 acc2[2][2];
    #pragma unroll
    for (int m = 0; m < 2; m++)
        #pragma unroll
        for (int n = 0; n < 2; n++) acc2[m][n] = zf;
    for (int kb = 0; kb < 2; ++kb) {
        if (kb == 0) {
            stage_async(w2h, 128, nullptr, 0, 64, lWh[1], 128, tid);
            stage_async(w2l, 128, nullptr, 0, 64, lWl[1], 128, tid);
        }
        #pragma unroll
        for (int kc = 0; kc < 2; ++kc) {
            short8 ah[2], al[2], bh[2], bl[2];
            #pragma unroll
            for (int m = 0; m < 2; m++) {
                ah[m] = frag_ld(lXh + kb * 4096, wm + m * 16 + l15, kc, lane);
                al[m] = frag_ld(lXl + kb * 4096, wm + m * 16 + l15, kc, lane);
            }
            #pragma unroll
            for (int n = 0; n < 2; n++) {
                bh[n] = frag_ld(lWh[kb], wn + n * 16 + l15, kc, lane);
                bl[n] = frag_ld(lWl[kb], wn + n * 16 + l15, kc, lane);
            }
            #pragma unroll
            for (int m = 0; m < 2; m++)
                #pragma unroll
                for (int n = 0; n < 2; n++) {
                    acc2[m][n] = __builtin_amdgcn_mfma_f32_16x16x32_bf16(ah[m], bh[n], acc2[m][n], 0, 0, 0);
                    acc2[m][n] = __builtin_amdgcn_mfma_f32_16x16x32_bf16(ah[m], bl[n], acc2[m][n], 0, 0, 0);
                    acc2[m][n] = __builtin_amdgcn_mfma_f32_16x16x32_bf16(al[m], bh[n], acc2[m][n], 0, 0, 0);
                }
        }
        __syncthreads();
    }
    stage_async(rth, 128, nullptr, 0, 0, lWh[0], 64, tid);
    stage_async(rtl, 128, nullptr, 0, 0, lWl[0], 64, tid);
    stage_async(rth, 128, nullptr, 0, 64, lWh[1], 64, tid);
    stage_async(rtl, 128, nullptr, 0, 64, lWl[1], 64, tid);
    {
        #pragma unroll
        for (int n = 0; n < 2; n++) {
            int cg = wn + n * 16 + l15;
            float b2v = b2[cg];
            int slab = 2 + (cg >> 6), c64 = cg & 63;
            int wg = c64 >> 3, e = c64 & 7;
            #pragma unroll
            for (int m = 0; m < 2; m++) {
                #pragma unroll
                for (int i = 0; i < 4; i++) {
                    int r = wm + m * 16 + r4 + i;
                    float xv = acc2[m][n][i] + b2v;
                    xd_out[(size_t)(base + r) * DDIM + cg] = xv;
                    ushort h = f2b(xv);
                    int w0 = (wg * 4) ^ ((r & 7) << 2);
                    int idx = slab * 4096 + r * 64 + w0 * 2 + e;
                    lXh[idx] = h;
                    lXl[idx] = f2b(xv - b2f(h));
                }
            }
        }
    }
    __syncthreads();

    // GEMM3: mul = xd @ rot
    floatx4 acc3[2];
    acc3[0] = zf; acc3[1] = zf;
    int wm3 = (wid >> 2) * 32, wn3 = (wid & 3) * 16;
    for (int kb = 0; kb < 2; ++kb) {
        #pragma unroll
        for (int kc = 0; kc < 2; ++kc) {
            short8 ah[2], al[2], bh, bl;
            #pragma unroll
            for (int m = 0; m < 2; m++) {
                ah[m] = frag_ld(lXh + (2 + kb) * 4096, wm3 + m * 16 + l15, kc, lane);
                al[m] = frag_ld(lXl + (2 + kb) * 4096, wm3 + m * 16 + l15, kc, lane);
            }
            bh = frag_ld(lWh[kb], wn3 + l15, kc, lane);
            bl = frag_ld(lWl[kb], wn3 + l15, kc, lane);
            #pragma unroll
            for (int m = 0; m < 2; m++) {
                acc3[m] = __builtin_amdgcn_mfma_f32_16x16x32_bf16(ah[m], bh, acc3[m], 0, 0, 0);
                acc3[m] = __builtin_amdgcn_mfma_f32_16x16x32_bf16(ah[m], bl, acc3[m], 0, 0, 0);
                acc3[m] = __builtin_amdgcn_mfma_f32_16x16x32_bf16(al[m], bh, acc3[m], 0, 0, 0);
            }
        }
    }
    __syncthreads();
    float* lMul = (float*)(&lWh[0][0]);
    {
        #pragma unroll
        for (int m = 0; m < 2; m++)
            #pragma unroll
            for (int i = 0; i < 4; i++) {
                int r = wm3 + m * 16 + r4 + i;
                lMul[r * 65 + wn3 + l15] = acc3[m][i];
            }
    }
    __syncthreads();

    {   // top-2 argmax over [mul, -mul], margin flag
        int p = tid >> 3, q = tid & 7;
        float v1 = -1e30f, v2 = -1e30f; int i1 = 1 << 29;
        #pragma unroll
        for (int j = 0; j < 8; ++j) {
            int c = q * 8 + j;
            if (c < 50) {
                float m = lMul[p * 65 + c];
                float wv, lv; int wi, li;
                if (m >= 0.f) { wv = m; wi = c; lv = -m; li = 50 + c; }
                else          { wv = -m; wi = 50 + c; lv = m; li = c; }
                if (wv > v1 || (wv == v1 && wi < i1)) { v2 = v1; v1 = wv; i1 = wi; }
                else if (wv > v2) v2 = wv;
                if (lv > v1 || (lv == v1 && li < i1)) { v2 = v1; v1 = lv; i1 = li; }
                else if (lv > v2) v2 = lv;
            }
        }
        #pragma unroll
        for (int off = 1; off < 8; off <<= 1) {
            float o1 = __shfl_xor(v1, off, 8);
            int   oi = __shfl_xor(i1, off, 8);
            float o2 = __shfl_xor(v2, off, 8);
            bool take = (o1 > v1) || (o1 == v1 && oi < i1);
            float small = take ? v1 : o1;
            if (take) { v1 = o1; i1 = oi; }
            v2 = fmaxf(fmaxf(v2, o2), small);
        }
        if (q == 0) {
            int pt = base + p;
            bin_out[pt] = i1 + (mski[pt] ? 0 : (NBINS - 1));
            float tau = 3e-4f + 1.5e-3f * v1;
            if (v1 - v2 < tau) {
                int pos = atomicAdd(fixcnt, 1);
                fixlist[pos] = pt;
            }
        }
    }
}

// ---------- fp64 fixup for margin-flagged points ----------
__global__ __launch_bounds__(64) void k_fixup(
    const float* __restrict__ x, const float* __restrict__ g, const float* __restrict__ be,
    const float* __restrict__ w1, const float* __restrict__ b1,
    const float* __restrict__ w2, const float* __restrict__ b2,
    const float* __restrict__ rot, const int* __restrict__ mski,
    const int* __restrict__ fixlist, const int* __restrict__ fixcnt,
    int* __restrict__ bin_out)
{
    __shared__ double xn_s[256];
    __shared__ double h_s[128];
    __shared__ double xd_s[128];
    int lane = threadIdx.x;
    int n = fixcnt[0];
    for (int e = blockIdx.x; e < n; e += gridDim.x) {
        int pt = fixlist[e];
        const float* xr = x + (size_t)pt * FF;
        double s = 0.0, xv[4];
        #pragma unroll
        for (int q = 0; q < 4; q++) { xv[q] = (double)xr[lane + q * 64]; s += xv[q]; }
        #pragma unroll
        for (int off = 1; off < 64; off <<= 1) s += __shfl_xor(s, off, 64);
        double mu = s * (1.0 / 256.0);
        double s2 = 0.0;
        #pragma unroll
        for (int q = 0; q < 4; q++) { double d = xv[q] - mu; s2 += d * d; }
        #pragma unroll
        for (int off = 1; off < 64; off <<= 1) s2 += __shfl_xor(s2, off, 64);
        double rs = 1.0 / sqrt(s2 * (1.0 / 256.0) + 1e-6);
        #pragma unroll
        for (int q = 0; q < 4; q++) {
            int i = lane + q * 64;
            xn_s[i] = (xv[q] - mu) * rs * (double)g[i] + (double)be[i];
        }
        __syncthreads();
        #pragma unroll
        for (int q = 0; q < 2; q++) {
            int j = lane + q * 64;
            double a0 = 0.0, a1 = 0.0;
            for (int k = 0; k < FF; k += 2) {
                a0 += xn_s[k] * (double)w1[k * DDIM + j];
                a1 += xn_s[k + 1] * (double)w1[(k + 1) * DDIM + j];
            }
            double a = (double)b1[j] + a0 + a1;
            h_s[j] = (a > 0.0) ? a : expm1(a);
        }
        __syncthreads();
        #pragma unroll
        for (int q = 0; q < 2; q++) {
            int j = lane + q * 64;
            double a0 = 0.0, a1 = 0.0;
            for (int k = 0; k < DDIM; k += 2) {
                a0 += h_s[k] * (double)w2[k * DDIM + j];
                a1 += h_s[k + 1] * (double)w2[(k + 1) * DDIM + j];
            }
            xd_s[j] = (double)b2[j] + a0 + a1;
        }
        __syncthreads();
        double v; int idx;
        if (lane < NROT) {
            double m = 0.0;
            for (int k = 0; k < DDIM; k++) m += xd_s[k] * (double)rot[k * 100 + lane];
            if (m >= 0.0) { v = m; idx = lane; } else { v = -m; idx = 50 + lane; }
        } else { v = -1e300; idx = 1 << 29; }
        #pragma unroll
        for (int off = 1; off < 64; off <<= 1) {
            double ov = __shfl_xor(v, off, 64);
            int oi = __shfl_xor(idx, off, 64);
            if (ov > v || (ov == v && oi < idx)) { v = ov; idx = oi; }
        }
        if (lane == 0) bin_out[pt] = idx + (mski[pt] ? 0 : (NBINS - 1));
        __syncthreads();
    }
}

// ---------- binning: stable counting sort ----------
__global__ void k_count(const int* __restrict__ bin, int* __restrict__ hist) {
    int c = blockIdx.x % 100, b = blockIdx.x / 100;
    int t = threadIdx.x;
    int v = bin[b * NN + c * BSIZE + t];
    atomicAdd(&hist[(b * 100 + c) * NIDS + v], 1);
}

__global__ void k_offsets(const int* __restrict__ hist, int* __restrict__ offs) {
    __shared__ int tot[NIDS];
    __shared__ int start[NIDS];
    int b = blockIdx.x, v = threadIdx.x;
    if (v < NIDS) {
        int s = 0;
        for (int c = 0; c < 100; c++) s += hist[(b * 100 + c) * NIDS + v];
        tot[v] = s;
    }
    __syncthreads();
    if (threadIdx.x == 0) {
        int run = 0;
        for (int i = 0; i < NIDS; i++) { start[i] = run; run += tot[i]; }
    }
    __syncthreads();
    if (v < NIDS) {
        int run = start[v];
        for (int c = 0; c < 100; c++) {
            offs[(b * 100 + c) * NIDS + v] = run;
            run += hist[(b * 100 + c) * NIDS + v];
        }
    }
}

__global__ void k_scatter(const int* __restrict__ bin, const int* __restrict__ offs,
                          const int* __restrict__ mski, int* __restrict__ flat,
                          float* __restrict__ mf) {
    __shared__ int sv[BSIZE];
    int c = blockIdx.x % 100, b = blockIdx.x / 100;
    int t = threadIdx.x;
    int n = c * BSIZE + t;
    int v = bin[b * NN + n];
    sv[t] = v;
    __syncthreads();
    int rank = 0;
    for (int u = 0; u < t; u++) rank += (sv[u] == v);
    int r = offs[(b * 100 + c) * NIDS + v] + rank;
    flat[b * NN + r] = b * NN + n;
    mf[b * NN + r] = mski[b * NN + n] ? 1.0f : 0.0f;
}

// ---------- per-bin pairwise kernel matrix (fp32 tiled), fused deg/norm ----------
__global__ __launch_bounds__(256) void k_dm(const float* __restrict__ xd, const int* __restrict__ flat,
                                            const float* __restrict__ mf, ushort* __restrict__ dmb,
                                            float* __restrict__ norm) {
    __shared__ float Xs[128 * 64];
    __shared__ float na[128];
    __shared__ float ml[128];
    __shared__ float ps[128 * 16];
    int g = blockIdx.x, tid = threadIdx.x;
    int tx = tid & 15, ty = tid >> 4;
    int rowbase = g * 128;
    if (tid < 128) ml[tid] = mf[rowbase + tid];
    float acc[8][8];
    #pragma unroll
    for (int i = 0; i < 8; i++)
        #pragma unroll
        for (int j = 0; j < 8; j++) acc[i][j] = 0.f;
    float nap[8];
    #pragma unroll
    for (int j = 0; j < 8; j++) nap[j] = 0.f;

    for (int kh = 0; kh < 2; ++kh) {
        __syncthreads();
        for (int q = 0; q < 8; ++q) {
            int gg = q * 256 + tid;
            int row = gg >> 4, f4 = gg & 15;
            int srow = flat[rowbase + row];
            float4 v = *(const float4*)(xd + (size_t)srow * DDIM + kh * 64 + f4 * 4);
            int f4s = f4 ^ ((row >> 3) & 7);
            *(float4*)(Xs + row * 64 + f4s * 4) = v;
        }
        __syncthreads();
        for (int k4 = 0; k4 < 16; ++k4) {
            int sa = (k4 ^ (ty & 7)) << 2;
            int sb = (k4 ^ (tx & 7)) << 2;
            float4 av[8], bv[8];
            #pragma unroll
            for (int i = 0; i < 8; i++) av[i] = *(const float4*)(Xs + (ty * 8 + i) * 64 + sa);
            #pragma unroll
            for (int j = 0; j < 8; j++) bv[j] = *(const float4*)(Xs + (tx * 8 + j) * 64 + sb);
            if (ty == 0) {
                #pragma unroll
                for (int j = 0; j < 8; j++)
                    nap[j] += bv[j].x * bv[j].x + bv[j].y * bv[j].y + bv[j].z * bv[j].z + bv[j].w * bv[j].w;
            }
            #pragma unroll
            for (int i = 0; i < 8; i++)
                #pragma unroll
                for (int j = 0; j < 8; j++)
                    acc[i][j] += av[i].x * bv[j].x + av[i].y * bv[j].y + av[i].z * bv[j].z + av[i].w * bv[j].w;
        }
    }
    if (ty == 0) {
        #pragma unroll
        for (int j = 0; j < 8; j++) na[tx * 8 + j] = nap[j];
    }
    __syncthreads();
    #pragma unroll
    for (int i = 0; i < 8; ++i) {
        int r = ty * 8 + i;
        float nai = na[r], mi = ml[r];
        float rs = 0.f;
        ushort o[8];
        #pragma unroll
        for (int j = 0; j < 8; ++j) {
            int c = tx * 8 + j;
            float D2 = nai - 2.f * acc[i][j] + na[c];
            float dv = expf(-0.1f * sqrtf(fmaxf(D2, 1e-6f)));
            dv *= mi * ml[c];
            rs += dv;
            o[j] = f2b(dv);
        }
        *(uint4*)(dmb + (size_t)g * 16384 + r * 128 + tx * 8) = pack8(o);
        ps[r * 16 + tx] = rs;
    }
    __syncthreads();
    if (tid < 128) {
        float deg = 0.f;
        for (int t2 = 0; t2 < 16; ++t2) deg += ps[tid * 16 + t2];
        deg = fminf(deg, 1000.0f);
        float nv = 1.0f / sqrtf(deg + 1e-6f);
        norm[rowbase + tid] = nv * ml[tid];
    }
}

// ---------- fused per-layer graph conv: T=(A@Th)*norm ; FH=(dm@T)*norm ; comb ----------
// block = (bin g, n-half). 512 threads, 8 warps (2 row-groups x 4 col-groups of 32).
template<int LAYER>
__global__ __launch_bounds__(512) void k_layer(
    const ushort* __restrict__ A, const int* __restrict__ rowmap,
    const ushort* __restrict__ ThT, const ushort* __restrict__ WhT, const ushort* __restrict__ WtT,
    const float* __restrict__ bt, const ushort* __restrict__ dmb,
    const float* __restrict__ norm, const float* __restrict__ mf,
    ushort* __restrict__ outb, float* __restrict__ outf, const int* __restrict__ flatscat)
{
    __shared__ ushort lT[2 * 8192];      // 32KB : T^T [c][j] swizzled, 2 j-slabs
    __shared__ ushort lA[2][8192];       // 32KB : A slabs ping
    __shared__ ushort lW[4][8192];       // 64KB : P: th ping in [0],[2], dm in [1],[3]; C: wh [0],[1], wt [2],[3]
    int tid = threadIdx.x, lane = tid & 63, wid = tid >> 6;
    int g = blockIdx.x, nh = blockIdx.y;
    int rowbase = g * 128, nbase = nh * 128;
    int l15 = lane & 15;
    int r4 = (lane >> 4) * 4;
    int wm = (wid >> 2) * 64, wn = (wid & 3) * 32;
    const ushort* dmg = dmb + (size_t)g * 16384;
    floatx4 zf = {0.f, 0.f, 0.f, 0.f};

    // prologue staging (async): A slab0, th slab0, dm (both slabs)
    stage_async(A, 256, rowmap, rowbase, 0, lA[0], 128, tid);
    stage_async(ThT, 256, nullptr, nbase, 0, lW[0], 128, tid);
    stage_async(dmg, 128, nullptr, 0, 0, lW[1], 128, tid);
    stage_async(dmg, 128, nullptr, 0, 64, lW[3], 128, tid);
    __syncthreads();

    // ---- phase P: T = (A@Th)*norm, M=128 N=128 K=256 ----
    floatx4 accP[4][2];
    #pragma unroll
    for (int m = 0; m < 4; m++) { accP[m][0] = zf; accP[m][1] = zf; }
    for (int kb = 0; kb < 4; ++kb) {
        if (kb < 3) {
            stage_async(A, 256, rowmap, rowbase, (size_t)(kb + 1) * 64, lA[(kb + 1) & 1], 128, tid);
            stage_async(ThT, 256, nullptr, nbase, (size_t)(kb + 1) * 64, lW[((kb + 1) & 1) * 2], 128, tid);
        }
        #pragma unroll
        for (int kc = 0; kc < 2; ++kc) {
            short8 a[4], b[2];
            #pragma unroll
            for (int m = 0; m < 4; m++) a[m] = frag_ld(lA[kb & 1], wm + m * 16 + l15, kc, lane);
            #pragma unroll
            for (int n = 0; n < 2; n++) b[n] = frag_ld(lW[(kb & 1) * 2], wn + n * 16 + l15, kc, lane);
            #pragma unroll
            for (int m = 0; m < 4; m++)
                #pragma unroll
                for (int n = 0; n < 2; n++)
                    accP[m][n] = __builtin_amdgcn_mfma_f32_16x16x32_bf16(a[m], b[n], accP[m][n], 0, 0, 0);
        }
        __syncthreads();
    }
    // epilogue P: issue phase-C slab0 prefetch first (overlaps VALU), then T^T into lT
    stage_async(WhT, 256, nullptr, nbase, 0, lW[0], 128, tid);
    stage_async(WtT, 256, nullptr, nbase, 0, lW[2], 128, tid);
    stage_async(A, 256, rowmap, rowbase, 0, lA[0], 128, tid);
    {
        #pragma unroll
        for (int m = 0; m < 4; m++) {
            float4 nv = *(const float4*)(norm + rowbase + wm + m * 16 + r4);
            float nvv[4] = {nv.x, nv.y, nv.z, nv.w};
            int jloc0 = wm + m * 16 + r4;
            int jb = jloc0 >> 6, jj = jloc0 & 63;
            #pragma unroll
            for (int n = 0; n < 2; n++) {
                int cloc = wn + n * 16 + l15;
                char* bp = (char*)lT + jb * 16384 + cloc * 128;
                int cx = (cloc & 7) << 2;
                ushort t0 = f2b(accP[m][n][0] * nvv[0]);
                ushort t1 = f2b(accP[m][n][1] * nvv[1]);
                ushort t2 = f2b(accP[m][n][2] * nvv[2]);
                ushort t3 = f2b(accP[m][n][3] * nvv[3]);
                *(unsigned*)(bp + ((((jj >> 1) + 0) ^ cx) << 2)) = (unsigned)t0 | ((unsigned)t1 << 16);
                *(unsigned*)(bp + ((((jj >> 1) + 1) ^ cx) << 2)) = (unsigned)t2 | ((unsigned)t3 << 16);
            }
        }
    }
    __syncthreads();

    // ---- phase A: FH = dm @ T, M=128 N=128 K=128 (dm in lW[1],[3]) ----
    floatx4 accFH[4][2];
    #pragma unroll
    for (int m = 0; m < 4; m++) { accFH[m][0] = zf; accFH[m][1] = zf; }
    for (int kb = 0; kb < 2; ++kb) {
        #pragma unroll
        for (int kc = 0; kc < 2; ++kc) {
            short8 a[4], b[2];
            #pragma unroll
            for (int m = 0; m < 4; m++) a[m] = frag_ld(lW[1 + kb * 2], wm + m * 16 + l15, kc, lane);
            #pragma unroll
            for (int n = 0; n < 2; n++) b[n] = frag_ld(lT + kb * 8192, wn + n * 16 + l15, kc, lane);
            #pragma unroll
            for (int m = 0; m < 4; m++)
                #pragma unroll
                for (int n = 0; n < 2; n++)
                    accFH[m][n] = __builtin_amdgcn_mfma_f32_16x16x32_bf16(a[m], b[n], accFH[m][n], 0, 0, 0);
        }
    }
    __syncthreads();

    // ---- phase C: H = A@Wh, G = A@Wt, M=128 N=128 K=256 ----
    floatx4 accH[4][2], accG[4][2];
    #pragma unroll
    for (int m = 0; m < 4; m++) {
        accH[m][0] = zf; accH[m][1] = zf;
        accG[m][0] = zf; accG[m][1] = zf;
    }
    for (int kb = 0; kb < 4; ++kb) {
        if (kb < 3) {
            stage_async(A, 256, rowmap, rowbase, (size_t)(kb + 1) * 64, lA[(kb + 1) & 1], 128, tid);
            stage_async(WhT, 256, nullptr, nbase, (size_t)(kb + 1) * 64, lW[(kb + 1) & 1], 128, tid);
            stage_async(WtT, 256, nullptr, nbase, (size_t)(kb + 1) * 64, lW[2 + ((kb + 1) & 1)], 128, tid);
        }
        #pragma unroll
        for (int kc = 0; kc < 2; ++kc) {
            short8 a[4], bh[2], bg[2];
            #pragma unroll
            for (int m = 0; m < 4; m++) a[m] = frag_ld(lA[kb & 1], wm + m * 16 + l15, kc, lane);
            #pragma unroll
            for (int n = 0; n < 2; n++) {
                bh[n] = frag_ld(lW[kb & 1], wn + n * 16 + l15, kc, lane);
                bg[n] = frag_ld(lW[2 + (kb & 1)], wn + n * 16 + l15, kc, lane);
            }
            #pragma unroll
            for (int m = 0; m < 4; m++)
                #pragma unroll
                for (int n = 0; n < 2; n++) {
                    accH[m][n] = __builtin_amdgcn_mfma_f32_16x16x32_bf16(a[m], bh[n], accH[m][n], 0, 0, 0);
                    accG[m][n] = __builtin_amdgcn_mfma_f32_16x16x32_bf16(a[m], bg[n], accG[m][n], 0, 0, 0);
                }
        }
        __syncthreads();
    }

    // ---- epilogue: gate/elu combine + coalesced store (bounce via lA) ----
    int bbase = wid * 512;
    for (int m = 0; m < 4; m++) {
        int r0l = wm + m * 16 + r4;
        int r0g = rowbase + r0l;
        float4 mv = *(const float4*)(mf + r0g);
        float4 nv = *(const float4*)(norm + r0g);
        float mvv[4] = {mv.x, mv.y, mv.z, mv.w};
        float nvv[4] = {nv.x, nv.y, nv.z, nv.w};
        float vals[2][4];
        #pragma unroll
        for (int n = 0; n < 2; n++) {
            int cg = nbase + wn + n * 16 + l15;
            float btc = bt[cg];
            #pragma unroll
            for (int i = 0; i < 4; i++) {
                float gate = 1.f / (1.f + expf(-(accG[m][n][i] + btc)));
                float fh = accFH[m][n][i] * nvv[i];
                float het = mvv[i] * accH[m][n][i];
                float o = gate * fh + (1.f - gate) * het;
                o = (o > 0.f) ? o : expm1f(o);
                vals[n][i] = o * mvv[i];
            }
        }
        __syncthreads();
        if (LAYER == 0) {
            ushort* Ls = &lA[0][0];
            #pragma unroll
            for (int n = 0; n < 2; n++)
                #pragma unroll
                for (int i = 0; i < 4; i++)
                    Ls[bbase + (r4 + i) * 32 + n * 16 + l15] = f2b(vals[n][i]);
            __syncthreads();
            #pragma unroll
            for (int it = 0; it < 2; ++it) {
                int lr = (lane >> 3) + it * 8;
                int lc4 = (lane & 7) * 4;
                ushort4 tv = *(const ushort4*)(Ls + bbase + lr * 32 + lc4);
                int rg = rowbase + wm + m * 16 + lr;
                *(ushort4*)(outb + (size_t)rg * 256 + nbase + wn + lc4) = tv;
            }
        } else {
            float* Ls = (float*)&lA[0][0];
            #pragma unroll
            for (int n = 0; n < 2; n++)
                #pragma unroll
                for (int i = 0; i < 4; i++)
                    Ls[bbase + (r4 + i) * 32 + n * 16 + l15] = vals[n][i];
            __syncthreads();
            #pragma unroll
            for (int it = 0; it < 2; ++it) {
                int lr = (lane >> 3) + it * 8;
                int lc4 = (lane & 7) * 4;
                float4 tv = *(const float4*)(Ls + bbase + lr * 32 + lc4);
                int rg = rowbase + wm + m * 16 + lr;
                int dst = flatscat[rg];
                *(float4*)(outf + (size_t)dst * 256 + nbase + wn + lc4) = tv;
            }
        }
    }
}

extern "C" void kernel_launch(void* const* d_in, const int* in_sizes, int n_in,
                              void* d_out, int out_size, void* d_ws, size_t ws_size,
                              hipStream_t stream) {
    const float* x    = (const float*)d_in[0];
    const void*  msk  = d_in[1];
    const float* ln_g = (const float*)d_in[2];
    const float* ln_b = (const float*)d_in[3];
    const float* w1   = (const float*)d_in[4];
    const float* b1   = (const float*)d_in[5];
    const float* w2   = (const float*)d_in[6];
    const float* b2   = (const float*)d_in[7];
    const float* rot  = (const float*)d_in[8];
    const float* th0  = (const float*)d_in[9];
    const float* wh0  = (const float*)d_in[10];
    const float* wt0  = (const float*)d_in[11];
    const float* bt0  = (const float*)d_in[12];
    const float* th1  = (const float*)d_in[13];
    const float* wh1  = (const float*)d_in[14];
    const float* wt1  = (const float*)d_in[15];
    const float* bt1  = (const float*)d_in[16];

    char* ws = (char*)d_ws;
    ushort* out0 = (ushort*)(ws + OFF_OUT0);
    ushort* dmb  = (ushort*)(ws + OFF_DMB);
    ushort* wb   = (ushort*)(ws + OFF_WB);
    ushort* wbth0 = wb + 0 * 65536;
    ushort* wbwh0 = wb + 1 * 65536;
    ushort* wbwt0 = wb + 2 * 65536;
    ushort* wbth1 = wb + 3 * 65536;
    ushort* wbwh1 = wb + 4 * 65536;
    ushort* wbwt1 = wb + 5 * 65536;
    float* norm = (float*)(ws + OFF_NORM);
    float* mf   = (float*)(ws + OFF_MF);
    int*   bin  = (int*)(ws + OFF_BIN);
    int*   flat = (int*)(ws + OFF_FLAT);
    int*   mski = (int*)(ws + OFF_MSKI);
    int*   hist = (int*)(ws + OFF_HIST);
    int*   offs = (int*)(ws + OFF_OFFS);
    int*   flag = (int*)(ws + OFF_FLAG);
    int*   fixcnt = (int*)(ws + OFF_CNT);
    int*   fixlist = (int*)(ws + OFF_LIST);
    ushort* w1h = (ushort*)(ws + OFF_W1H);
    ushort* w1l = (ushort*)(ws + OFF_W1L);
    ushort* w2h = (ushort*)(ws + OFF_W2H);
    ushort* w2l = (ushort*)(ws + OFF_W2L);
    ushort* rth = (ushort*)(ws + OFF_RH);
    ushort* rtl = (ushort*)(ws + OFF_RL);
    float*  xd  = (float*)d_out;
    ushort* xnb = (ushort*)((char*)d_out + (size_t)PTS * DDIM * 4);

    hipMemsetAsync(hist, 0, HISTBYTES, stream);
    hipMemsetAsync(fixcnt, 0, 4, stream);
    k_maskflag<<<1, 256, 0, stream>>>((const int*)msk, flag);
    k_masknorm<<<PTS / 256, 256, 0, stream>>>(msk, flag, mski);
    k_wprep<<<dim3(16, 6), 256, 0, stream>>>(th0, wh0, wt0, th1, wh1, wt1,
                                             wbth0, wbwh0, wbwt0, wbth1, wbwh1, wbwt1);
    k_wsplit<<<8, 256, 0, stream>>>(w1, 256, 128, 128, 128, w1h, w1l);
    k_wsplit<<<4, 256, 0, stream>>>(w2, 128, 128, 128, 128, w2h, w2l);
    k_wsplit<<<2, 256, 0, stream>>>(rot, 128, 64, 100, 50, rth, rtl);
    k_stage1<<<PTS / 64, 512, 0, stream>>>(x, ln_g, ln_b, b1, b2,
                                           w1h, w1l, w2h, w2l, rth, rtl, mski,
                                           xnb, xd, bin, fixlist, fixcnt);
    k_fixup<<<4096, 64, 0, stream>>>(x, ln_g, ln_b, w1, b1, w2, b2, rot, mski,
                                     fixlist, fixcnt, bin);
    k_count<<<800, 128, 0, stream>>>(bin, hist);
    k_offsets<<<8, 256, 0, stream>>>(hist, offs);
    k_scatter<<<800, 128, 0, stream>>>(bin, offs, mski, flat, mf);
    k_dm<<<800, 256, 0, stream>>>(xd, flat, mf, dmb, norm);
    // layer 0 (fully fused)
    k_layer<0><<<dim3(800, 2), 512, 0, stream>>>(xnb, flat, wbth0, wbwh0, wbwt0, bt0,
                                                 dmb, norm, mf, out0, nullptr, nullptr);
    // layer 1 (fully fused, scattered fp32 output)
    k_layer<1><<<dim3(800, 2), 512, 0, stream>>>(out0, nullptr, wbth1, wbwh1, wbwt1, bt1,
                                                 dmb, norm, mf, nullptr, (float*)d_out, flat);
}

// Round 8
// 517.383 us; speedup vs baseline: 2.1272x; 1.1460x over previous
//
#include <hip/hip_runtime.h>
#include <math.h>

#define BB 8
#define NN 12800
#define FF 256
#define DDIM 128
#define NBINS 100
#define BSIZE 128
#define NROT 50
#define NIDS 199
#define PTS (BB*NN)            // 102400

// ---- workspace layout (bytes) ----
#define OFF_OUT0 ((size_t)157286400)    // 52428800  : out0 bf16 [102400][256]
#define OFF_DMB  ((size_t)209715200)    // 26214400  : dm bf16 [800][128][128]
#define OFF_WB   ((size_t)235929600)    // 786432    : 6 weights bf16 transposed [256][256]
#define OFF_NORM ((size_t)236716032)    // 409600
#define OFF_MF   ((size_t)237125632)    // 409600
#define OFF_BIN  ((size_t)237535232)    // 409600 (int)
#define OFF_FLAT ((size_t)237944832)    // 409600 (int)
#define OFF_MSKI ((size_t)238354432)    // 409600 (int)
#define OFF_HIST ((size_t)238764032)    // 636800 (int)
#define OFF_OFFS ((size_t)239400832)    // 636800 (int)
#define OFF_FLAG ((size_t)240037632)    // 64
#define OFF_CNT  ((size_t)240037696)    // 64
#define OFF_LIST ((size_t)240037760)    // 409600 (int)
#define OFF_W1H  ((size_t)240447360)    // 65536 : w1^T hi bf16 [128][256]
#define OFF_W1L  ((size_t)240512896)    // 65536
#define OFF_W2H  ((size_t)240578432)    // 32768 : w2^T hi bf16 [128][128]
#define OFF_W2L  ((size_t)240611200)    // 32768
#define OFF_RH   ((size_t)240643968)    // 16384 : rot^T hi bf16 [64][128]
#define OFF_RL   ((size_t)240660352)    // 16384
#define HISTBYTES (8*100*199*4)

using short8  = __attribute__((ext_vector_type(8))) short;
using floatx4 = __attribute__((ext_vector_type(4))) float;

__device__ __forceinline__ ushort f2b(float f) {
    unsigned u = __float_as_uint(f);
    unsigned r = (u + 0x7FFFu + ((u >> 16) & 1u)) >> 16;
    return (ushort)r;
}
__device__ __forceinline__ float b2f(ushort h) {
    return __uint_as_float(((unsigned)h) << 16);
}
__device__ __forceinline__ uint4 pack8(const ushort* o) {
    uint4 u;
    u.x = (unsigned)o[0] | ((unsigned)o[1] << 16);
    u.y = (unsigned)o[2] | ((unsigned)o[3] << 16);
    u.z = (unsigned)o[4] | ((unsigned)o[5] << 16);
    u.w = (unsigned)o[6] | ((unsigned)o[7] << 16);
    return u;
}

// ---------- mask dtype sniffing ----------
__global__ void k_maskflag(const int* mi, int* flag) {
    __shared__ int notInt, notFloat;
    if (threadIdx.x == 0) { notInt = 0; notFloat = 0; }
    __syncthreads();
    int v = mi[threadIdx.x];
    if (v != 0 && v != 1) atomicOr(&notInt, 1);
    if (v != 0 && v != 0x3F800000) atomicOr(&notFloat, 1);
    __syncthreads();
    if (threadIdx.x == 0) flag[0] = (!notInt) ? 0 : ((!notFloat) ? 2 : 1);
}

__global__ void k_masknorm(const void* msk, const int* flag, int* mski) {
    int i = blockIdx.x * blockDim.x + threadIdx.x;
    if (i >= PTS) return;
    int f = flag[0];
    int v;
    if (f == 0)      v = ((const int*)msk)[i] != 0;
    else if (f == 2) v = ((const float*)msk)[i] != 0.0f;
    else             v = ((const unsigned char*)msk)[i] != 0;
    mski[i] = v;
}

// ---------- weight prep: fp32 [k][n] -> bf16 transposed [n][k] (GHConv weights) ----------
__global__ __launch_bounds__(256) void k_wprep(
    const float* s0, const float* s1, const float* s2,
    const float* s3, const float* s4, const float* s5,
    ushort* d0, ushort* d1, ushort* d2, ushort* d3, ushort* d4, ushort* d5)
{
    __shared__ float Ls[64 * 65];
    const float* src; ushort* dst;
    switch (blockIdx.y) {
        case 0: src = s0; dst = d0; break;
        case 1: src = s1; dst = d1; break;
        case 2: src = s2; dst = d2; break;
        case 3: src = s3; dst = d3; break;
        case 4: src = s4; dst = d4; break;
        default: src = s5; dst = d5; break;
    }
    int t = blockIdx.x;
    int kb = (t & 3) * 64, nb = (t >> 2) * 64;
    int tid = threadIdx.x;
    for (int q = 0; q < 4; ++q) {
        int g = q * 256 + tid;
        int kl = g >> 4, f4 = g & 15;
        float4 v = *(const float4*)(src + (size_t)(kb + kl) * 256 + nb + f4 * 4);
        Ls[kl * 65 + f4 * 4 + 0] = v.x;
        Ls[kl * 65 + f4 * 4 + 1] = v.y;
        Ls[kl * 65 + f4 * 4 + 2] = v.z;
        Ls[kl * 65 + f4 * 4 + 3] = v.w;
    }
    __syncthreads();
    for (int q = 0; q < 2; ++q) {
        int g = q * 256 + tid;
        int nl = g >> 3, wg = g & 7;
        ushort o[8];
        #pragma unroll
        for (int c = 0; c < 8; ++c) o[c] = f2b(Ls[(wg * 8 + c) * 65 + nl]);
        *(uint4*)(dst + (size_t)(nb + nl) * 256 + kb + wg * 8) = pack8(o);
    }
}

// ---------- split-weight prep: fp32 [K][srcN] -> hi/lo bf16 transposed [N][K] ----------
__global__ __launch_bounds__(256) void k_wsplit(const float* __restrict__ src, int K, int N,
                                               int srcN, int nvalid,
                                               ushort* __restrict__ dh, ushort* __restrict__ dl) {
    __shared__ float Ls[64 * 65];
    int tilesN = N >> 6;
    int kb = (blockIdx.x / tilesN) * 64, nb = (blockIdx.x % tilesN) * 64;
    int tid = threadIdx.x;
    for (int q = 0; q < 4; ++q) {
        int g = q * 256 + tid;
        int kl = g >> 4, c4 = (g & 15) * 4;
        #pragma unroll
        for (int j = 0; j < 4; ++j) {
            int n = nb + c4 + j;
            float v = (n < nvalid) ? src[(size_t)(kb + kl) * srcN + n] : 0.f;
            Ls[kl * 65 + c4 + j] = v;
        }
    }
    __syncthreads();
    for (int q = 0; q < 2; ++q) {
        int g = q * 256 + tid;
        int nl = g >> 3, wg = g & 7;
        ushort oh[8], ol[8];
        #pragma unroll
        for (int c = 0; c < 8; ++c) {
            float v = Ls[(wg * 8 + c) * 65 + nl];
            ushort h = f2b(v);
            oh[c] = h;
            ol[c] = f2b(v - b2f(h));
        }
        *(uint4*)(dh + (size_t)(nb + nl) * K + kb + wg * 8) = pack8(oh);
        *(uint4*)(dl + (size_t)(nb + nl) * K + kb + wg * 8) = pack8(ol);
    }
}

// ---------- MFMA LDS helpers (layout verified in rounds 2-7) ----------
// async staging: linear LDS dest (wave-uniform base + lane*16) with the XOR
// swizzle folded into the per-lane GLOBAL source chunk (involution: dst = src^(row&7)).
__device__ __forceinline__ void stage_async(const ushort* __restrict__ src, size_t pitch,
                                            const int* __restrict__ rowmap, int rowbase, size_t kbase,
                                            ushort* lds, int nrows, int tid) {
    int lane = tid & 63, wid = tid >> 6;
    int total = nrows * 8;
    for (int b0 = 0; b0 < total; b0 += 512) {
        int g = b0 + wid * 64 + lane;
        int row = g >> 3;
        int ck = (g & 7) ^ (row & 7);
        size_t srow = rowmap ? (size_t)rowmap[rowbase + row] : (size_t)(rowbase + row);
        const ushort* gp = src + srow * pitch + kbase + ck * 8;
        ushort* lp = lds + (size_t)(b0 + wid * 64) * 8;   // wave-uniform
        __builtin_amdgcn_global_load_lds(
            (const __attribute__((address_space(1))) unsigned int*)gp,
            (__attribute__((address_space(3))) unsigned int*)lp, 16, 0, 0);
    }
}

__device__ __forceinline__ short8 frag_ld(const ushort* lds, int row, int kc, int lane) {
    int w0 = (kc * 16 + ((lane >> 4) << 2)) ^ ((row & 7) << 2);
    return *(const short8*)((const char*)lds + row * 128 + w0 * 4);
}

// ---------- stage 1 v3: fused LN + FFN + rot via split-bf16 MFMA ----------
__global__ __launch_bounds__(512) void k_stage1(
    const float* __restrict__ x, const float* __restrict__ g, const float* __restrict__ be,
    const float* __restrict__ b1, const float* __restrict__ b2,
    const ushort* __restrict__ w1h, const ushort* __restrict__ w1l,
    const ushort* __restrict__ w2h, const ushort* __restrict__ w2l,
    const ushort* __restrict__ rth, const ushort* __restrict__ rtl,
    const int* __restrict__ mski,
    ushort* __restrict__ xn_out, float* __restrict__ xd_out, int* __restrict__ bin_out,
    int* __restrict__ fixlist, int* __restrict__ fixcnt)
{
    __shared__ ushort lXh[4 * 64 * 64];
    __shared__ ushort lXl[4 * 64 * 64];
    __shared__ ushort lWh[2][128 * 64];
    __shared__ ushort lWl[2][128 * 64];
    int tid = threadIdx.x, lane = tid & 63, wid = tid >> 6;
    int base = blockIdx.x * 64;
    int l15 = lane & 15;
    int r4 = (lane >> 4) * 4;

    stage_async(w1h, 256, nullptr, 0, 0, lWh[0], 128, tid);
    stage_async(w1l, 256, nullptr, 0, 0, lWl[0], 128, tid);

    {   // phase 0: LN (8 threads/point)
        int row = tid >> 3, sub = tid & 7;
        const float* xr = x + (size_t)(base + row) * FF + sub * 32;
        float v[32];
        float s = 0.f;
        #pragma unroll
        for (int q = 0; q < 8; ++q) {
            float4 f = *(const float4*)(xr + q * 4);
            v[q*4+0] = f.x; v[q*4+1] = f.y; v[q*4+2] = f.z; v[q*4+3] = f.w;
            s += f.x + f.y + f.z + f.w;
        }
        s += __shfl_xor(s, 1, 8); s += __shfl_xor(s, 2, 8); s += __shfl_xor(s, 4, 8);
        float mu = s * (1.f / 256.f);
        float s2 = 0.f;
        #pragma unroll
        for (int q = 0; q < 32; ++q) { float d = v[q] - mu; s2 += d * d; }
        s2 += __shfl_xor(s2, 1, 8); s2 += __shfl_xor(s2, 2, 8); s2 += __shfl_xor(s2, 4, 8);
        float rs = 1.0f / sqrtf(s2 * (1.f / 256.f) + 1e-6f);
        int kb = sub >> 1;
        ushort* xo = xn_out + (size_t)(base + row) * FF + sub * 32;
        #pragma unroll
        for (int j = 0; j < 4; ++j) {
            int i0 = sub * 32 + j * 8;
            float4 g0 = *(const float4*)(g + i0);
            float4 g1 = *(const float4*)(g + i0 + 4);
            float4 e0 = *(const float4*)(be + i0);
            float4 e1 = *(const float4*)(be + i0 + 4);
            float gv[8] = {g0.x,g0.y,g0.z,g0.w,g1.x,g1.y,g1.z,g1.w};
            float ev[8] = {e0.x,e0.y,e0.z,e0.w,e1.x,e1.y,e1.z,e1.w};
            ushort hh[8], ll[8];
            #pragma unroll
            for (int c = 0; c < 8; ++c) {
                float xv = (v[j*8+c] - mu) * rs * gv[c] + ev[c];
                ushort h = f2b(xv);
                hh[c] = h;
                ll[c] = f2b(xv - b2f(h));
            }
            uint4 uh = pack8(hh), ul = pack8(ll);
            *(uint4*)(xo + j * 8) = uh;
            int wg = (sub & 1) * 4 + j;
            int w0 = (wg * 4) ^ ((row & 7) << 2);
            *(uint4*)((char*)lXh + kb * 8192 + row * 128 + w0 * 4) = uh;
            *(uint4*)((char*)lXl + kb * 8192 + row * 128 + w0 * 4) = ul;
        }
    }
    __syncthreads();

    int wm = (wid >> 2) * 32, wn = (wid & 3) * 32;
    floatx4 zf = {0.f, 0.f, 0.f, 0.f};

    // GEMM1: h = elu(xn @ w1 + b1)
    floatx4 acc[2][2];
    #pragma unroll
    for (int m = 0; m < 2; m++)
        #pragma unroll
        for (int n = 0; n < 2; n++) acc[m][n] = zf;
    for (int kb = 0; kb < 4; ++kb) {
        if (kb < 3) {
            stage_async(w1h, 256, nullptr, 0, (size_t)(kb + 1) * 64, lWh[(kb + 1) & 1], 128, tid);
            stage_async(w1l, 256, nullptr, 0, (size_t)(kb + 1) * 64, lWl[(kb + 1) & 1], 128, tid);
        }
        #pragma unroll
        for (int kc = 0; kc < 2; ++kc) {
            short8 ah[2], al[2], bh[2], bl[2];
            #pragma unroll
            for (int m = 0; m < 2; m++) {
                ah[m] = frag_ld(lXh + kb * 4096, wm + m * 16 + l15, kc, lane);
                al[m] = frag_ld(lXl + kb * 4096, wm + m * 16 + l15, kc, lane);
            }
            #pragma unroll
            for (int n = 0; n < 2; n++) {
                bh[n] = frag_ld(lWh[kb & 1], wn + n * 16 + l15, kc, lane);
                bl[n] = frag_ld(lWl[kb & 1], wn + n * 16 + l15, kc, lane);
            }
            #pragma unroll
            for (int m = 0; m < 2; m++)
                #pragma unroll
                for (int n = 0; n < 2; n++) {
                    acc[m][n] = __builtin_amdgcn_mfma_f32_16x16x32_bf16(ah[m], bh[n], acc[m][n], 0, 0, 0);
                    acc[m][n] = __builtin_amdgcn_mfma_f32_16x16x32_bf16(ah[m], bl[n], acc[m][n], 0, 0, 0);
                    acc[m][n] = __builtin_amdgcn_mfma_f32_16x16x32_bf16(al[m], bh[n], acc[m][n], 0, 0, 0);
                }
        }
        __syncthreads();
    }
    stage_async(w2h, 128, nullptr, 0, 0, lWh[0], 128, tid);
    stage_async(w2l, 128, nullptr, 0, 0, lWl[0], 128, tid);
    {
        #pragma unroll
        for (int n = 0; n < 2; n++) {
            int cg = wn + n * 16 + l15;
            float b1v = b1[cg];
            int slab = cg >> 6, c64 = cg & 63;
            int wg = c64 >> 3, e = c64 & 7;
            #pragma unroll
            for (int m = 0; m < 2; m++) {
                #pragma unroll
                for (int i = 0; i < 4; i++) {
                    int r = wm + m * 16 + r4 + i;
                    float hv = acc[m][n][i] + b1v;
                    hv = (hv > 0.f) ? hv : expm1f(hv);
                    ushort h = f2b(hv);
                    int w0 = (wg * 4) ^ ((r & 7) << 2);
                    int idx = slab * 4096 + r * 64 + w0 * 2 + e;
                    lXh[idx] = h;
                    lXl[idx] = f2b(hv - b2f(h));
                }
            }
        }
    }
    __syncthreads();

    // GEMM2: xd = h @ w2 + b2
    floatx4 acc2[2][2];
    #pragma unroll
    for (int m = 0; m < 2; m++)
        #pragma unroll
        for (int n = 0; n < 2; n++) acc2[m][n] = zf;
    for (int kb = 0; kb < 2; ++kb) {
        if (kb == 0) {
            stage_async(w2h, 128, nullptr, 0, 64, lWh[1], 128, tid);
            stage_async(w2l, 128, nullptr, 0, 64, lWl[1], 128, tid);
        }
        #pragma unroll
        for (int kc = 0; kc < 2; ++kc) {
            short8 ah[2], al[2], bh[2], bl[2];
            #pragma unroll
            for (int m = 0; m < 2; m++) {
                ah[m] = frag_ld(lXh + kb * 4096, wm + m * 16 + l15, kc, lane);
                al[m] = frag_ld(lXl + kb * 4096, wm + m * 16 + l15, kc, lane);
            }
            #pragma unroll
            for (int n = 0; n < 2; n++) {
                bh[n] = frag_ld(lWh[kb], wn + n * 16 + l15, kc, lane);
                bl[n] = frag_ld(lWl[kb], wn + n * 16 + l15, kc, lane);
            }
            #pragma unroll
            for (int m = 0; m < 2; m++)
                #pragma unroll
                for (int n = 0; n < 2; n++) {
                    acc2[m][n] = __builtin_amdgcn_mfma_f32_16x16x32_bf16(ah[m], bh[n], acc2[m][n], 0, 0, 0);
                    acc2[m][n] = __builtin_amdgcn_mfma_f32_16x16x32_bf16(ah[m], bl[n], acc2[m][n], 0, 0, 0);
                    acc2[m][n] = __builtin_amdgcn_mfma_f32_16x16x32_bf16(al[m], bh[n], acc2[m][n], 0, 0, 0);
                }
        }
        __syncthreads();
    }
    stage_async(rth, 128, nullptr, 0, 0, lWh[0], 64, tid);
    stage_async(rtl, 128, nullptr, 0, 0, lWl[0], 64, tid);
    stage_async(rth, 128, nullptr, 0, 64, lWh[1], 64, tid);
    stage_async(rtl, 128, nullptr, 0, 64, lWl[1], 64, tid);
    {
        #pragma unroll
        for (int n = 0; n < 2; n++) {
            int cg = wn + n * 16 + l15;
            float b2v = b2[cg];
            int slab = 2 + (cg >> 6), c64 = cg & 63;
            int wg = c64 >> 3, e = c64 & 7;
            #pragma unroll
            for (int m = 0; m < 2; m++) {
                #pragma unroll
                for (int i = 0; i < 4; i++) {
                    int r = wm + m * 16 + r4 + i;
                    float xv = acc2[m][n][i] + b2v;
                    xd_out[(size_t)(base + r) * DDIM + cg] = xv;
                    ushort h = f2b(xv);
                    int w0 = (wg * 4) ^ ((r & 7) << 2);
                    int idx = slab * 4096 + r * 64 + w0 * 2 + e;
                    lXh[idx] = h;
                    lXl[idx] = f2b(xv - b2f(h));
                }
            }
        }
    }
    __syncthreads();

    // GEMM3: mul = xd @ rot
    floatx4 acc3[2];
    acc3[0] = zf; acc3[1] = zf;
    int wm3 = (wid >> 2) * 32, wn3 = (wid & 3) * 16;
    for (int kb = 0; kb < 2; ++kb) {
        #pragma unroll
        for (int kc = 0; kc < 2; ++kc) {
            short8 ah[2], al[2], bh, bl;
            #pragma unroll
            for (int m = 0; m < 2; m++) {
                ah[m] = frag_ld(lXh + (2 + kb) * 4096, wm3 + m * 16 + l15, kc, lane);
                al[m] = frag_ld(lXl + (2 + kb) * 4096, wm3 + m * 16 + l15, kc, lane);
            }
            bh = frag_ld(lWh[kb], wn3 + l15, kc, lane);
            bl = frag_ld(lWl[kb], wn3 + l15, kc, lane);
            #pragma unroll
            for (int m = 0; m < 2; m++) {
                acc3[m] = __builtin_amdgcn_mfma_f32_16x16x32_bf16(ah[m], bh, acc3[m], 0, 0, 0);
                acc3[m] = __builtin_amdgcn_mfma_f32_16x16x32_bf16(ah[m], bl, acc3[m], 0, 0, 0);
                acc3[m] = __builtin_amdgcn_mfma_f32_16x16x32_bf16(al[m], bh, acc3[m], 0, 0, 0);
            }
        }
    }
    __syncthreads();
    float* lMul = (float*)(&lWh[0][0]);
    {
        #pragma unroll
        for (int m = 0; m < 2; m++)
            #pragma unroll
            for (int i = 0; i < 4; i++) {
                int r = wm3 + m * 16 + r4 + i;
                lMul[r * 65 + wn3 + l15] = acc3[m][i];
            }
    }
    __syncthreads();

    {   // top-2 argmax over [mul, -mul], margin flag
        int p = tid >> 3, q = tid & 7;
        float v1 = -1e30f, v2 = -1e30f; int i1 = 1 << 29;
        #pragma unroll
        for (int j = 0; j < 8; ++j) {
            int c = q * 8 + j;
            if (c < 50) {
                float m = lMul[p * 65 + c];
                float wv, lv; int wi, li;
                if (m >= 0.f) { wv = m; wi = c; lv = -m; li = 50 + c; }
                else          { wv = -m; wi = 50 + c; lv = m; li = c; }
                if (wv > v1 || (wv == v1 && wi < i1)) { v2 = v1; v1 = wv; i1 = wi; }
                else if (wv > v2) v2 = wv;
                if (lv > v1 || (lv == v1 && li < i1)) { v2 = v1; v1 = lv; i1 = li; }
                else if (lv > v2) v2 = lv;
            }
        }
        #pragma unroll
        for (int off = 1; off < 8; off <<= 1) {
            float o1 = __shfl_xor(v1, off, 8);
            int   oi = __shfl_xor(i1, off, 8);
            float o2 = __shfl_xor(v2, off, 8);
            bool take = (o1 > v1) || (o1 == v1 && oi < i1);
            float small = take ? v1 : o1;
            if (take) { v1 = o1; i1 = oi; }
            v2 = fmaxf(fmaxf(v2, o2), small);
        }
        if (q == 0) {
            int pt = base + p;
            bin_out[pt] = i1 + (mski[pt] ? 0 : (NBINS - 1));
            float tau = 3e-4f + 1.5e-3f * v1;
            if (v1 - v2 < tau) {
                int pos = atomicAdd(fixcnt, 1);
                fixlist[pos] = pt;
            }
        }
    }
}

// ---------- fp64 fixup for margin-flagged points ----------
__global__ __launch_bounds__(64) void k_fixup(
    const float* __restrict__ x, const float* __restrict__ g, const float* __restrict__ be,
    const float* __restrict__ w1, const float* __restrict__ b1,
    const float* __restrict__ w2, const float* __restrict__ b2,
    const float* __restrict__ rot, const int* __restrict__ mski,
    const int* __restrict__ fixlist, const int* __restrict__ fixcnt,
    int* __restrict__ bin_out)
{
    __shared__ double xn_s[256];
    __shared__ double h_s[128];
    __shared__ double xd_s[128];
    int lane = threadIdx.x;
    int n = fixcnt[0];
    for (int e = blockIdx.x; e < n; e += gridDim.x) {
        int pt = fixlist[e];
        const float* xr = x + (size_t)pt * FF;
        double s = 0.0, xv[4];
        #pragma unroll
        for (int q = 0; q < 4; q++) { xv[q] = (double)xr[lane + q * 64]; s += xv[q]; }
        #pragma unroll
        for (int off = 1; off < 64; off <<= 1) s += __shfl_xor(s, off, 64);
        double mu = s * (1.0 / 256.0);
        double s2 = 0.0;
        #pragma unroll
        for (int q = 0; q < 4; q++) { double d = xv[q] - mu; s2 += d * d; }
        #pragma unroll
        for (int off = 1; off < 64; off <<= 1) s2 += __shfl_xor(s2, off, 64);
        double rs = 1.0 / sqrt(s2 * (1.0 / 256.0) + 1e-6);
        #pragma unroll
        for (int q = 0; q < 4; q++) {
            int i = lane + q * 64;
            xn_s[i] = (xv[q] - mu) * rs * (double)g[i] + (double)be[i];
        }
        __syncthreads();
        #pragma unroll
        for (int q = 0; q < 2; q++) {
            int j = lane + q * 64;
            double a0 = 0.0, a1 = 0.0;
            for (int k = 0; k < FF; k += 2) {
                a0 += xn_s[k] * (double)w1[k * DDIM + j];
                a1 += xn_s[k + 1] * (double)w1[(k + 1) * DDIM + j];
            }
            double a = (double)b1[j] + a0 + a1;
            h_s[j] = (a > 0.0) ? a : expm1(a);
        }
        __syncthreads();
        #pragma unroll
        for (int q = 0; q < 2; q++) {
            int j = lane + q * 64;
            double a0 = 0.0, a1 = 0.0;
            for (int k = 0; k < DDIM; k += 2) {
                a0 += h_s[k] * (double)w2[k * DDIM + j];
                a1 += h_s[k + 1] * (double)w2[(k + 1) * DDIM + j];
            }
            xd_s[j] = (double)b2[j] + a0 + a1;
        }
        __syncthreads();
        double v; int idx;
        if (lane < NROT) {
            double m = 0.0;
            for (int k = 0; k < DDIM; k++) m += xd_s[k] * (double)rot[k * 100 + lane];
            if (m >= 0.0) { v = m; idx = lane; } else { v = -m; idx = 50 + lane; }
        } else { v = -1e300; idx = 1 << 29; }
        #pragma unroll
        for (int off = 1; off < 64; off <<= 1) {
            double ov = __shfl_xor(v, off, 64);
            int oi = __shfl_xor(idx, off, 64);
            if (ov > v || (ov == v && oi < idx)) { v = ov; idx = oi; }
        }
        if (lane == 0) bin_out[pt] = idx + (mski[pt] ? 0 : (NBINS - 1));
        __syncthreads();
    }
}

// ---------- binning: stable counting sort ----------
__global__ void k_count(const int* __restrict__ bin, int* __restrict__ hist) {
    int c = blockIdx.x % 100, b = blockIdx.x / 100;
    int t = threadIdx.x;
    int v = bin[b * NN + c * BSIZE + t];
    atomicAdd(&hist[(b * 100 + c) * NIDS + v], 1);
}

__global__ void k_offsets(const int* __restrict__ hist, int* __restrict__ offs) {
    __shared__ int tot[NIDS];
    __shared__ int start[NIDS];
    int b = blockIdx.x, v = threadIdx.x;
    if (v < NIDS) {
        int s = 0;
        for (int c = 0; c < 100; c++) s += hist[(b * 100 + c) * NIDS + v];
        tot[v] = s;
    }
    __syncthreads();
    if (threadIdx.x == 0) {
        int run = 0;
        for (int i = 0; i < NIDS; i++) { start[i] = run; run += tot[i]; }
    }
    __syncthreads();
    if (v < NIDS) {
        int run = start[v];
        for (int c = 0; c < 100; c++) {
            offs[(b * 100 + c) * NIDS + v] = run;
            run += hist[(b * 100 + c) * NIDS + v];
        }
    }
}

__global__ void k_scatter(const int* __restrict__ bin, const int* __restrict__ offs,
                          const int* __restrict__ mski, int* __restrict__ flat,
                          float* __restrict__ mf) {
    __shared__ int sv[BSIZE];
    int c = blockIdx.x % 100, b = blockIdx.x / 100;
    int t = threadIdx.x;
    int n = c * BSIZE + t;
    int v = bin[b * NN + n];
    sv[t] = v;
    __syncthreads();
    int rank = 0;
    for (int u = 0; u < t; u++) rank += (sv[u] == v);
    int r = offs[(b * 100 + c) * NIDS + v] + rank;
    flat[b * NN + r] = b * NN + n;
    mf[b * NN + r] = mski[b * NN + n] ? 1.0f : 0.0f;
}

// ---------- per-bin pairwise kernel matrix (fp32 tiled), fused deg/norm ----------
__global__ __launch_bounds__(256) void k_dm(const float* __restrict__ xd, const int* __restrict__ flat,
                                            const float* __restrict__ mf, ushort* __restrict__ dmb,
                                            float* __restrict__ norm) {
    __shared__ float Xs[128 * 64];
    __shared__ float na[128];
    __shared__ float ml[128];
    __shared__ float ps[128 * 16];
    int g = blockIdx.x, tid = threadIdx.x;
    int tx = tid & 15, ty = tid >> 4;
    int rowbase = g * 128;
    if (tid < 128) ml[tid] = mf[rowbase + tid];
    float acc[8][8];
    #pragma unroll
    for (int i = 0; i < 8; i++)
        #pragma unroll
        for (int j = 0; j < 8; j++) acc[i][j] = 0.f;
    float nap[8];
    #pragma unroll
    for (int j = 0; j < 8; j++) nap[j] = 0.f;

    for (int kh = 0; kh < 2; ++kh) {
        __syncthreads();
        for (int q = 0; q < 8; ++q) {
            int gg = q * 256 + tid;
            int row = gg >> 4, f4 = gg & 15;
            int srow = flat[rowbase + row];
            float4 v = *(const float4*)(xd + (size_t)srow * DDIM + kh * 64 + f4 * 4);
            int f4s = f4 ^ ((row >> 3) & 7);
            *(float4*)(Xs + row * 64 + f4s * 4) = v;
        }
        __syncthreads();
        for (int k4 = 0; k4 < 16; ++k4) {
            int sa = (k4 ^ (ty & 7)) << 2;
            int sb = (k4 ^ (tx & 7)) << 2;
            float4 av[8], bv[8];
            #pragma unroll
            for (int i = 0; i < 8; i++) av[i] = *(const float4*)(Xs + (ty * 8 + i) * 64 + sa);
            #pragma unroll
            for (int j = 0; j < 8; j++) bv[j] = *(const float4*)(Xs + (tx * 8 + j) * 64 + sb);
            if (ty == 0) {
                #pragma unroll
                for (int j = 0; j < 8; j++)
                    nap[j] += bv[j].x * bv[j].x + bv[j].y * bv[j].y + bv[j].z * bv[j].z + bv[j].w * bv[j].w;
            }
            #pragma unroll
            for (int i = 0; i < 8; i++)
                #pragma unroll
                for (int j = 0; j < 8; j++)
                    acc[i][j] += av[i].x * bv[j].x + av[i].y * bv[j].y + av[i].z * bv[j].z + av[i].w * bv[j].w;
        }
    }
    if (ty == 0) {
        #pragma unroll
        for (int j = 0; j < 8; j++) na[tx * 8 + j] = nap[j];
    }
    __syncthreads();
    #pragma unroll
    for (int i = 0; i < 8; ++i) {
        int r = ty * 8 + i;
        float nai = na[r], mi = ml[r];
        float rs = 0.f;
        ushort o[8];
        #pragma unroll
        for (int j = 0; j < 8; ++j) {
            int c = tx * 8 + j;
            float D2 = nai - 2.f * acc[i][j] + na[c];
            float dv = expf(-0.1f * sqrtf(fmaxf(D2, 1e-6f)));
            dv *= mi * ml[c];
            rs += dv;
            o[j] = f2b(dv);
        }
        *(uint4*)(dmb + (size_t)g * 16384 + r * 128 + tx * 8) = pack8(o);
        ps[r * 16 + tx] = rs;
    }
    __syncthreads();
    if (tid < 128) {
        float deg = 0.f;
        for (int t2 = 0; t2 < 16; ++t2) deg += ps[tid * 16 + t2];
        deg = fminf(deg, 1000.0f);
        float nv = 1.0f / sqrtf(deg + 1e-6f);
        norm[rowbase + tid] = nv * ml[tid];
    }
}

// ---------- fused per-layer graph conv v2: merged triple GEMM, 80KB LDS, 2 blocks/CU ----------
// block = (bin g, n-quarter nh). 512 threads, 8 waves = 4 M-groups x 2 N-groups (32x32 tiles).
template<int LAYER>
__global__ __launch_bounds__(512, 4) void k_layer(
    const ushort* __restrict__ A, const int* __restrict__ rowmap,
    const ushort* __restrict__ ThT, const ushort* __restrict__ WhT, const ushort* __restrict__ WtT,
    const float* __restrict__ bt, const ushort* __restrict__ dmb,
    const float* __restrict__ norm, const float* __restrict__ mf,
    ushort* __restrict__ outb, float* __restrict__ outf, const int* __restrict__ flatscat)
{
    __shared__ char smem[81920];
    // GEMM phase: lA ping = smem[0..32K), B slabs = smem[32K..80K) (6 x 8KB: th0 th1 wh0 wh1 wt0 wt1)
    // post-GEMM:  lT (2 x 8KB j-slabs) aliases smem[0..16K); dm (2 x 16KB) aliases smem[32K..64K)
    // epilogue:   bounce aliases smem[0..16K)
    ushort* lAbuf = (ushort*)smem;                 // +kb&1 ? 8192 : 0 (ushort idx)
    ushort* lB    = (ushort*)(smem + 32768);       // slab s at lB + s*4096
    ushort* lT    = (ushort*)smem;                 // slab kb at lT + kb*4096
    ushort* ldm   = (ushort*)(smem + 32768);       // slab kb at ldm + kb*8192

    int tid = threadIdx.x, lane = tid & 63, wid = tid >> 6;
    int g = blockIdx.x, nh = blockIdx.y;
    int rowbase = g * 128, nbase = nh * 64;
    int l15 = lane & 15;
    int r4 = (lane >> 4) * 4;
    int wm = (wid >> 1) * 32, wn = (wid & 1) * 32;
    const ushort* dmg = dmb + (size_t)g * 16384;
    floatx4 zf = {0.f, 0.f, 0.f, 0.f};

    // prologue: A slab0 + th/wh/wt slab0
    stage_async(A, 256, rowmap, rowbase, 0, lAbuf, 128, tid);
    stage_async(ThT, 256, nullptr, nbase, 0, lB + 0 * 4096, 64, tid);
    stage_async(WhT, 256, nullptr, nbase, 0, lB + 2 * 4096, 64, tid);
    stage_async(WtT, 256, nullptr, nbase, 0, lB + 4 * 4096, 64, tid);
    __syncthreads();

    // ---- merged GEMM: T = A@Th, H = A@Wh, G = A@Wt  (M=128, N=64, K=256) ----
    floatx4 accT[2][2], accH[2][2], accG[2][2];
    #pragma unroll
    for (int m = 0; m < 2; m++)
        #pragma unroll
        for (int n = 0; n < 2; n++) { accT[m][n] = zf; accH[m][n] = zf; accG[m][n] = zf; }
    for (int kb = 0; kb < 4; ++kb) {
        if (kb < 3) {
            int pp = (kb + 1) & 1;
            stage_async(A, 256, rowmap, rowbase, (size_t)(kb + 1) * 64, lAbuf + pp * 8192, 128, tid);
            stage_async(ThT, 256, nullptr, nbase, (size_t)(kb + 1) * 64, lB + (0 + pp) * 4096, 64, tid);
            stage_async(WhT, 256, nullptr, nbase, (size_t)(kb + 1) * 64, lB + (2 + pp) * 4096, 64, tid);
            stage_async(WtT, 256, nullptr, nbase, (size_t)(kb + 1) * 64, lB + (4 + pp) * 4096, 64, tid);
        }
        const ushort* lA = lAbuf + (kb & 1) * 8192;
        const ushort* sTh = lB + (0 + (kb & 1)) * 4096;
        const ushort* sWh = lB + (2 + (kb & 1)) * 4096;
        const ushort* sWt = lB + (4 + (kb & 1)) * 4096;
        #pragma unroll
        for (int kc = 0; kc < 2; ++kc) {
            short8 a[2], bt_[2], bh_[2], bg_[2];
            #pragma unroll
            for (int m = 0; m < 2; m++) a[m] = frag_ld(lA, wm + m * 16 + l15, kc, lane);
            #pragma unroll
            for (int n = 0; n < 2; n++) {
                bt_[n] = frag_ld(sTh, wn + n * 16 + l15, kc, lane);
                bh_[n] = frag_ld(sWh, wn + n * 16 + l15, kc, lane);
                bg_[n] = frag_ld(sWt, wn + n * 16 + l15, kc, lane);
            }
            #pragma unroll
            for (int m = 0; m < 2; m++)
                #pragma unroll
                for (int n = 0; n < 2; n++) {
                    accT[m][n] = __builtin_amdgcn_mfma_f32_16x16x32_bf16(a[m], bt_[n], accT[m][n], 0, 0, 0);
                    accH[m][n] = __builtin_amdgcn_mfma_f32_16x16x32_bf16(a[m], bh_[n], accH[m][n], 0, 0, 0);
                    accG[m][n] = __builtin_amdgcn_mfma_f32_16x16x32_bf16(a[m], bg_[n], accG[m][n], 0, 0, 0);
                }
        }
        __syncthreads();
    }

    // stage dm into freed B region (async, overlaps the T^T writes below)
    stage_async(dmg, 128, nullptr, 0, 0, ldm, 128, tid);
    stage_async(dmg, 128, nullptr, 0, 64, ldm + 8192, 128, tid);

    // T^T (scaled by norm, bf16, frag-swizzled) into lT j-slabs (aliases dead lA)
    {
        #pragma unroll
        for (int m = 0; m < 2; m++) {
            float4 nv = *(const float4*)(norm + rowbase + wm + m * 16 + r4);
            float nvv[4] = {nv.x, nv.y, nv.z, nv.w};
            int jloc0 = wm + m * 16 + r4;
            int jb = jloc0 >> 6, jj = jloc0 & 63;
            #pragma unroll
            for (int n = 0; n < 2; n++) {
                int cloc = wn + n * 16 + l15;
                char* bp = (char*)(lT + jb * 4096) + cloc * 128;
                int cx = (cloc & 7) << 2;
                ushort t0 = f2b(accT[m][n][0] * nvv[0]);
                ushort t1 = f2b(accT[m][n][1] * nvv[1]);
                ushort t2 = f2b(accT[m][n][2] * nvv[2]);
                ushort t3 = f2b(accT[m][n][3] * nvv[3]);
                *(unsigned*)(bp + ((((jj >> 1) + 0) ^ cx) << 2)) = (unsigned)t0 | ((unsigned)t1 << 16);
                *(unsigned*)(bp + ((((jj >> 1) + 1) ^ cx) << 2)) = (unsigned)t2 | ((unsigned)t3 << 16);
            }
        }
    }
    __syncthreads();

    // ---- phase A: FH = dm @ T  (M=128, N=64, K=128) ----
    floatx4 accFH[2][2];
    #pragma unroll
    for (int m = 0; m < 2; m++) { accFH[m][0] = zf; accFH[m][1] = zf; }
    for (int kb = 0; kb < 2; ++kb) {
        #pragma unroll
        for (int kc = 0; kc < 2; ++kc) {
            short8 a[2], b[2];
            #pragma unroll
            for (int m = 0; m < 2; m++) a[m] = frag_ld(ldm + kb * 8192, wm + m * 16 + l15, kc, lane);
            #pragma unroll
            for (int n = 0; n < 2; n++) b[n] = frag_ld(lT + kb * 4096, wn + n * 16 + l15, kc, lane);
            #pragma unroll
            for (int m = 0; m < 2; m++)
                #pragma unroll
                for (int n = 0; n < 2; n++)
                    accFH[m][n] = __builtin_amdgcn_mfma_f32_16x16x32_bf16(a[m], b[n], accFH[m][n], 0, 0, 0);
        }
    }
    __syncthreads();   // lT dead; bounce region reuse safe

    // ---- epilogue: gate/elu combine + coalesced store (wave-local bounce at smem[0..16K)) ----
    for (int m = 0; m < 2; m++) {
        int r0l = wm + m * 16 + r4;
        int r0g = rowbase + r0l;
        float4 mv = *(const float4*)(mf + r0g);
        float4 nv = *(const float4*)(norm + r0g);
        float mvv[4] = {mv.x, mv.y, mv.z, mv.w};
        float nvv[4] = {nv.x, nv.y, nv.z, nv.w};
        float vals[2][4];
        #pragma unroll
        for (int n = 0; n < 2; n++) {
            int cg = nbase + wn + n * 16 + l15;
            float btc = bt[cg];
            #pragma unroll
            for (int i = 0; i < 4; i++) {
                float gate = 1.f / (1.f + expf(-(accG[m][n][i] + btc)));
                float fh = accFH[m][n][i] * nvv[i];
                float het = mvv[i] * accH[m][n][i];
                float o = gate * fh + (1.f - gate) * het;
                o = (o > 0.f) ? o : expm1f(o);
                vals[n][i] = o * mvv[i];
            }
        }
        if (LAYER == 0) {
            ushort* Ls = (ushort*)smem;
            int bbase = wid * 512;
            #pragma unroll
            for (int n = 0; n < 2; n++)
                #pragma unroll
                for (int i = 0; i < 4; i++)
                    Ls[bbase + (r4 + i) * 32 + n * 16 + l15] = f2b(vals[n][i]);
            __builtin_amdgcn_s_waitcnt(0);  // lgkmcnt drain (wave-local RAW)
            #pragma unroll
            for (int it = 0; it < 2; ++it) {
                int lr = (lane >> 3) + it * 8;
                int lc4 = (lane & 7) * 4;
                ushort4 tv = *(const ushort4*)(Ls + bbase + lr * 32 + lc4);
                int rg = rowbase + wm + m * 16 + lr;
                *(ushort4*)(outb + (size_t)rg * 256 + nbase + wn + lc4) = tv;
            }
        } else {
            float* Ls = (float*)smem;
            int bbase = wid * 512;
            #pragma unroll
            for (int n = 0; n < 2; n++)
                #pragma unroll
                for (int i = 0; i < 4; i++)
                    Ls[bbase + (r4 + i) * 32 + n * 16 + l15] = vals[n][i];
            __builtin_amdgcn_s_waitcnt(0);
            #pragma unroll
            for (int it = 0; it < 2; ++it) {
                int lr = (lane >> 3) + it * 8;
                int lc4 = (lane & 7) * 4;
                float4 tv = *(const float4*)(Ls + bbase + lr * 32 + lc4);
                int rg = rowbase + wm + m * 16 + lr;
                int dst = flatscat[rg];
                *(float4*)(outf + (size_t)dst * 256 + nbase + wn + lc4) = tv;
            }
        }
    }
}

extern "C" void kernel_launch(void* const* d_in, const int* in_sizes, int n_in,
                              void* d_out, int out_size, void* d_ws, size_t ws_size,
                              hipStream_t stream) {
    const float* x    = (const float*)d_in[0];
    const void*  msk  = d_in[1];
    const float* ln_g = (const float*)d_in[2];
    const float* ln_b = (const float*)d_in[3];
    const float* w1   = (const float*)d_in[4];
    const float* b1   = (const float*)d_in[5];
    const float* w2   = (const float*)d_in[6];
    const float* b2   = (const float*)d_in[7];
    const float* rot  = (const float*)d_in[8];
    const float* th0  = (const float*)d_in[9];
    const float* wh0  = (const float*)d_in[10];
    const float* wt0  = (const float*)d_in[11];
    const float* bt0  = (const float*)d_in[12];
    const float* th1  = (const float*)d_in[13];
    const float* wh1  = (const float*)d_in[14];
    const float* wt1  = (const float*)d_in[15];
    const float* bt1  = (const float*)d_in[16];

    char* ws = (char*)d_ws;
    ushort* out0 = (ushort*)(ws + OFF_OUT0);
    ushort* dmb  = (ushort*)(ws + OFF_DMB);
    ushort* wb   = (ushort*)(ws + OFF_WB);
    ushort* wbth0 = wb + 0 * 65536;
    ushort* wbwh0 = wb + 1 * 65536;
    ushort* wbwt0 = wb + 2 * 65536;
    ushort* wbth1 = wb + 3 * 65536;
    ushort* wbwh1 = wb + 4 * 65536;
    ushort* wbwt1 = wb + 5 * 65536;
    float* norm = (float*)(ws + OFF_NORM);
    float* mf   = (float*)(ws + OFF_MF);
    int*   bin  = (int*)(ws + OFF_BIN);
    int*   flat = (int*)(ws + OFF_FLAT);
    int*   mski = (int*)(ws + OFF_MSKI);
    int*   hist = (int*)(ws + OFF_HIST);
    int*   offs = (int*)(ws + OFF_OFFS);
    int*   flag = (int*)(ws + OFF_FLAG);
    int*   fixcnt = (int*)(ws + OFF_CNT);
    int*   fixlist = (int*)(ws + OFF_LIST);
    ushort* w1h = (ushort*)(ws + OFF_W1H);
    ushort* w1l = (ushort*)(ws + OFF_W1L);
    ushort* w2h = (ushort*)(ws + OFF_W2H);
    ushort* w2l = (ushort*)(ws + OFF_W2L);
    ushort* rth = (ushort*)(ws + OFF_RH);
    ushort* rtl = (ushort*)(ws + OFF_RL);
    float*  xd  = (float*)d_out;
    ushort* xnb = (ushort*)((char*)d_out + (size_t)PTS * DDIM * 4);

    hipMemsetAsync(hist, 0, HISTBYTES, stream);
    hipMemsetAsync(fixcnt, 0, 4, stream);
    k_maskflag<<<1, 256, 0, stream>>>((const int*)msk, flag);
    k_masknorm<<<PTS / 256, 256, 0, stream>>>(msk, flag, mski);
    k_wprep<<<dim3(16, 6), 256, 0, stream>>>(th0, wh0, wt0, th1, wh1, wt1,
                                             wbth0, wbwh0, wbwt0, wbth1, wbwh1, wbwt1);
    k_wsplit<<<8, 256, 0, stream>>>(w1, 256, 128, 128, 128, w1h, w1l);
    k_wsplit<<<4, 256, 0, stream>>>(w2, 128, 128, 128, 128, w2h, w2l);
    k_wsplit<<<2, 256, 0, stream>>>(rot, 128, 64, 100, 50, rth, rtl);
    k_stage1<<<PTS / 64, 512, 0, stream>>>(x, ln_g, ln_b, b1, b2,
                                           w1h, w1l, w2h, w2l, rth, rtl, mski,
                                           xnb, xd, bin, fixlist, fixcnt);
    k_fixup<<<4096, 64, 0, stream>>>(x, ln_g, ln_b, w1, b1, w2, b2, rot, mski,
                                     fixlist, fixcnt, bin);
    k_count<<<800, 128, 0, stream>>>(bin, hist);
    k_offsets<<<8, 256, 0, stream>>>(hist, offs);
    k_scatter<<<800, 128, 0, stream>>>(bin, offs, mski, flat, mf);
    k_dm<<<800, 256, 0, stream>>>(xd, flat, mf, dmb, norm);
    // layer 0 (fused, N=64 quarters)
    k_layer<0><<<dim3(800, 4), 512, 0, stream>>>(xnb, flat, wbth0, wbwh0, wbwt0, bt0,
                                                 dmb, norm, mf, out0, nullptr, nullptr);
    // layer 1 (fused, scattered fp32 output)
    k_layer<1><<<dim3(800, 4), 512, 0, stream>>>(out0, nullptr, wbth1, wbwh1, wbwt1, bt1,
                                                 dmb, norm, mf, nullptr, (float*)d_out, flat);
}

// Round 9
// 484.304 us; speedup vs baseline: 2.2725x; 1.0683x over previous
//
#include <hip/hip_runtime.h>
#include <math.h>

#define BB 8
#define NN 12800
#define FF 256
#define DDIM 128
#define NBINS 100
#define BSIZE 128
#define NROT 50
#define NIDS 199
#define PTS (BB*NN)            // 102400

// ---- workspace layout (bytes) ----
#define OFF_OUT0 ((size_t)157286400)    // 52428800  : out0 bf16 [102400][256]
#define OFF_DMB  ((size_t)209715200)    // 26214400  : dm bf16 [800][128][128]
#define OFF_WB   ((size_t)235929600)    // 786432    : 6 weights bf16 transposed [256][256]
#define OFF_NORM ((size_t)236716032)    // 409600
#define OFF_MF   ((size_t)237125632)    // 409600
#define OFF_BIN  ((size_t)237535232)    // 409600 (int)
#define OFF_FLAT ((size_t)237944832)    // 409600 (int)
#define OFF_MSKI ((size_t)238354432)    // 409600 (int)
#define OFF_HIST ((size_t)238764032)    // 636800 (int)
#define OFF_OFFS ((size_t)239400832)    // 636800 (int)
#define OFF_FLAG ((size_t)240037632)    // 64
#define OFF_CNT  ((size_t)240037696)    // 64
#define OFF_LIST ((size_t)240037760)    // 409600 (int)
#define OFF_W1H  ((size_t)240447360)    // 65536 : w1^T hi bf16 [128][256]
#define OFF_W1L  ((size_t)240512896)    // 65536
#define OFF_W2H  ((size_t)240578432)    // 32768 : w2^T hi bf16 [128][128]
#define OFF_W2L  ((size_t)240611200)    // 32768
#define OFF_RH   ((size_t)240643968)    // 16384 : rot^T hi bf16 [64][128]
#define OFF_RL   ((size_t)240660352)    // 16384
#define HISTBYTES (8*100*199*4)

using short8  = __attribute__((ext_vector_type(8))) short;
using floatx4 = __attribute__((ext_vector_type(4))) float;

__device__ __forceinline__ ushort f2b(float f) {
    unsigned u = __float_as_uint(f);
    unsigned r = (u + 0x7FFFu + ((u >> 16) & 1u)) >> 16;
    return (ushort)r;
}
__device__ __forceinline__ float b2f(ushort h) {
    return __uint_as_float(((unsigned)h) << 16);
}
__device__ __forceinline__ uint4 pack8(const ushort* o) {
    uint4 u;
    u.x = (unsigned)o[0] | ((unsigned)o[1] << 16);
    u.y = (unsigned)o[2] | ((unsigned)o[3] << 16);
    u.z = (unsigned)o[4] | ((unsigned)o[5] << 16);
    u.w = (unsigned)o[6] | ((unsigned)o[7] << 16);
    return u;
}

// ---------- mask dtype sniffing ----------
__global__ void k_maskflag(const int* mi, int* flag) {
    __shared__ int notInt, notFloat;
    if (threadIdx.x == 0) { notInt = 0; notFloat = 0; }
    __syncthreads();
    int v = mi[threadIdx.x];
    if (v != 0 && v != 1) atomicOr(&notInt, 1);
    if (v != 0 && v != 0x3F800000) atomicOr(&notFloat, 1);
    __syncthreads();
    if (threadIdx.x == 0) flag[0] = (!notInt) ? 0 : ((!notFloat) ? 2 : 1);
}

__global__ void k_masknorm(const void* msk, const int* flag, int* mski) {
    int i = blockIdx.x * blockDim.x + threadIdx.x;
    if (i >= PTS) return;
    int f = flag[0];
    int v;
    if (f == 0)      v = ((const int*)msk)[i] != 0;
    else if (f == 2) v = ((const float*)msk)[i] != 0.0f;
    else             v = ((const unsigned char*)msk)[i] != 0;
    mski[i] = v;
}

// ---------- weight prep: fp32 [k][n] -> bf16 transposed [n][k] (GHConv weights) ----------
__global__ __launch_bounds__(256) void k_wprep(
    const float* s0, const float* s1, const float* s2,
    const float* s3, const float* s4, const float* s5,
    ushort* d0, ushort* d1, ushort* d2, ushort* d3, ushort* d4, ushort* d5)
{
    __shared__ float Ls[64 * 65];
    const float* src; ushort* dst;
    switch (blockIdx.y) {
        case 0: src = s0; dst = d0; break;
        case 1: src = s1; dst = d1; break;
        case 2: src = s2; dst = d2; break;
        case 3: src = s3; dst = d3; break;
        case 4: src = s4; dst = d4; break;
        default: src = s5; dst = d5; break;
    }
    int t = blockIdx.x;
    int kb = (t & 3) * 64, nb = (t >> 2) * 64;
    int tid = threadIdx.x;
    for (int q = 0; q < 4; ++q) {
        int g = q * 256 + tid;
        int kl = g >> 4, f4 = g & 15;
        float4 v = *(const float4*)(src + (size_t)(kb + kl) * 256 + nb + f4 * 4);
        Ls[kl * 65 + f4 * 4 + 0] = v.x;
        Ls[kl * 65 + f4 * 4 + 1] = v.y;
        Ls[kl * 65 + f4 * 4 + 2] = v.z;
        Ls[kl * 65 + f4 * 4 + 3] = v.w;
    }
    __syncthreads();
    for (int q = 0; q < 2; ++q) {
        int g = q * 256 + tid;
        int nl = g >> 3, wg = g & 7;
        ushort o[8];
        #pragma unroll
        for (int c = 0; c < 8; ++c) o[c] = f2b(Ls[(wg * 8 + c) * 65 + nl]);
        *(uint4*)(dst + (size_t)(nb + nl) * 256 + kb + wg * 8) = pack8(o);
    }
}

// ---------- split-weight prep: fp32 [K][srcN] -> hi/lo bf16 transposed [N][K] ----------
__global__ __launch_bounds__(256) void k_wsplit(const float* __restrict__ src, int K, int N,
                                               int srcN, int nvalid,
                                               ushort* __restrict__ dh, ushort* __restrict__ dl) {
    __shared__ float Ls[64 * 65];
    int tilesN = N >> 6;
    int kb = (blockIdx.x / tilesN) * 64, nb = (blockIdx.x % tilesN) * 64;
    int tid = threadIdx.x;
    for (int q = 0; q < 4; ++q) {
        int g = q * 256 + tid;
        int kl = g >> 4, c4 = (g & 15) * 4;
        #pragma unroll
        for (int j = 0; j < 4; ++j) {
            int n = nb + c4 + j;
            float v = (n < nvalid) ? src[(size_t)(kb + kl) * srcN + n] : 0.f;
            Ls[kl * 65 + c4 + j] = v;
        }
    }
    __syncthreads();
    for (int q = 0; q < 2; ++q) {
        int g = q * 256 + tid;
        int nl = g >> 3, wg = g & 7;
        ushort oh[8], ol[8];
        #pragma unroll
        for (int c = 0; c < 8; ++c) {
            float v = Ls[(wg * 8 + c) * 65 + nl];
            ushort h = f2b(v);
            oh[c] = h;
            ol[c] = f2b(v - b2f(h));
        }
        *(uint4*)(dh + (size_t)(nb + nl) * K + kb + wg * 8) = pack8(oh);
        *(uint4*)(dl + (size_t)(nb + nl) * K + kb + wg * 8) = pack8(ol);
    }
}

// ---------- MFMA LDS helpers (layout verified in rounds 2-8) ----------
// async staging: linear LDS dest (wave-uniform base + lane*16) with the XOR
// swizzle folded into the per-lane GLOBAL source chunk (involution: dst = src^(row&7)).
__device__ __forceinline__ void stage_async(const ushort* __restrict__ src, size_t pitch,
                                            const int* __restrict__ rowmap, int rowbase, size_t kbase,
                                            ushort* lds, int nrows, int tid) {
    int lane = tid & 63, wid = tid >> 6;
    int total = nrows * 8;
    for (int b0 = 0; b0 < total; b0 += 512) {
        int g = b0 + wid * 64 + lane;
        int row = g >> 3;
        int ck = (g & 7) ^ (row & 7);
        size_t srow = rowmap ? (size_t)rowmap[rowbase + row] : (size_t)(rowbase + row);
        const ushort* gp = src + srow * pitch + kbase + ck * 8;
        ushort* lp = lds + (size_t)(b0 + wid * 64) * 8;   // wave-uniform
        __builtin_amdgcn_global_load_lds(
            (const __attribute__((address_space(1))) unsigned int*)gp,
            (__attribute__((address_space(3))) unsigned int*)lp, 16, 0, 0);
    }
}

__device__ __forceinline__ short8 frag_ld(const ushort* lds, int row, int kc, int lane) {
    int w0 = (kc * 16 + ((lane >> 4) << 2)) ^ ((row & 7) << 2);
    return *(const short8*)((const char*)lds + row * 128 + w0 * 4);
}

// ---------- stage 1 v4: fused LN + FFN + rot via split-bf16 MFMA ----------
// 32 points/block, 512 threads, 64KB LDS -> 2 blocks/CU.
// Weights single-buffered (stage->barrier->compute); co-resident block hides drains.
__global__ __launch_bounds__(512, 4) void k_stage1(
    const float* __restrict__ x, const float* __restrict__ g, const float* __restrict__ be,
    const float* __restrict__ b1, const float* __restrict__ b2,
    const ushort* __restrict__ w1h, const ushort* __restrict__ w1l,
    const ushort* __restrict__ w2h, const ushort* __restrict__ w2l,
    const ushort* __restrict__ rth, const ushort* __restrict__ rtl,
    const int* __restrict__ mski,
    ushort* __restrict__ xn_out, float* __restrict__ xd_out, int* __restrict__ bin_out,
    int* __restrict__ fixlist, int* __restrict__ fixcnt)
{
    __shared__ ushort lXh[4 * 2048];   // 16KB : 4 k-slabs x [32 rows][64 k] (xn; h in 0-1, xd in 2-3)
    __shared__ ushort lXl[4 * 2048];   // 16KB
    __shared__ ushort lWh[8192];       // 16KB : single weight slab [128][64] (or 2x rot [64][64])
    __shared__ ushort lWl[8192];       // 16KB
    int tid = threadIdx.x, lane = tid & 63, wid = tid >> 6;
    int base = blockIdx.x * 32;
    int l15 = lane & 15;
    int r4 = (lane >> 4) * 4;

    // prologue: stage w1 slab 0 (overlaps LN)
    stage_async(w1h, 256, nullptr, 0, 0, lWh, 128, tid);
    stage_async(w1l, 256, nullptr, 0, 0, lWl, 128, tid);

    {   // ---- phase 0: LN (16 threads/point, 16 features each) ----
        int row = tid >> 4, sub = tid & 15;
        const float* xr = x + (size_t)(base + row) * FF + sub * 16;
        float v[16];
        float s = 0.f;
        #pragma unroll
        for (int q = 0; q < 4; ++q) {
            float4 f = *(const float4*)(xr + q * 4);
            v[q*4+0] = f.x; v[q*4+1] = f.y; v[q*4+2] = f.z; v[q*4+3] = f.w;
            s += f.x + f.y + f.z + f.w;
        }
        s += __shfl_xor(s, 1, 16); s += __shfl_xor(s, 2, 16);
        s += __shfl_xor(s, 4, 16); s += __shfl_xor(s, 8, 16);
        float mu = s * (1.f / 256.f);
        float s2 = 0.f;
        #pragma unroll
        for (int q = 0; q < 16; ++q) { float d = v[q] - mu; s2 += d * d; }
        s2 += __shfl_xor(s2, 1, 16); s2 += __shfl_xor(s2, 2, 16);
        s2 += __shfl_xor(s2, 4, 16); s2 += __shfl_xor(s2, 8, 16);
        float rs = 1.0f / sqrtf(s2 * (1.f / 256.f) + 1e-6f);
        ushort* xo = xn_out + (size_t)(base + row) * FF + sub * 16;
        #pragma unroll
        for (int j = 0; j < 2; ++j) {
            int i0 = sub * 16 + j * 8;
            float4 g0 = *(const float4*)(g + i0);
            float4 g1 = *(const float4*)(g + i0 + 4);
            float4 e0 = *(const float4*)(be + i0);
            float4 e1 = *(const float4*)(be + i0 + 4);
            float gv[8] = {g0.x,g0.y,g0.z,g0.w,g1.x,g1.y,g1.z,g1.w};
            float ev[8] = {e0.x,e0.y,e0.z,e0.w,e1.x,e1.y,e1.z,e1.w};
            ushort hh[8], ll[8];
            #pragma unroll
            for (int c = 0; c < 8; ++c) {
                float xv = (v[j*8+c] - mu) * rs * gv[c] + ev[c];
                ushort h = f2b(xv);
                hh[c] = h;
                ll[c] = f2b(xv - b2f(h));
            }
            uint4 uh = pack8(hh), ul = pack8(ll);
            *(uint4*)(xo + j * 8) = uh;
            int kb = i0 >> 6;
            int wg = (i0 & 63) >> 3;
            int w0 = (wg * 4) ^ ((row & 7) << 2);
            *(uint4*)((char*)lXh + kb * 4096 + row * 128 + w0 * 4) = uh;
            *(uint4*)((char*)lXl + kb * 4096 + row * 128 + w0 * 4) = ul;
        }
    }
    __syncthreads();   // xn visible + w1 slab0 ready

    int mg = wid >> 2, ng = wid & 3;
    int wm = mg * 16, wn = ng * 32;
    floatx4 zf = {0.f, 0.f, 0.f, 0.f};

    // ---- GEMM1: h = elu(xn @ w1 + b1), M=32 N=128 K=256, single-buffered weights ----
    floatx4 acc[2];
    acc[0] = zf; acc[1] = zf;
    for (int kb = 0; kb < 4; ++kb) {
        #pragma unroll
        for (int kc = 0; kc < 2; ++kc) {
            short8 ah, al, bh[2], bl[2];
            ah = frag_ld(lXh + kb * 2048, wm + l15, kc, lane);
            al = frag_ld(lXl + kb * 2048, wm + l15, kc, lane);
            #pragma unroll
            for (int n = 0; n < 2; n++) {
                bh[n] = frag_ld(lWh, wn + n * 16 + l15, kc, lane);
                bl[n] = frag_ld(lWl, wn + n * 16 + l15, kc, lane);
            }
            #pragma unroll
            for (int n = 0; n < 2; n++) {
                acc[n] = __builtin_amdgcn_mfma_f32_16x16x32_bf16(ah, bh[n], acc[n], 0, 0, 0);
                acc[n] = __builtin_amdgcn_mfma_f32_16x16x32_bf16(ah, bl[n], acc[n], 0, 0, 0);
                acc[n] = __builtin_amdgcn_mfma_f32_16x16x32_bf16(al, bh[n], acc[n], 0, 0, 0);
            }
        }
        __syncthreads();   // readers done with lW
        if (kb < 3) {
            stage_async(w1h, 256, nullptr, 0, (size_t)(kb + 1) * 64, lWh, 128, tid);
            stage_async(w1l, 256, nullptr, 0, (size_t)(kb + 1) * 64, lWl, 128, tid);
            __syncthreads();   // slab ready
        }
    }
    // stage w2 slab0; write h into lX slabs 0-1
    stage_async(w2h, 128, nullptr, 0, 0, lWh, 128, tid);
    stage_async(w2l, 128, nullptr, 0, 0, lWl, 128, tid);
    {
        #pragma unroll
        for (int n = 0; n < 2; n++) {
            int cg = wn + n * 16 + l15;
            float b1v = b1[cg];
            int slab = cg >> 6, c64 = cg & 63;
            int wg = c64 >> 3, e = c64 & 7;
            #pragma unroll
            for (int i = 0; i < 4; i++) {
                int r = wm + r4 + i;
                float hv = acc[n][i] + b1v;
                hv = (hv > 0.f) ? hv : expm1f(hv);
                ushort h = f2b(hv);
                int w0 = (wg * 4) ^ ((r & 7) << 2);
                int idx = slab * 2048 + r * 64 + w0 * 2 + e;
                lXh[idx] = h;
                lXl[idx] = f2b(hv - b2f(h));
            }
        }
    }
    __syncthreads();   // h visible + w2 slab0 ready

    // ---- GEMM2: xd = h @ w2 + b2, M=32 N=128 K=128 ----
    floatx4 acc2[2];
    acc2[0] = zf; acc2[1] = zf;
    for (int kb = 0; kb < 2; ++kb) {
        #pragma unroll
        for (int kc = 0; kc < 2; ++kc) {
            short8 ah, al, bh[2], bl[2];
            ah = frag_ld(lXh + kb * 2048, wm + l15, kc, lane);
            al = frag_ld(lXl + kb * 2048, wm + l15, kc, lane);
            #pragma unroll
            for (int n = 0; n < 2; n++) {
                bh[n] = frag_ld(lWh, wn + n * 16 + l15, kc, lane);
                bl[n] = frag_ld(lWl, wn + n * 16 + l15, kc, lane);
            }
            #pragma unroll
            for (int n = 0; n < 2; n++) {
                acc2[n] = __builtin_amdgcn_mfma_f32_16x16x32_bf16(ah, bh[n], acc2[n], 0, 0, 0);
                acc2[n] = __builtin_amdgcn_mfma_f32_16x16x32_bf16(ah, bl[n], acc2[n], 0, 0, 0);
                acc2[n] = __builtin_amdgcn_mfma_f32_16x16x32_bf16(al, bh[n], acc2[n], 0, 0, 0);
            }
        }
        __syncthreads();
        if (kb == 0) {
            stage_async(w2h, 128, nullptr, 0, 64, lWh, 128, tid);
            stage_async(w2l, 128, nullptr, 0, 64, lWl, 128, tid);
            __syncthreads();
        }
    }
    // stage rot (both slabs fit the lW buffer); write xd global + lX slabs 2-3
    stage_async(rth, 128, nullptr, 0, 0, lWh, 64, tid);
    stage_async(rtl, 128, nullptr, 0, 0, lWl, 64, tid);
    stage_async(rth, 128, nullptr, 0, 64, lWh + 4096, 64, tid);
    stage_async(rtl, 128, nullptr, 0, 64, lWl + 4096, 64, tid);
    {
        #pragma unroll
        for (int n = 0; n < 2; n++) {
            int cg = wn + n * 16 + l15;
            float b2v = b2[cg];
            int slab = 2 + (cg >> 6), c64 = cg & 63;
            int wg = c64 >> 3, e = c64 & 7;
            #pragma unroll
            for (int i = 0; i < 4; i++) {
                int r = wm + r4 + i;
                float xv = acc2[n][i] + b2v;
                xd_out[(size_t)(base + r) * DDIM + cg] = xv;
                ushort h = f2b(xv);
                int w0 = (wg * 4) ^ ((r & 7) << 2);
                int idx = slab * 2048 + r * 64 + w0 * 2 + e;
                lXh[idx] = h;
                lXl[idx] = f2b(xv - b2f(h));
            }
        }
    }
    __syncthreads();   // xd visible + rot ready

    // ---- GEMM3: mul = xd @ rot, M=32 N=64 K=128 ----
    floatx4 acc3 = zf;
    int wn3 = ng * 16;
    for (int kb = 0; kb < 2; ++kb) {
        #pragma unroll
        for (int kc = 0; kc < 2; ++kc) {
            short8 ah, al, bh, bl;
            ah = frag_ld(lXh + (2 + kb) * 2048, wm + l15, kc, lane);
            al = frag_ld(lXl + (2 + kb) * 2048, wm + l15, kc, lane);
            bh = frag_ld(lWh + kb * 4096, wn3 + l15, kc, lane);
            bl = frag_ld(lWl + kb * 4096, wn3 + l15, kc, lane);
            acc3 = __builtin_amdgcn_mfma_f32_16x16x32_bf16(ah, bh, acc3, 0, 0, 0);
            acc3 = __builtin_amdgcn_mfma_f32_16x16x32_bf16(ah, bl, acc3, 0, 0, 0);
            acc3 = __builtin_amdgcn_mfma_f32_16x16x32_bf16(al, bh, acc3, 0, 0, 0);
        }
    }
    __syncthreads();
    float* lMul = (float*)lXh;   // 32 x 65 fp32 = 8.3KB (slabs 0-1 region, dead)
    {
        #pragma unroll
        for (int i = 0; i < 4; i++) {
            int r = wm + r4 + i;
            lMul[r * 65 + wn3 + l15] = acc3[i];
        }
    }
    __syncthreads();

    {   // ---- top-2 argmax over [mul, -mul], margin flag (16 thr/pt) ----
        int p = tid >> 4, q = tid & 15;
        float v1 = -1e30f, v2 = -1e30f; int i1 = 1 << 29;
        #pragma unroll
        for (int j = 0; j < 4; ++j) {
            int c = q * 4 + j;
            if (c < 50) {
                float m = lMul[p * 65 + c];
                float wv, lv; int wi, li;
                if (m >= 0.f) { wv = m; wi = c; lv = -m; li = 50 + c; }
                else          { wv = -m; wi = 50 + c; lv = m; li = c; }
                if (wv > v1 || (wv == v1 && wi < i1)) { v2 = v1; v1 = wv; i1 = wi; }
                else if (wv > v2) v2 = wv;
                if (lv > v1 || (lv == v1 && li < i1)) { v2 = v1; v1 = lv; i1 = li; }
                else if (lv > v2) v2 = lv;
            }
        }
        #pragma unroll
        for (int off = 1; off < 16; off <<= 1) {
            float o1 = __shfl_xor(v1, off, 16);
            int   oi = __shfl_xor(i1, off, 16);
            float o2 = __shfl_xor(v2, off, 16);
            bool take = (o1 > v1) || (o1 == v1 && oi < i1);
            float small = take ? v1 : o1;
            if (take) { v1 = o1; i1 = oi; }
            v2 = fmaxf(fmaxf(v2, o2), small);
        }
        if (q == 0) {
            int pt = base + p;
            bin_out[pt] = i1 + (mski[pt] ? 0 : (NBINS - 1));
            float tau = 3e-4f + 1.5e-3f * v1;
            if (v1 - v2 < tau) {
                int pos = atomicAdd(fixcnt, 1);
                fixlist[pos] = pt;
            }
        }
    }
}

// ---------- fp64 fixup for margin-flagged points ----------
__global__ __launch_bounds__(64) void k_fixup(
    const float* __restrict__ x, const float* __restrict__ g, const float* __restrict__ be,
    const float* __restrict__ w1, const float* __restrict__ b1,
    const float* __restrict__ w2, const float* __restrict__ b2,
    const float* __restrict__ rot, const int* __restrict__ mski,
    const int* __restrict__ fixlist, const int* __restrict__ fixcnt,
    int* __restrict__ bin_out)
{
    __shared__ double xn_s[256];
    __shared__ double h_s[128];
    __shared__ double xd_s[128];
    int lane = threadIdx.x;
    int n = fixcnt[0];
    for (int e = blockIdx.x; e < n; e += gridDim.x) {
        int pt = fixlist[e];
        const float* xr = x + (size_t)pt * FF;
        double s = 0.0, xv[4];
        #pragma unroll
        for (int q = 0; q < 4; q++) { xv[q] = (double)xr[lane + q * 64]; s += xv[q]; }
        #pragma unroll
        for (int off = 1; off < 64; off <<= 1) s += __shfl_xor(s, off, 64);
        double mu = s * (1.0 / 256.0);
        double s2 = 0.0;
        #pragma unroll
        for (int q = 0; q < 4; q++) { double d = xv[q] - mu; s2 += d * d; }
        #pragma unroll
        for (int off = 1; off < 64; off <<= 1) s2 += __shfl_xor(s2, off, 64);
        double rs = 1.0 / sqrt(s2 * (1.0 / 256.0) + 1e-6);
        #pragma unroll
        for (int q = 0; q < 4; q++) {
            int i = lane + q * 64;
            xn_s[i] = (xv[q] - mu) * rs * (double)g[i] + (double)be[i];
        }
        __syncthreads();
        #pragma unroll
        for (int q = 0; q < 2; q++) {
            int j = lane + q * 64;
            double a0 = 0.0, a1 = 0.0;
            for (int k = 0; k < FF; k += 2) {
                a0 += xn_s[k] * (double)w1[k * DDIM + j];
                a1 += xn_s[k + 1] * (double)w1[(k + 1) * DDIM + j];
            }
            double a = (double)b1[j] + a0 + a1;
            h_s[j] = (a > 0.0) ? a : expm1(a);
        }
        __syncthreads();
        #pragma unroll
        for (int q = 0; q < 2; q++) {
            int j = lane + q * 64;
            double a0 = 0.0, a1 = 0.0;
            for (int k = 0; k < DDIM; k += 2) {
                a0 += h_s[k] * (double)w2[k * DDIM + j];
                a1 += h_s[k + 1] * (double)w2[(k + 1) * DDIM + j];
            }
            xd_s[j] = (double)b2[j] + a0 + a1;
        }
        __syncthreads();
        double v; int idx;
        if (lane < NROT) {
            double m = 0.0;
            for (int k = 0; k < DDIM; k++) m += xd_s[k] * (double)rot[k * 100 + lane];
            if (m >= 0.0) { v = m; idx = lane; } else { v = -m; idx = 50 + lane; }
        } else { v = -1e300; idx = 1 << 29; }
        #pragma unroll
        for (int off = 1; off < 64; off <<= 1) {
            double ov = __shfl_xor(v, off, 64);
            int oi = __shfl_xor(idx, off, 64);
            if (ov > v || (ov == v && oi < idx)) { v = ov; idx = oi; }
        }
        if (lane == 0) bin_out[pt] = idx + (mski[pt] ? 0 : (NBINS - 1));
        __syncthreads();
    }
}

// ---------- binning: stable counting sort ----------
__global__ void k_count(const int* __restrict__ bin, int* __restrict__ hist) {
    int c = blockIdx.x % 100, b = blockIdx.x / 100;
    int t = threadIdx.x;
    int v = bin[b * NN + c * BSIZE + t];
    atomicAdd(&hist[(b * 100 + c) * NIDS + v], 1);
}

__global__ void k_offsets(const int* __restrict__ hist, int* __restrict__ offs) {
    __shared__ int tot[NIDS];
    __shared__ int start[NIDS];
    int b = blockIdx.x, v = threadIdx.x;
    if (v < NIDS) {
        int s = 0;
        for (int c = 0; c < 100; c++) s += hist[(b * 100 + c) * NIDS + v];
        tot[v] = s;
    }
    __syncthreads();
    if (threadIdx.x == 0) {
        int run = 0;
        for (int i = 0; i < NIDS; i++) { start[i] = run; run += tot[i]; }
    }
    __syncthreads();
    if (v < NIDS) {
        int run = start[v];
        for (int c = 0; c < 100; c++) {
            offs[(b * 100 + c) * NIDS + v] = run;
            run += hist[(b * 100 + c) * NIDS + v];
        }
    }
}

__global__ void k_scatter(const int* __restrict__ bin, const int* __restrict__ offs,
                          const int* __restrict__ mski, int* __restrict__ flat,
                          float* __restrict__ mf) {
    __shared__ int sv[BSIZE];
    int c = blockIdx.x % 100, b = blockIdx.x / 100;
    int t = threadIdx.x;
    int n = c * BSIZE + t;
    int v = bin[b * NN + n];
    sv[t] = v;
    __syncthreads();
    int rank = 0;
    for (int u = 0; u < t; u++) rank += (sv[u] == v);
    int r = offs[(b * 100 + c) * NIDS + v] + rank;
    flat[b * NN + r] = b * NN + n;
    mf[b * NN + r] = mski[b * NN + n] ? 1.0f : 0.0f;
}

// ---------- per-bin pairwise kernel matrix (fp32 tiled), fused deg/norm ----------
__global__ __launch_bounds__(256) void k_dm(const float* __restrict__ xd, const int* __restrict__ flat,
                                            const float* __restrict__ mf, ushort* __restrict__ dmb,
                                            float* __restrict__ norm) {
    __shared__ float Xs[128 * 64];
    __shared__ float na[128];
    __shared__ float ml[128];
    __shared__ float ps[128 * 16];
    int g = blockIdx.x, tid = threadIdx.x;
    int tx = tid & 15, ty = tid >> 4;
    int rowbase = g * 128;
    if (tid < 128) ml[tid] = mf[rowbase + tid];
    float acc[8][8];
    #pragma unroll
    for (int i = 0; i < 8; i++)
        #pragma unroll
        for (int j = 0; j < 8; j++) acc[i][j] = 0.f;
    float nap[8];
    #pragma unroll
    for (int j = 0; j < 8; j++) nap[j] = 0.f;

    for (int kh = 0; kh < 2; ++kh) {
        __syncthreads();
        for (int q = 0; q < 8; ++q) {
            int gg = q * 256 + tid;
            int row = gg >> 4, f4 = gg & 15;
            int srow = flat[rowbase + row];
            float4 v = *(const float4*)(xd + (size_t)srow * DDIM + kh * 64 + f4 * 4);
            int f4s = f4 ^ ((row >> 3) & 7);
            *(float4*)(Xs + row * 64 + f4s * 4) = v;
        }
        __syncthreads();
        for (int k4 = 0; k4 < 16; ++k4) {
            int sa = (k4 ^ (ty & 7)) << 2;
            int sb = (k4 ^ (tx & 7)) << 2;
            float4 av[8], bv[8];
            #pragma unroll
            for (int i = 0; i < 8; i++) av[i] = *(const float4*)(Xs + (ty * 8 + i) * 64 + sa);
            #pragma unroll
            for (int j = 0; j < 8; j++) bv[j] = *(const float4*)(Xs + (tx * 8 + j) * 64 + sb);
            if (ty == 0) {
                #pragma unroll
                for (int j = 0; j < 8; j++)
                    nap[j] += bv[j].x * bv[j].x + bv[j].y * bv[j].y + bv[j].z * bv[j].z + bv[j].w * bv[j].w;
            }
            #pragma unroll
            for (int i = 0; i < 8; i++)
                #pragma unroll
                for (int j = 0; j < 8; j++)
                    acc[i][j] += av[i].x * bv[j].x + av[i].y * bv[j].y + av[i].z * bv[j].z + av[i].w * bv[j].w;
        }
    }
    if (ty == 0) {
        #pragma unroll
        for (int j = 0; j < 8; j++) na[tx * 8 + j] = nap[j];
    }
    __syncthreads();
    #pragma unroll
    for (int i = 0; i < 8; ++i) {
        int r = ty * 8 + i;
        float nai = na[r], mi = ml[r];
        float rs = 0.f;
        ushort o[8];
        #pragma unroll
        for (int j = 0; j < 8; ++j) {
            int c = tx * 8 + j;
            float D2 = nai - 2.f * acc[i][j] + na[c];
            float dv = expf(-0.1f * sqrtf(fmaxf(D2, 1e-6f)));
            dv *= mi * ml[c];
            rs += dv;
            o[j] = f2b(dv);
        }
        *(uint4*)(dmb + (size_t)g * 16384 + r * 128 + tx * 8) = pack8(o);
        ps[r * 16 + tx] = rs;
    }
    __syncthreads();
    if (tid < 128) {
        float deg = 0.f;
        for (int t2 = 0; t2 < 16; ++t2) deg += ps[tid * 16 + t2];
        deg = fminf(deg, 1000.0f);
        float nv = 1.0f / sqrtf(deg + 1e-6f);
        norm[rowbase + tid] = nv * ml[tid];
    }
}

// ---------- fused per-layer graph conv v2: merged triple GEMM, 80KB LDS, 2 blocks/CU ----------
template<int LAYER>
__global__ __launch_bounds__(512, 4) void k_layer(
    const ushort* __restrict__ A, const int* __restrict__ rowmap,
    const ushort* __restrict__ ThT, const ushort* __restrict__ WhT, const ushort* __restrict__ WtT,
    const float* __restrict__ bt, const ushort* __restrict__ dmb,
    const float* __restrict__ norm, const float* __restrict__ mf,
    ushort* __restrict__ outb, float* __restrict__ outf, const int* __restrict__ flatscat)
{
    __shared__ char smem[81920];
    ushort* lAbuf = (ushort*)smem;                 // 2 x 16KB A ping
    ushort* lB    = (ushort*)(smem + 32768);       // 6 x 8KB: th0 th1 wh0 wh1 wt0 wt1
    ushort* lT    = (ushort*)smem;                 // post-GEMM: 2 x 8KB T^T j-slabs
    ushort* ldm   = (ushort*)(smem + 32768);       // post-GEMM: 2 x 16KB dm slabs

    int tid = threadIdx.x, lane = tid & 63, wid = tid >> 6;
    int g = blockIdx.x, nh = blockIdx.y;
    int rowbase = g * 128, nbase = nh * 64;
    int l15 = lane & 15;
    int r4 = (lane >> 4) * 4;
    int wm = (wid >> 1) * 32, wn = (wid & 1) * 32;
    const ushort* dmg = dmb + (size_t)g * 16384;
    floatx4 zf = {0.f, 0.f, 0.f, 0.f};

    stage_async(A, 256, rowmap, rowbase, 0, lAbuf, 128, tid);
    stage_async(ThT, 256, nullptr, nbase, 0, lB + 0 * 4096, 64, tid);
    stage_async(WhT, 256, nullptr, nbase, 0, lB + 2 * 4096, 64, tid);
    stage_async(WtT, 256, nullptr, nbase, 0, lB + 4 * 4096, 64, tid);
    __syncthreads();

    // ---- merged GEMM: T = A@Th, H = A@Wh, G = A@Wt  (M=128, N=64, K=256) ----
    floatx4 accT[2][2], accH[2][2], accG[2][2];
    #pragma unroll
    for (int m = 0; m < 2; m++)
        #pragma unroll
        for (int n = 0; n < 2; n++) { accT[m][n] = zf; accH[m][n] = zf; accG[m][n] = zf; }
    for (int kb = 0; kb < 4; ++kb) {
        if (kb < 3) {
            int pp = (kb + 1) & 1;
            stage_async(A, 256, rowmap, rowbase, (size_t)(kb + 1) * 64, lAbuf + pp * 8192, 128, tid);
            stage_async(ThT, 256, nullptr, nbase, (size_t)(kb + 1) * 64, lB + (0 + pp) * 4096, 64, tid);
            stage_async(WhT, 256, nullptr, nbase, (size_t)(kb + 1) * 64, lB + (2 + pp) * 4096, 64, tid);
            stage_async(WtT, 256, nullptr, nbase, (size_t)(kb + 1) * 64, lB + (4 + pp) * 4096, 64, tid);
        }
        const ushort* lA = lAbuf + (kb & 1) * 8192;
        const ushort* sTh = lB + (0 + (kb & 1)) * 4096;
        const ushort* sWh = lB + (2 + (kb & 1)) * 4096;
        const ushort* sWt = lB + (4 + (kb & 1)) * 4096;
        #pragma unroll
        for (int kc = 0; kc < 2; ++kc) {
            short8 a[2], bt_[2], bh_[2], bg_[2];
            #pragma unroll
            for (int m = 0; m < 2; m++) a[m] = frag_ld(lA, wm + m * 16 + l15, kc, lane);
            #pragma unroll
            for (int n = 0; n < 2; n++) {
                bt_[n] = frag_ld(sTh, wn + n * 16 + l15, kc, lane);
                bh_[n] = frag_ld(sWh, wn + n * 16 + l15, kc, lane);
                bg_[n] = frag_ld(sWt, wn + n * 16 + l15, kc, lane);
            }
            #pragma unroll
            for (int m = 0; m < 2; m++)
                #pragma unroll
                for (int n = 0; n < 2; n++) {
                    accT[m][n] = __builtin_amdgcn_mfma_f32_16x16x32_bf16(a[m], bt_[n], accT[m][n], 0, 0, 0);
                    accH[m][n] = __builtin_amdgcn_mfma_f32_16x16x32_bf16(a[m], bh_[n], accH[m][n], 0, 0, 0);
                    accG[m][n] = __builtin_amdgcn_mfma_f32_16x16x32_bf16(a[m], bg_[n], accG[m][n], 0, 0, 0);
                }
        }
        __syncthreads();
    }

    stage_async(dmg, 128, nullptr, 0, 0, ldm, 128, tid);
    stage_async(dmg, 128, nullptr, 0, 64, ldm + 8192, 128, tid);

    {   // T^T (scaled by norm, bf16, frag-swizzled) into lT j-slabs
        #pragma unroll
        for (int m = 0; m < 2; m++) {
            float4 nv = *(const float4*)(norm + rowbase + wm + m * 16 + r4);
            float nvv[4] = {nv.x, nv.y, nv.z, nv.w};
            int jloc0 = wm + m * 16 + r4;
            int jb = jloc0 >> 6, jj = jloc0 & 63;
            #pragma unroll
            for (int n = 0; n < 2; n++) {
                int cloc = wn + n * 16 + l15;
                char* bp = (char*)(lT + jb * 4096) + cloc * 128;
                int cx = (cloc & 7) << 2;
                ushort t0 = f2b(accT[m][n][0] * nvv[0]);
                ushort t1 = f2b(accT[m][n][1] * nvv[1]);
                ushort t2 = f2b(accT[m][n][2] * nvv[2]);
                ushort t3 = f2b(accT[m][n][3] * nvv[3]);
                *(unsigned*)(bp + ((((jj >> 1) + 0) ^ cx) << 2)) = (unsigned)t0 | ((unsigned)t1 << 16);
                *(unsigned*)(bp + ((((jj >> 1) + 1) ^ cx) << 2)) = (unsigned)t2 | ((unsigned)t3 << 16);
            }
        }
    }
    __syncthreads();

    // ---- phase A: FH = dm @ T  (M=128, N=64, K=128) ----
    floatx4 accFH[2][2];
    #pragma unroll
    for (int m = 0; m < 2; m++) { accFH[m][0] = zf; accFH[m][1] = zf; }
    for (int kb = 0; kb < 2; ++kb) {
        #pragma unroll
        for (int kc = 0; kc < 2; ++kc) {
            short8 a[2], b[2];
            #pragma unroll
            for (int m = 0; m < 2; m++) a[m] = frag_ld(ldm + kb * 8192, wm + m * 16 + l15, kc, lane);
            #pragma unroll
            for (int n = 0; n < 2; n++) b[n] = frag_ld(lT + kb * 4096, wn + n * 16 + l15, kc, lane);
            #pragma unroll
            for (int m = 0; m < 2; m++)
                #pragma unroll
                for (int n = 0; n < 2; n++)
                    accFH[m][n] = __builtin_amdgcn_mfma_f32_16x16x32_bf16(a[m], b[n], accFH[m][n], 0, 0, 0);
        }
    }
    __syncthreads();

    // ---- epilogue: gate/elu combine + coalesced store (wave-local bounce) ----
    for (int m = 0; m < 2; m++) {
        int r0l = wm + m * 16 + r4;
        int r0g = rowbase + r0l;
        float4 mv = *(const float4*)(mf + r0g);
        float4 nv = *(const float4*)(norm + r0g);
        float mvv[4] = {mv.x, mv.y, mv.z, mv.w};
        float nvv[4] = {nv.x, nv.y, nv.z, nv.w};
        float vals[2][4];
        #pragma unroll
        for (int n = 0; n < 2; n++) {
            int cg = nbase + wn + n * 16 + l15;
            float btc = bt[cg];
            #pragma unroll
            for (int i = 0; i < 4; i++) {
                float gate = 1.f / (1.f + expf(-(accG[m][n][i] + btc)));
                float fh = accFH[m][n][i] * nvv[i];
                float het = mvv[i] * accH[m][n][i];
                float o = gate * fh + (1.f - gate) * het;
                o = (o > 0.f) ? o : expm1f(o);
                vals[n][i] = o * mvv[i];
            }
        }
        if (LAYER == 0) {
            ushort* Ls = (ushort*)smem;
            int bbase = wid * 512;
            #pragma unroll
            for (int n = 0; n < 2; n++)
                #pragma unroll
                for (int i = 0; i < 4; i++)
                    Ls[bbase + (r4 + i) * 32 + n * 16 + l15] = f2b(vals[n][i]);
            __builtin_amdgcn_s_waitcnt(0);
            #pragma unroll
            for (int it = 0; it < 2; ++it) {
                int lr = (lane >> 3) + it * 8;
                int lc4 = (lane & 7) * 4;
                ushort4 tv = *(const ushort4*)(Ls + bbase + lr * 32 + lc4);
                int rg = rowbase + wm + m * 16 + lr;
                *(ushort4*)(outb + (size_t)rg * 256 + nbase + wn + lc4) = tv;
            }
        } else {
            float* Ls = (float*)smem;
            int bbase = wid * 512;
            #pragma unroll
            for (int n = 0; n < 2; n++)
                #pragma unroll
                for (int i = 0; i < 4; i++)
                    Ls[bbase + (r4 + i) * 32 + n * 16 + l15] = vals[n][i];
            __builtin_amdgcn_s_waitcnt(0);
            #pragma unroll
            for (int it = 0; it < 2; ++it) {
                int lr = (lane >> 3) + it * 8;
                int lc4 = (lane & 7) * 4;
                float4 tv = *(const float4*)(Ls + bbase + lr * 32 + lc4);
                int rg = rowbase + wm + m * 16 + lr;
                int dst = flatscat[rg];
                *(float4*)(outf + (size_t)dst * 256 + nbase + wn + lc4) = tv;
            }
        }
    }
}

extern "C" void kernel_launch(void* const* d_in, const int* in_sizes, int n_in,
                              void* d_out, int out_size, void* d_ws, size_t ws_size,
                              hipStream_t stream) {
    const float* x    = (const float*)d_in[0];
    const void*  msk  = d_in[1];
    const float* ln_g = (const float*)d_in[2];
    const float* ln_b = (const float*)d_in[3];
    const float* w1   = (const float*)d_in[4];
    const float* b1   = (const float*)d_in[5];
    const float* w2   = (const float*)d_in[6];
    const float* b2   = (const float*)d_in[7];
    const float* rot  = (const float*)d_in[8];
    const float* th0  = (const float*)d_in[9];
    const float* wh0  = (const float*)d_in[10];
    const float* wt0  = (const float*)d_in[11];
    const float* bt0  = (const float*)d_in[12];
    const float* th1  = (const float*)d_in[13];
    const float* wh1  = (const float*)d_in[14];
    const float* wt1  = (const float*)d_in[15];
    const float* bt1  = (const float*)d_in[16];

    char* ws = (char*)d_ws;
    ushort* out0 = (ushort*)(ws + OFF_OUT0);
    ushort* dmb  = (ushort*)(ws + OFF_DMB);
    ushort* wb   = (ushort*)(ws + OFF_WB);
    ushort* wbth0 = wb + 0 * 65536;
    ushort* wbwh0 = wb + 1 * 65536;
    ushort* wbwt0 = wb + 2 * 65536;
    ushort* wbth1 = wb + 3 * 65536;
    ushort* wbwh1 = wb + 4 * 65536;
    ushort* wbwt1 = wb + 5 * 65536;
    float* norm = (float*)(ws + OFF_NORM);
    float* mf   = (float*)(ws + OFF_MF);
    int*   bin  = (int*)(ws + OFF_BIN);
    int*   flat = (int*)(ws + OFF_FLAT);
    int*   mski = (int*)(ws + OFF_MSKI);
    int*   hist = (int*)(ws + OFF_HIST);
    int*   offs = (int*)(ws + OFF_OFFS);
    int*   flag = (int*)(ws + OFF_FLAG);
    int*   fixcnt = (int*)(ws + OFF_CNT);
    int*   fixlist = (int*)(ws + OFF_LIST);
    ushort* w1h = (ushort*)(ws + OFF_W1H);
    ushort* w1l = (ushort*)(ws + OFF_W1L);
    ushort* w2h = (ushort*)(ws + OFF_W2H);
    ushort* w2l = (ushort*)(ws + OFF_W2L);
    ushort* rth = (ushort*)(ws + OFF_RH);
    ushort* rtl = (ushort*)(ws + OFF_RL);
    float*  xd  = (float*)d_out;
    ushort* xnb = (ushort*)((char*)d_out + (size_t)PTS * DDIM * 4);

    hipMemsetAsync(hist, 0, HISTBYTES, stream);
    hipMemsetAsync(fixcnt, 0, 4, stream);
    k_maskflag<<<1, 256, 0, stream>>>((const int*)msk, flag);
    k_masknorm<<<PTS / 256, 256, 0, stream>>>(msk, flag, mski);
    k_wprep<<<dim3(16, 6), 256, 0, stream>>>(th0, wh0, wt0, th1, wh1, wt1,
                                             wbth0, wbwh0, wbwt0, wbth1, wbwh1, wbwt1);
    k_wsplit<<<8, 256, 0, stream>>>(w1, 256, 128, 128, 128, w1h, w1l);
    k_wsplit<<<4, 256, 0, stream>>>(w2, 128, 128, 128, 128, w2h, w2l);
    k_wsplit<<<2, 256, 0, stream>>>(rot, 128, 64, 100, 50, rth, rtl);
    k_stage1<<<PTS / 32, 512, 0, stream>>>(x, ln_g, ln_b, b1, b2,
                                           w1h, w1l, w2h, w2l, rth, rtl, mski,
                                           xnb, xd, bin, fixlist, fixcnt);
    k_fixup<<<4096, 64, 0, stream>>>(x, ln_g, ln_b, w1, b1, w2, b2, rot, mski,
                                     fixlist, fixcnt, bin);
    k_count<<<800, 128, 0, stream>>>(bin, hist);
    k_offsets<<<8, 256, 0, stream>>>(hist, offs);
    k_scatter<<<800, 128, 0, stream>>>(bin, offs, mski, flat, mf);
    k_dm<<<800, 256, 0, stream>>>(xd, flat, mf, dmb, norm);
    // layer 0 (fused, N=64 quarters)
    k_layer<0><<<dim3(800, 4), 512, 0, stream>>>(xnb, flat, wbth0, wbwh0, wbwt0, bt0,
                                                 dmb, norm, mf, out0, nullptr, nullptr);
    // layer 1 (fused, scattered fp32 output)
    k_layer<1><<<dim3(800, 4), 512, 0, stream>>>(out0, nullptr, wbth1, wbwh1, wbwt1, bt1,
                                                 dmb, norm, mf, nullptr, (float*)d_out, flat);
}

// Round 10
// 439.755 us; speedup vs baseline: 2.5027x; 1.1013x over previous
//
#include <hip/hip_runtime.h>
#include <math.h>

#define BB 8
#define NN 12800
#define FF 256
#define DDIM 128
#define NBINS 100
#define BSIZE 128
#define NROT 50
#define NIDS 199
#define PTS (BB*NN)            // 102400

// ---- workspace layout (bytes) ----
#define OFF_OUT0 ((size_t)157286400)    // 52428800  : out0 bf16 [102400][256]
#define OFF_DMB  ((size_t)209715200)    // 26214400  : dm bf16 [800][128][128]
#define OFF_WB   ((size_t)235929600)    // 786432    : 6 weights bf16 transposed [256][256]
#define OFF_NORM ((size_t)236716032)    // 409600
#define OFF_MF   ((size_t)237125632)    // 409600
#define OFF_BIN  ((size_t)237535232)    // 409600 (int)
#define OFF_FLAT ((size_t)237944832)    // 409600 (int)
#define OFF_MSKI ((size_t)238354432)    // 409600 (int)
#define OFF_HIST ((size_t)238764032)    // 636800 (int)
#define OFF_OFFS ((size_t)239400832)    // 636800 (int)
#define OFF_FLAG ((size_t)240037632)    // 64
#define OFF_CNT  ((size_t)240037696)    // 64
#define OFF_LIST ((size_t)240037760)    // 409600 (int)
#define OFF_W1H  ((size_t)240447360)    // 65536 : w1^T hi bf16 [128][256]
#define OFF_W1L  ((size_t)240512896)    // 65536
#define OFF_W2H  ((size_t)240578432)    // 32768 : w2^T hi bf16 [128][128]
#define OFF_W2L  ((size_t)240611200)    // 32768
#define OFF_RH   ((size_t)240643968)    // 16384 : rot^T hi bf16 [64][128]
#define OFF_RL   ((size_t)240660352)    // 16384
#define HISTBYTES (8*100*199*4)

using short8  = __attribute__((ext_vector_type(8))) short;
using floatx4 = __attribute__((ext_vector_type(4))) float;

__device__ __forceinline__ ushort f2b(float f) {
    unsigned u = __float_as_uint(f);
    unsigned r = (u + 0x7FFFu + ((u >> 16) & 1u)) >> 16;
    return (ushort)r;
}
__device__ __forceinline__ float b2f(ushort h) {
    return __uint_as_float(((unsigned)h) << 16);
}
__device__ __forceinline__ uint4 pack8(const ushort* o) {
    uint4 u;
    u.x = (unsigned)o[0] | ((unsigned)o[1] << 16);
    u.y = (unsigned)o[2] | ((unsigned)o[3] << 16);
    u.z = (unsigned)o[4] | ((unsigned)o[5] << 16);
    u.w = (unsigned)o[6] | ((unsigned)o[7] << 16);
    return u;
}

// ---------- mask dtype sniffing ----------
__global__ void k_maskflag(const int* mi, int* flag) {
    __shared__ int notInt, notFloat;
    if (threadIdx.x == 0) { notInt = 0; notFloat = 0; }
    __syncthreads();
    int v = mi[threadIdx.x];
    if (v != 0 && v != 1) atomicOr(&notInt, 1);
    if (v != 0 && v != 0x3F800000) atomicOr(&notFloat, 1);
    __syncthreads();
    if (threadIdx.x == 0) flag[0] = (!notInt) ? 0 : ((!notFloat) ? 2 : 1);
}

__global__ void k_masknorm(const void* msk, const int* flag, int* mski) {
    int i = blockIdx.x * blockDim.x + threadIdx.x;
    if (i >= PTS) return;
    int f = flag[0];
    int v;
    if (f == 0)      v = ((const int*)msk)[i] != 0;
    else if (f == 2) v = ((const float*)msk)[i] != 0.0f;
    else             v = ((const unsigned char*)msk)[i] != 0;
    mski[i] = v;
}

// ---------- weight prep: fp32 [k][n] -> bf16 transposed [n][k] (GHConv weights) ----------
__global__ __launch_bounds__(256) void k_wprep(
    const float* s0, const float* s1, const float* s2,
    const float* s3, const float* s4, const float* s5,
    ushort* d0, ushort* d1, ushort* d2, ushort* d3, ushort* d4, ushort* d5)
{
    __shared__ float Ls[64 * 65];
    const float* src; ushort* dst;
    switch (blockIdx.y) {
        case 0: src = s0; dst = d0; break;
        case 1: src = s1; dst = d1; break;
        case 2: src = s2; dst = d2; break;
        case 3: src = s3; dst = d3; break;
        case 4: src = s4; dst = d4; break;
        default: src = s5; dst = d5; break;
    }
    int t = blockIdx.x;
    int kb = (t & 3) * 64, nb = (t >> 2) * 64;
    int tid = threadIdx.x;
    for (int q = 0; q < 4; ++q) {
        int g = q * 256 + tid;
        int kl = g >> 4, f4 = g & 15;
        float4 v = *(const float4*)(src + (size_t)(kb + kl) * 256 + nb + f4 * 4);
        Ls[kl * 65 + f4 * 4 + 0] = v.x;
        Ls[kl * 65 + f4 * 4 + 1] = v.y;
        Ls[kl * 65 + f4 * 4 + 2] = v.z;
        Ls[kl * 65 + f4 * 4 + 3] = v.w;
    }
    __syncthreads();
    for (int q = 0; q < 2; ++q) {
        int g = q * 256 + tid;
        int nl = g >> 3, wg = g & 7;
        ushort o[8];
        #pragma unroll
        for (int c = 0; c < 8; ++c) o[c] = f2b(Ls[(wg * 8 + c) * 65 + nl]);
        *(uint4*)(dst + (size_t)(nb + nl) * 256 + kb + wg * 8) = pack8(o);
    }
}

// ---------- split-weight prep: fp32 [K][srcN] -> hi/lo bf16 transposed [N][K] ----------
__global__ __launch_bounds__(256) void k_wsplit(const float* __restrict__ src, int K, int N,
                                               int srcN, int nvalid,
                                               ushort* __restrict__ dh, ushort* __restrict__ dl) {
    __shared__ float Ls[64 * 65];
    int tilesN = N >> 6;
    int kb = (blockIdx.x / tilesN) * 64, nb = (blockIdx.x % tilesN) * 64;
    int tid = threadIdx.x;
    for (int q = 0; q < 4; ++q) {
        int g = q * 256 + tid;
        int kl = g >> 4, c4 = (g & 15) * 4;
        #pragma unroll
        for (int j = 0; j < 4; ++j) {
            int n = nb + c4 + j;
            float v = (n < nvalid) ? src[(size_t)(kb + kl) * srcN + n] : 0.f;
            Ls[kl * 65 + c4 + j] = v;
        }
    }
    __syncthreads();
    for (int q = 0; q < 2; ++q) {
        int g = q * 256 + tid;
        int nl = g >> 3, wg = g & 7;
        ushort oh[8], ol[8];
        #pragma unroll
        for (int c = 0; c < 8; ++c) {
            float v = Ls[(wg * 8 + c) * 65 + nl];
            ushort h = f2b(v);
            oh[c] = h;
            ol[c] = f2b(v - b2f(h));
        }
        *(uint4*)(dh + (size_t)(nb + nl) * K + kb + wg * 8) = pack8(oh);
        *(uint4*)(dl + (size_t)(nb + nl) * K + kb + wg * 8) = pack8(ol);
    }
}

// ---------- MFMA LDS helpers (layout verified in rounds 2-9) ----------
// async staging: linear LDS dest (wave-uniform base + lane*16) with the XOR
// swizzle folded into the per-lane GLOBAL source chunk (involution: dst = src^(row&7)).
__device__ __forceinline__ void stage_async(const ushort* __restrict__ src, size_t pitch,
                                            const int* __restrict__ rowmap, int rowbase, size_t kbase,
                                            ushort* lds, int nrows, int tid) {
    int lane = tid & 63, wid = tid >> 6;
    int total = nrows * 8;
    for (int b0 = 0; b0 < total; b0 += 512) {
        int g = b0 + wid * 64 + lane;
        int row = g >> 3;
        int ck = (g & 7) ^ (row & 7);
        size_t srow = rowmap ? (size_t)rowmap[rowbase + row] : (size_t)(rowbase + row);
        const ushort* gp = src + srow * pitch + kbase + ck * 8;
        ushort* lp = lds + (size_t)(b0 + wid * 64) * 8;   // wave-uniform
        __builtin_amdgcn_global_load_lds(
            (const __attribute__((address_space(1))) unsigned int*)gp,
            (__attribute__((address_space(3))) unsigned int*)lp, 16, 0, 0);
    }
}

__device__ __forceinline__ short8 frag_ld(const ushort* lds, int row, int kc, int lane) {
    int w0 = (kc * 16 + ((lane >> 4) << 2)) ^ ((row & 7) << 2);
    return *(const short8*)((const char*)lds + row * 128 + w0 * 4);
}

// ---------- stage 1 v4: fused LN + FFN + rot via split-bf16 MFMA ----------
// 32 points/block, 512 threads, 64KB LDS -> 2 blocks/CU.
__global__ __launch_bounds__(512, 4) void k_stage1(
    const float* __restrict__ x, const float* __restrict__ g, const float* __restrict__ be,
    const float* __restrict__ b1, const float* __restrict__ b2,
    const ushort* __restrict__ w1h, const ushort* __restrict__ w1l,
    const ushort* __restrict__ w2h, const ushort* __restrict__ w2l,
    const ushort* __restrict__ rth, const ushort* __restrict__ rtl,
    const int* __restrict__ mski,
    ushort* __restrict__ xn_out, float* __restrict__ xd_out, int* __restrict__ bin_out,
    int* __restrict__ fixlist, int* __restrict__ fixcnt)
{
    __shared__ ushort lXh[4 * 2048];   // 16KB : 4 k-slabs x [32 rows][64 k]
    __shared__ ushort lXl[4 * 2048];   // 16KB
    __shared__ ushort lWh[8192];       // 16KB : single weight slab [128][64]
    __shared__ ushort lWl[8192];       // 16KB
    int tid = threadIdx.x, lane = tid & 63, wid = tid >> 6;
    int base = blockIdx.x * 32;
    int l15 = lane & 15;
    int r4 = (lane >> 4) * 4;

    stage_async(w1h, 256, nullptr, 0, 0, lWh, 128, tid);
    stage_async(w1l, 256, nullptr, 0, 0, lWl, 128, tid);

    {   // ---- phase 0: LN (16 threads/point, 16 features each) ----
        int row = tid >> 4, sub = tid & 15;
        const float* xr = x + (size_t)(base + row) * FF + sub * 16;
        float v[16];
        float s = 0.f;
        #pragma unroll
        for (int q = 0; q < 4; ++q) {
            float4 f = *(const float4*)(xr + q * 4);
            v[q*4+0] = f.x; v[q*4+1] = f.y; v[q*4+2] = f.z; v[q*4+3] = f.w;
            s += f.x + f.y + f.z + f.w;
        }
        s += __shfl_xor(s, 1, 16); s += __shfl_xor(s, 2, 16);
        s += __shfl_xor(s, 4, 16); s += __shfl_xor(s, 8, 16);
        float mu = s * (1.f / 256.f);
        float s2 = 0.f;
        #pragma unroll
        for (int q = 0; q < 16; ++q) { float d = v[q] - mu; s2 += d * d; }
        s2 += __shfl_xor(s2, 1, 16); s2 += __shfl_xor(s2, 2, 16);
        s2 += __shfl_xor(s2, 4, 16); s2 += __shfl_xor(s2, 8, 16);
        float rs = 1.0f / sqrtf(s2 * (1.f / 256.f) + 1e-6f);
        ushort* xo = xn_out + (size_t)(base + row) * FF + sub * 16;
        #pragma unroll
        for (int j = 0; j < 2; ++j) {
            int i0 = sub * 16 + j * 8;
            float4 g0 = *(const float4*)(g + i0);
            float4 g1 = *(const float4*)(g + i0 + 4);
            float4 e0 = *(const float4*)(be + i0);
            float4 e1 = *(const float4*)(be + i0 + 4);
            float gv[8] = {g0.x,g0.y,g0.z,g0.w,g1.x,g1.y,g1.z,g1.w};
            float ev[8] = {e0.x,e0.y,e0.z,e0.w,e1.x,e1.y,e1.z,e1.w};
            ushort hh[8], ll[8];
            #pragma unroll
            for (int c = 0; c < 8; ++c) {
                float xv = (v[j*8+c] - mu) * rs * gv[c] + ev[c];
                ushort h = f2b(xv);
                hh[c] = h;
                ll[c] = f2b(xv - b2f(h));
            }
            uint4 uh = pack8(hh), ul = pack8(ll);
            *(uint4*)(xo + j * 8) = uh;
            int kb = i0 >> 6;
            int wg = (i0 & 63) >> 3;
            int w0 = (wg * 4) ^ ((row & 7) << 2);
            *(uint4*)((char*)lXh + kb * 4096 + row * 128 + w0 * 4) = uh;
            *(uint4*)((char*)lXl + kb * 4096 + row * 128 + w0 * 4) = ul;
        }
    }
    __syncthreads();

    int mg = wid >> 2, ng = wid & 3;
    int wm = mg * 16, wn = ng * 32;
    floatx4 zf = {0.f, 0.f, 0.f, 0.f};

    // ---- GEMM1: h = elu(xn @ w1 + b1), M=32 N=128 K=256 ----
    floatx4 acc[2];
    acc[0] = zf; acc[1] = zf;
    for (int kb = 0; kb < 4; ++kb) {
        #pragma unroll
        for (int kc = 0; kc < 2; ++kc) {
            short8 ah, al, bh[2], bl[2];
            ah = frag_ld(lXh + kb * 2048, wm + l15, kc, lane);
            al = frag_ld(lXl + kb * 2048, wm + l15, kc, lane);
            #pragma unroll
            for (int n = 0; n < 2; n++) {
                bh[n] = frag_ld(lWh, wn + n * 16 + l15, kc, lane);
                bl[n] = frag_ld(lWl, wn + n * 16 + l15, kc, lane);
            }
            #pragma unroll
            for (int n = 0; n < 2; n++) {
                acc[n] = __builtin_amdgcn_mfma_f32_16x16x32_bf16(ah, bh[n], acc[n], 0, 0, 0);
                acc[n] = __builtin_amdgcn_mfma_f32_16x16x32_bf16(ah, bl[n], acc[n], 0, 0, 0);
                acc[n] = __builtin_amdgcn_mfma_f32_16x16x32_bf16(al, bh[n], acc[n], 0, 0, 0);
            }
        }
        __syncthreads();
        if (kb < 3) {
            stage_async(w1h, 256, nullptr, 0, (size_t)(kb + 1) * 64, lWh, 128, tid);
            stage_async(w1l, 256, nullptr, 0, (size_t)(kb + 1) * 64, lWl, 128, tid);
            __syncthreads();
        }
    }
    stage_async(w2h, 128, nullptr, 0, 0, lWh, 128, tid);
    stage_async(w2l, 128, nullptr, 0, 0, lWl, 128, tid);
    {
        #pragma unroll
        for (int n = 0; n < 2; n++) {
            int cg = wn + n * 16 + l15;
            float b1v = b1[cg];
            int slab = cg >> 6, c64 = cg & 63;
            int wg = c64 >> 3, e = c64 & 7;
            #pragma unroll
            for (int i = 0; i < 4; i++) {
                int r = wm + r4 + i;
                float hv = acc[n][i] + b1v;
                hv = (hv > 0.f) ? hv : expm1f(hv);
                ushort h = f2b(hv);
                int w0 = (wg * 4) ^ ((r & 7) << 2);
                int idx = slab * 2048 + r * 64 + w0 * 2 + e;
                lXh[idx] = h;
                lXl[idx] = f2b(hv - b2f(h));
            }
        }
    }
    __syncthreads();

    // ---- GEMM2: xd = h @ w2 + b2, M=32 N=128 K=128 ----
    floatx4 acc2[2];
    acc2[0] = zf; acc2[1] = zf;
    for (int kb = 0; kb < 2; ++kb) {
        #pragma unroll
        for (int kc = 0; kc < 2; ++kc) {
            short8 ah, al, bh[2], bl[2];
            ah = frag_ld(lXh + kb * 2048, wm + l15, kc, lane);
            al = frag_ld(lXl + kb * 2048, wm + l15, kc, lane);
            #pragma unroll
            for (int n = 0; n < 2; n++) {
                bh[n] = frag_ld(lWh, wn + n * 16 + l15, kc, lane);
                bl[n] = frag_ld(lWl, wn + n * 16 + l15, kc, lane);
            }
            #pragma unroll
            for (int n = 0; n < 2; n++) {
                acc2[n] = __builtin_amdgcn_mfma_f32_16x16x32_bf16(ah, bh[n], acc2[n], 0, 0, 0);
                acc2[n] = __builtin_amdgcn_mfma_f32_16x16x32_bf16(ah, bl[n], acc2[n], 0, 0, 0);
                acc2[n] = __builtin_amdgcn_mfma_f32_16x16x32_bf16(al, bh[n], acc2[n], 0, 0, 0);
            }
        }
        __syncthreads();
        if (kb == 0) {
            stage_async(w2h, 128, nullptr, 0, 64, lWh, 128, tid);
            stage_async(w2l, 128, nullptr, 0, 64, lWl, 128, tid);
            __syncthreads();
        }
    }
    stage_async(rth, 128, nullptr, 0, 0, lWh, 64, tid);
    stage_async(rtl, 128, nullptr, 0, 0, lWl, 64, tid);
    stage_async(rth, 128, nullptr, 0, 64, lWh + 4096, 64, tid);
    stage_async(rtl, 128, nullptr, 0, 64, lWl + 4096, 64, tid);
    {
        #pragma unroll
        for (int n = 0; n < 2; n++) {
            int cg = wn + n * 16 + l15;
            float b2v = b2[cg];
            int slab = 2 + (cg >> 6), c64 = cg & 63;
            int wg = c64 >> 3, e = c64 & 7;
            #pragma unroll
            for (int i = 0; i < 4; i++) {
                int r = wm + r4 + i;
                float xv = acc2[n][i] + b2v;
                xd_out[(size_t)(base + r) * DDIM + cg] = xv;
                ushort h = f2b(xv);
                int w0 = (wg * 4) ^ ((r & 7) << 2);
                int idx = slab * 2048 + r * 64 + w0 * 2 + e;
                lXh[idx] = h;
                lXl[idx] = f2b(xv - b2f(h));
            }
        }
    }
    __syncthreads();

    // ---- GEMM3: mul = xd @ rot, M=32 N=64 K=128 ----
    floatx4 acc3 = zf;
    int wn3 = ng * 16;
    for (int kb = 0; kb < 2; ++kb) {
        #pragma unroll
        for (int kc = 0; kc < 2; ++kc) {
            short8 ah, al, bh, bl;
            ah = frag_ld(lXh + (2 + kb) * 2048, wm + l15, kc, lane);
            al = frag_ld(lXl + (2 + kb) * 2048, wm + l15, kc, lane);
            bh = frag_ld(lWh + kb * 4096, wn3 + l15, kc, lane);
            bl = frag_ld(lWl + kb * 4096, wn3 + l15, kc, lane);
            acc3 = __builtin_amdgcn_mfma_f32_16x16x32_bf16(ah, bh, acc3, 0, 0, 0);
            acc3 = __builtin_amdgcn_mfma_f32_16x16x32_bf16(ah, bl, acc3, 0, 0, 0);
            acc3 = __builtin_amdgcn_mfma_f32_16x16x32_bf16(al, bh, acc3, 0, 0, 0);
        }
    }
    __syncthreads();
    float* lMul = (float*)lXh;
    {
        #pragma unroll
        for (int i = 0; i < 4; i++) {
            int r = wm + r4 + i;
            lMul[r * 65 + wn3 + l15] = acc3[i];
        }
    }
    __syncthreads();

    {   // ---- top-2 argmax over [mul, -mul], margin flag (16 thr/pt) ----
        int p = tid >> 4, q = tid & 15;
        float v1 = -1e30f, v2 = -1e30f; int i1 = 1 << 29;
        #pragma unroll
        for (int j = 0; j < 4; ++j) {
            int c = q * 4 + j;
            if (c < 50) {
                float m = lMul[p * 65 + c];
                float wv, lv; int wi, li;
                if (m >= 0.f) { wv = m; wi = c; lv = -m; li = 50 + c; }
                else          { wv = -m; wi = 50 + c; lv = m; li = c; }
                if (wv > v1 || (wv == v1 && wi < i1)) { v2 = v1; v1 = wv; i1 = wi; }
                else if (wv > v2) v2 = wv;
                if (lv > v1 || (lv == v1 && li < i1)) { v2 = v1; v1 = lv; i1 = li; }
                else if (lv > v2) v2 = lv;
            }
        }
        #pragma unroll
        for (int off = 1; off < 16; off <<= 1) {
            float o1 = __shfl_xor(v1, off, 16);
            int   oi = __shfl_xor(i1, off, 16);
            float o2 = __shfl_xor(v2, off, 16);
            bool take = (o1 > v1) || (o1 == v1 && oi < i1);
            float small = take ? v1 : o1;
            if (take) { v1 = o1; i1 = oi; }
            v2 = fmaxf(fmaxf(v2, o2), small);
        }
        if (q == 0) {
            int pt = base + p;
            bin_out[pt] = i1 + (mski[pt] ? 0 : (NBINS - 1));
            float tau = 3e-4f + 1.5e-3f * v1;
            if (v1 - v2 < tau) {
                int pos = atomicAdd(fixcnt, 1);
                fixlist[pos] = pt;
            }
        }
    }
}

// ---------- fp64 fixup for margin-flagged points ----------
__global__ __launch_bounds__(64) void k_fixup(
    const float* __restrict__ x, const float* __restrict__ g, const float* __restrict__ be,
    const float* __restrict__ w1, const float* __restrict__ b1,
    const float* __restrict__ w2, const float* __restrict__ b2,
    const float* __restrict__ rot, const int* __restrict__ mski,
    const int* __restrict__ fixlist, const int* __restrict__ fixcnt,
    int* __restrict__ bin_out)
{
    __shared__ double xn_s[256];
    __shared__ double h_s[128];
    __shared__ double xd_s[128];
    int lane = threadIdx.x;
    int n = fixcnt[0];
    for (int e = blockIdx.x; e < n; e += gridDim.x) {
        int pt = fixlist[e];
        const float* xr = x + (size_t)pt * FF;
        double s = 0.0, xv[4];
        #pragma unroll
        for (int q = 0; q < 4; q++) { xv[q] = (double)xr[lane + q * 64]; s += xv[q]; }
        #pragma unroll
        for (int off = 1; off < 64; off <<= 1) s += __shfl_xor(s, off, 64);
        double mu = s * (1.0 / 256.0);
        double s2 = 0.0;
        #pragma unroll
        for (int q = 0; q < 4; q++) { double d = xv[q] - mu; s2 += d * d; }
        #pragma unroll
        for (int off = 1; off < 64; off <<= 1) s2 += __shfl_xor(s2, off, 64);
        double rs = 1.0 / sqrt(s2 * (1.0 / 256.0) + 1e-6);
        #pragma unroll
        for (int q = 0; q < 4; q++) {
            int i = lane + q * 64;
            xn_s[i] = (xv[q] - mu) * rs * (double)g[i] + (double)be[i];
        }
        __syncthreads();
        #pragma unroll
        for (int q = 0; q < 2; q++) {
            int j = lane + q * 64;
            double a0 = 0.0, a1 = 0.0;
            for (int k = 0; k < FF; k += 2) {
                a0 += xn_s[k] * (double)w1[k * DDIM + j];
                a1 += xn_s[k + 1] * (double)w1[(k + 1) * DDIM + j];
            }
            double a = (double)b1[j] + a0 + a1;
            h_s[j] = (a > 0.0) ? a : expm1(a);
        }
        __syncthreads();
        #pragma unroll
        for (int q = 0; q < 2; q++) {
            int j = lane + q * 64;
            double a0 = 0.0, a1 = 0.0;
            for (int k = 0; k < DDIM; k += 2) {
                a0 += h_s[k] * (double)w2[k * DDIM + j];
                a1 += h_s[k + 1] * (double)w2[(k + 1) * DDIM + j];
            }
            xd_s[j] = (double)b2[j] + a0 + a1;
        }
        __syncthreads();
        double v; int idx;
        if (lane < NROT) {
            double m = 0.0;
            for (int k = 0; k < DDIM; k++) m += xd_s[k] * (double)rot[k * 100 + lane];
            if (m >= 0.0) { v = m; idx = lane; } else { v = -m; idx = 50 + lane; }
        } else { v = -1e300; idx = 1 << 29; }
        #pragma unroll
        for (int off = 1; off < 64; off <<= 1) {
            double ov = __shfl_xor(v, off, 64);
            int oi = __shfl_xor(idx, off, 64);
            if (ov > v || (ov == v && oi < idx)) { v = ov; idx = oi; }
        }
        if (lane == 0) bin_out[pt] = idx + (mski[pt] ? 0 : (NBINS - 1));
        __syncthreads();
    }
}

// ---------- binning: stable counting sort ----------
__global__ void k_count(const int* __restrict__ bin, int* __restrict__ hist) {
    int c = blockIdx.x % 100, b = blockIdx.x / 100;
    int t = threadIdx.x;
    int v = bin[b * NN + c * BSIZE + t];
    atomicAdd(&hist[(b * 100 + c) * NIDS + v], 1);
}

__global__ void k_offsets(const int* __restrict__ hist, int* __restrict__ offs) {
    __shared__ int tot[NIDS];
    __shared__ int start[NIDS];
    int b = blockIdx.x, v = threadIdx.x;
    if (v < NIDS) {
        int s = 0;
        for (int c = 0; c < 100; c++) s += hist[(b * 100 + c) * NIDS + v];
        tot[v] = s;
    }
    __syncthreads();
    if (threadIdx.x == 0) {
        int run = 0;
        for (int i = 0; i < NIDS; i++) { start[i] = run; run += tot[i]; }
    }
    __syncthreads();
    if (v < NIDS) {
        int run = start[v];
        for (int c = 0; c < 100; c++) {
            offs[(b * 100 + c) * NIDS + v] = run;
            run += hist[(b * 100 + c) * NIDS + v];
        }
    }
}

__global__ void k_scatter(const int* __restrict__ bin, const int* __restrict__ offs,
                          const int* __restrict__ mski, int* __restrict__ flat,
                          float* __restrict__ mf) {
    __shared__ int sv[BSIZE];
    int c = blockIdx.x % 100, b = blockIdx.x / 100;
    int t = threadIdx.x;
    int n = c * BSIZE + t;
    int v = bin[b * NN + n];
    sv[t] = v;
    __syncthreads();
    int rank = 0;
    for (int u = 0; u < t; u++) rank += (sv[u] == v);
    int r = offs[(b * 100 + c) * NIDS + v] + rank;
    flat[b * NN + r] = b * NN + n;
    mf[b * NN + r] = mski[b * NN + n] ? 1.0f : 0.0f;
}

// ---------- per-bin pairwise kernel matrix (fp32 tiled), fused deg/norm ----------
__global__ __launch_bounds__(256) void k_dm(const float* __restrict__ xd, const int* __restrict__ flat,
                                            const float* __restrict__ mf, ushort* __restrict__ dmb,
                                            float* __restrict__ norm) {
    __shared__ float Xs[128 * 64];
    __shared__ float na[128];
    __shared__ float ml[128];
    __shared__ float ps[128 * 16];
    int g = blockIdx.x, tid = threadIdx.x;
    int tx = tid & 15, ty = tid >> 4;
    int rowbase = g * 128;
    if (tid < 128) ml[tid] = mf[rowbase + tid];
    float acc[8][8];
    #pragma unroll
    for (int i = 0; i < 8; i++)
        #pragma unroll
        for (int j = 0; j < 8; j++) acc[i][j] = 0.f;
    float nap[8];
    #pragma unroll
    for (int j = 0; j < 8; j++) nap[j] = 0.f;

    for (int kh = 0; kh < 2; ++kh) {
        __syncthreads();
        for (int q = 0; q < 8; ++q) {
            int gg = q * 256 + tid;
            int row = gg >> 4, f4 = gg & 15;
            int srow = flat[rowbase + row];
            float4 v = *(const float4*)(xd + (size_t)srow * DDIM + kh * 64 + f4 * 4);
            int f4s = f4 ^ ((row >> 3) & 7);
            *(float4*)(Xs + row * 64 + f4s * 4) = v;
        }
        __syncthreads();
        for (int k4 = 0; k4 < 16; ++k4) {
            int sa = (k4 ^ (ty & 7)) << 2;
            int sb = (k4 ^ (tx & 7)) << 2;
            float4 av[8], bv[8];
            #pragma unroll
            for (int i = 0; i < 8; i++) av[i] = *(const float4*)(Xs + (ty * 8 + i) * 64 + sa);
            #pragma unroll
            for (int j = 0; j < 8; j++) bv[j] = *(const float4*)(Xs + (tx * 8 + j) * 64 + sb);
            if (ty == 0) {
                #pragma unroll
                for (int j = 0; j < 8; j++)
                    nap[j] += bv[j].x * bv[j].x + bv[j].y * bv[j].y + bv[j].z * bv[j].z + bv[j].w * bv[j].w;
            }
            #pragma unroll
            for (int i = 0; i < 8; i++)
                #pragma unroll
                for (int j = 0; j < 8; j++)
                    acc[i][j] += av[i].x * bv[j].x + av[i].y * bv[j].y + av[i].z * bv[j].z + av[i].w * bv[j].w;
        }
    }
    if (ty == 0) {
        #pragma unroll
        for (int j = 0; j < 8; j++) na[tx * 8 + j] = nap[j];
    }
    __syncthreads();
    #pragma unroll
    for (int i = 0; i < 8; ++i) {
        int r = ty * 8 + i;
        float nai = na[r], mi = ml[r];
        float rs = 0.f;
        ushort o[8];
        #pragma unroll
        for (int j = 0; j < 8; ++j) {
            int c = tx * 8 + j;
            float D2 = nai - 2.f * acc[i][j] + na[c];
            float dv = expf(-0.1f * sqrtf(fmaxf(D2, 1e-6f)));
            dv *= mi * ml[c];
            rs += dv;
            o[j] = f2b(dv);
        }
        *(uint4*)(dmb + (size_t)g * 16384 + r * 128 + tx * 8) = pack8(o);
        ps[r * 16 + tx] = rs;
    }
    __syncthreads();
    if (tid < 128) {
        float deg = 0.f;
        for (int t2 = 0; t2 < 16; ++t2) deg += ps[tid * 16 + t2];
        deg = fminf(deg, 1000.0f);
        float nv = 1.0f / sqrtf(deg + 1e-6f);
        norm[rowbase + tid] = nv * ml[tid];
    }
}

// ---------- fused per-layer graph conv v2: merged triple GEMM, 80KB LDS, 2 blocks/CU ----------
// 1-D grid 3200 with XCD-locality remap: id = grp*32 + nh*8 + gsub -> g = grp*8+gsub.
// Same-bin blocks (nh=0..3) land on the same XCD (ids differ by 8) within a 32-block
// window -> A-tile and dm fetched ~once per XCD instead of 4x.
template<int LAYER>
__global__ __launch_bounds__(512, 4) void k_layer(
    const ushort* __restrict__ A, const int* __restrict__ rowmap,
    const ushort* __restrict__ ThT, const ushort* __restrict__ WhT, const ushort* __restrict__ WtT,
    const float* __restrict__ bt, const ushort* __restrict__ dmb,
    const float* __restrict__ norm, const float* __restrict__ mf,
    ushort* __restrict__ outb, float* __restrict__ outf, const int* __restrict__ flatscat)
{
    __shared__ char smem[81920];
    ushort* lAbuf = (ushort*)smem;                 // 2 x 16KB A ping
    ushort* lB    = (ushort*)(smem + 32768);       // 6 x 8KB: th0 th1 wh0 wh1 wt0 wt1
    ushort* lT    = (ushort*)smem;                 // post-GEMM: 2 x 8KB T^T j-slabs
    ushort* ldm   = (ushort*)(smem + 32768);       // post-GEMM: 2 x 16KB dm slabs

    int tid = threadIdx.x, lane = tid & 63, wid = tid >> 6;
    int bid = blockIdx.x;
    int grp = bid >> 5, within = bid & 31;
    int nh = within >> 3, g = grp * 8 + (within & 7);
    int rowbase = g * 128, nbase = nh * 64;
    int l15 = lane & 15;
    int r4 = (lane >> 4) * 4;
    int wm = (wid >> 1) * 32, wn = (wid & 1) * 32;
    const ushort* dmg = dmb + (size_t)g * 16384;
    floatx4 zf = {0.f, 0.f, 0.f, 0.f};

    stage_async(A, 256, rowmap, rowbase, 0, lAbuf, 128, tid);
    stage_async(ThT, 256, nullptr, nbase, 0, lB + 0 * 4096, 64, tid);
    stage_async(WhT, 256, nullptr, nbase, 0, lB + 2 * 4096, 64, tid);
    stage_async(WtT, 256, nullptr, nbase, 0, lB + 4 * 4096, 64, tid);
    __syncthreads();

    // ---- merged GEMM: T = A@Th, H = A@Wh, G = A@Wt  (M=128, N=64, K=256) ----
    floatx4 accT[2][2], accH[2][2], accG[2][2];
    #pragma unroll
    for (int m = 0; m < 2; m++)
        #pragma unroll
        for (int n = 0; n < 2; n++) { accT[m][n] = zf; accH[m][n] = zf; accG[m][n] = zf; }
    for (int kb = 0; kb < 4; ++kb) {
        if (kb < 3) {
            int pp = (kb + 1) & 1;
            stage_async(A, 256, rowmap, rowbase, (size_t)(kb + 1) * 64, lAbuf + pp * 8192, 128, tid);
            stage_async(ThT, 256, nullptr, nbase, (size_t)(kb + 1) * 64, lB + (0 + pp) * 4096, 64, tid);
            stage_async(WhT, 256, nullptr, nbase, (size_t)(kb + 1) * 64, lB + (2 + pp) * 4096, 64, tid);
            stage_async(WtT, 256, nullptr, nbase, (size_t)(kb + 1) * 64, lB + (4 + pp) * 4096, 64, tid);
        }
        const ushort* lA = lAbuf + (kb & 1) * 8192;
        const ushort* sTh = lB + (0 + (kb & 1)) * 4096;
        const ushort* sWh = lB + (2 + (kb & 1)) * 4096;
        const ushort* sWt = lB + (4 + (kb & 1)) * 4096;
        #pragma unroll
        for (int kc = 0; kc < 2; ++kc) {
            short8 a[2], bt_[2], bh_[2], bg_[2];
            #pragma unroll
            for (int m = 0; m < 2; m++) a[m] = frag_ld(lA, wm + m * 16 + l15, kc, lane);
            #pragma unroll
            for (int n = 0; n < 2; n++) {
                bt_[n] = frag_ld(sTh, wn + n * 16 + l15, kc, lane);
                bh_[n] = frag_ld(sWh, wn + n * 16 + l15, kc, lane);
                bg_[n] = frag_ld(sWt, wn + n * 16 + l15, kc, lane);
            }
            #pragma unroll
            for (int m = 0; m < 2; m++)
                #pragma unroll
                for (int n = 0; n < 2; n++) {
                    accT[m][n] = __builtin_amdgcn_mfma_f32_16x16x32_bf16(a[m], bt_[n], accT[m][n], 0, 0, 0);
                    accH[m][n] = __builtin_amdgcn_mfma_f32_16x16x32_bf16(a[m], bh_[n], accH[m][n], 0, 0, 0);
                    accG[m][n] = __builtin_amdgcn_mfma_f32_16x16x32_bf16(a[m], bg_[n], accG[m][n], 0, 0, 0);
                }
        }
        __syncthreads();
    }

    stage_async(dmg, 128, nullptr, 0, 0, ldm, 128, tid);
    stage_async(dmg, 128, nullptr, 0, 64, ldm + 8192, 128, tid);

    {   // T^T (scaled by norm, bf16, frag-swizzled) into lT j-slabs
        #pragma unroll
        for (int m = 0; m < 2; m++) {
            float4 nv = *(const float4*)(norm + rowbase + wm + m * 16 + r4);
            float nvv[4] = {nv.x, nv.y, nv.z, nv.w};
            int jloc0 = wm + m * 16 + r4;
            int jb = jloc0 >> 6, jj = jloc0 & 63;
            #pragma unroll
            for (int n = 0; n < 2; n++) {
                int cloc = wn + n * 16 + l15;
                char* bp = (char*)(lT + jb * 4096) + cloc * 128;
                int cx = (cloc & 7) << 2;
                ushort t0 = f2b(accT[m][n][0] * nvv[0]);
                ushort t1 = f2b(accT[m][n][1] * nvv[1]);
                ushort t2 = f2b(accT[m][n][2] * nvv[2]);
                ushort t3 = f2b(accT[m][n][3] * nvv[3]);
                *(unsigned*)(bp + ((((jj >> 1) + 0) ^ cx) << 2)) = (unsigned)t0 | ((unsigned)t1 << 16);
                *(unsigned*)(bp + ((((jj >> 1) + 1) ^ cx) << 2)) = (unsigned)t2 | ((unsigned)t3 << 16);
            }
        }
    }
    __syncthreads();

    // ---- phase A: FH = dm @ T  (M=128, N=64, K=128) ----
    floatx4 accFH[2][2];
    #pragma unroll
    for (int m = 0; m < 2; m++) { accFH[m][0] = zf; accFH[m][1] = zf; }
    for (int kb = 0; kb < 2; ++kb) {
        #pragma unroll
        for (int kc = 0; kc < 2; ++kc) {
            short8 a[2], b[2];
            #pragma unroll
            for (int m = 0; m < 2; m++) a[m] = frag_ld(ldm + kb * 8192, wm + m * 16 + l15, kc, lane);
            #pragma unroll
            for (int n = 0; n < 2; n++) b[n] = frag_ld(lT + kb * 4096, wn + n * 16 + l15, kc, lane);
            #pragma unroll
            for (int m = 0; m < 2; m++)
                #pragma unroll
                for (int n = 0; n < 2; n++)
                    accFH[m][n] = __builtin_amdgcn_mfma_f32_16x16x32_bf16(a[m], b[n], accFH[m][n], 0, 0, 0);
        }
    }
    __syncthreads();

    // ---- epilogue: gate/elu combine + coalesced store (wave-local bounce) ----
    for (int m = 0; m < 2; m++) {
        int r0l = wm + m * 16 + r4;
        int r0g = rowbase + r0l;
        float4 mv = *(const float4*)(mf + r0g);
        float4 nv = *(const float4*)(norm + r0g);
        float mvv[4] = {mv.x, mv.y, mv.z, mv.w};
        float nvv[4] = {nv.x, nv.y, nv.z, nv.w};
        float vals[2][4];
        #pragma unroll
        for (int n = 0; n < 2; n++) {
            int cg = nbase + wn + n * 16 + l15;
            float btc = bt[cg];
            #pragma unroll
            for (int i = 0; i < 4; i++) {
                float gate = 1.f / (1.f + expf(-(accG[m][n][i] + btc)));
                float fh = accFH[m][n][i] * nvv[i];
                float het = mvv[i] * accH[m][n][i];
                float o = gate * fh + (1.f - gate) * het;
                o = (o > 0.f) ? o : expm1f(o);
                vals[n][i] = o * mvv[i];
            }
        }
        if (LAYER == 0) {
            ushort* Ls = (ushort*)smem;
            int bbase = wid * 512;
            #pragma unroll
            for (int n = 0; n < 2; n++)
                #pragma unroll
                for (int i = 0; i < 4; i++)
                    Ls[bbase + (r4 + i) * 32 + n * 16 + l15] = f2b(vals[n][i]);
            __builtin_amdgcn_s_waitcnt(0);
            #pragma unroll
            for (int it = 0; it < 2; ++it) {
                int lr = (lane >> 3) + it * 8;
                int lc4 = (lane & 7) * 4;
                ushort4 tv = *(const ushort4*)(Ls + bbase + lr * 32 + lc4);
                int rg = rowbase + wm + m * 16 + lr;
                *(ushort4*)(outb + (size_t)rg * 256 + nbase + wn + lc4) = tv;
            }
        } else {
            float* Ls = (float*)smem;
            int bbase = wid * 512;
            #pragma unroll
            for (int n = 0; n < 2; n++)
                #pragma unroll
                for (int i = 0; i < 4; i++)
                    Ls[bbase + (r4 + i) * 32 + n * 16 + l15] = vals[n][i];
            __builtin_amdgcn_s_waitcnt(0);
            #pragma unroll
            for (int it = 0; it < 2; ++it) {
                int lr = (lane >> 3) + it * 8;
                int lc4 = (lane & 7) * 4;
                float4 tv = *(const float4*)(Ls + bbase + lr * 32 + lc4);
                int rg = rowbase + wm + m * 16 + lr;
                int dst = flatscat[rg];
                *(float4*)(outf + (size_t)dst * 256 + nbase + wn + lc4) = tv;
            }
        }
    }
}

extern "C" void kernel_launch(void* const* d_in, const int* in_sizes, int n_in,
                              void* d_out, int out_size, void* d_ws, size_t ws_size,
                              hipStream_t stream) {
    const float* x    = (const float*)d_in[0];
    const void*  msk  = d_in[1];
    const float* ln_g = (const float*)d_in[2];
    const float* ln_b = (const float*)d_in[3];
    const float* w1   = (const float*)d_in[4];
    const float* b1   = (const float*)d_in[5];
    const float* w2   = (const float*)d_in[6];
    const float* b2   = (const float*)d_in[7];
    const float* rot  = (const float*)d_in[8];
    const float* th0  = (const float*)d_in[9];
    const float* wh0  = (const float*)d_in[10];
    const float* wt0  = (const float*)d_in[11];
    const float* bt0  = (const float*)d_in[12];
    const float* th1  = (const float*)d_in[13];
    const float* wh1  = (const float*)d_in[14];
    const float* wt1  = (const float*)d_in[15];
    const float* bt1  = (const float*)d_in[16];

    char* ws = (char*)d_ws;
    ushort* out0 = (ushort*)(ws + OFF_OUT0);
    ushort* dmb  = (ushort*)(ws + OFF_DMB);
    ushort* wb   = (ushort*)(ws + OFF_WB);
    ushort* wbth0 = wb + 0 * 65536;
    ushort* wbwh0 = wb + 1 * 65536;
    ushort* wbwt0 = wb + 2 * 65536;
    ushort* wbth1 = wb + 3 * 65536;
    ushort* wbwh1 = wb + 4 * 65536;
    ushort* wbwt1 = wb + 5 * 65536;
    float* norm = (float*)(ws + OFF_NORM);
    float* mf   = (float*)(ws + OFF_MF);
    int*   bin  = (int*)(ws + OFF_BIN);
    int*   flat = (int*)(ws + OFF_FLAT);
    int*   mski = (int*)(ws + OFF_MSKI);
    int*   hist = (int*)(ws + OFF_HIST);
    int*   offs = (int*)(ws + OFF_OFFS);
    int*   flag = (int*)(ws + OFF_FLAG);
    int*   fixcnt = (int*)(ws + OFF_CNT);
    int*   fixlist = (int*)(ws + OFF_LIST);
    ushort* w1h = (ushort*)(ws + OFF_W1H);
    ushort* w1l = (ushort*)(ws + OFF_W1L);
    ushort* w2h = (ushort*)(ws + OFF_W2H);
    ushort* w2l = (ushort*)(ws + OFF_W2L);
    ushort* rth = (ushort*)(ws + OFF_RH);
    ushort* rtl = (ushort*)(ws + OFF_RL);
    float*  xd  = (float*)d_out;
    ushort* xnb = (ushort*)((char*)d_out + (size_t)PTS * DDIM * 4);

    hipMemsetAsync(hist, 0, HISTBYTES, stream);
    hipMemsetAsync(fixcnt, 0, 4, stream);
    k_maskflag<<<1, 256, 0, stream>>>((const int*)msk, flag);
    k_masknorm<<<PTS / 256, 256, 0, stream>>>(msk, flag, mski);
    k_wprep<<<dim3(16, 6), 256, 0, stream>>>(th0, wh0, wt0, th1, wh1, wt1,
                                             wbth0, wbwh0, wbwt0, wbth1, wbwh1, wbwt1);
    k_wsplit<<<8, 256, 0, stream>>>(w1, 256, 128, 128, 128, w1h, w1l);
    k_wsplit<<<4, 256, 0, stream>>>(w2, 128, 128, 128, 128, w2h, w2l);
    k_wsplit<<<2, 256, 0, stream>>>(rot, 128, 64, 100, 50, rth, rtl);
    k_stage1<<<PTS / 32, 512, 0, stream>>>(x, ln_g, ln_b, b1, b2,
                                           w1h, w1l, w2h, w2l, rth, rtl, mski,
                                           xnb, xd, bin, fixlist, fixcnt);
    k_fixup<<<4096, 64, 0, stream>>>(x, ln_g, ln_b, w1, b1, w2, b2, rot, mski,
                                     fixlist, fixcnt, bin);
    k_count<<<800, 128, 0, stream>>>(bin, hist);
    k_offsets<<<8, 256, 0, stream>>>(hist, offs);
    k_scatter<<<800, 128, 0, stream>>>(bin, offs, mski, flat, mf);
    k_dm<<<800, 256, 0, stream>>>(xd, flat, mf, dmb, norm);
    // layer 0 (fused, XCD-locality remapped 1-D grid)
    k_layer<0><<<3200, 512, 0, stream>>>(xnb, flat, wbth0, wbwh0, wbwt0, bt0,
                                         dmb, norm, mf, out0, nullptr, nullptr);
    // layer 1 (fused, scattered fp32 output)
    k_layer<1><<<3200, 512, 0, stream>>>(out0, nullptr, wbth1, wbwh1, wbwt1, bt1,
                                         dmb, norm, mf, nullptr, (float*)d_out, flat);
}

// Round 11
// 388.436 us; speedup vs baseline: 2.8333x; 1.1321x over previous
//
#include <hip/hip_runtime.h>
#include <math.h>

#define BB 8
#define NN 12800
#define FF 256
#define DDIM 128
#define NBINS 100
#define BSIZE 128
#define NROT 50
#define NIDS 199
#define PTS (BB*NN)            // 102400

// ---- workspace layout (bytes) ----
#define OFF_OUT0 ((size_t)157286400)    // 52428800  : out0 bf16 [102400][256]
#define OFF_DMB  ((size_t)209715200)    // 26214400  : dm bf16 [800][128][128]
#define OFF_WB   ((size_t)235929600)    // 786432    : 6 weights bf16 transposed [256][256]
#define OFF_NORM ((size_t)236716032)    // 409600
#define OFF_MF   ((size_t)237125632)    // 409600
#define OFF_BIN  ((size_t)237535232)    // 409600 (int)
#define OFF_FLAT ((size_t)237944832)    // 409600 (int)
#define OFF_MSKI ((size_t)238354432)    // 409600 (int)
#define OFF_HIST ((size_t)238764032)    // 636800 (int)
#define OFF_OFFS ((size_t)239400832)    // 636800 (int)
#define OFF_FLAG ((size_t)240037632)    // 64
#define OFF_CNT  ((size_t)240037696)    // 64
#define OFF_LIST ((size_t)240037760)    // 409600 (int)
#define OFF_W1H  ((size_t)240447360)    // 65536 : w1^T hi bf16 [128][256]
#define OFF_W1L  ((size_t)240512896)    // 65536
#define OFF_W2H  ((size_t)240578432)    // 32768 : w2^T hi bf16 [128][128]
#define OFF_W2L  ((size_t)240611200)    // 32768
#define OFF_RH   ((size_t)240643968)    // 16384 : rot^T hi bf16 [64][128]
#define OFF_RL   ((size_t)240660352)    // 16384
#define HISTBYTES (8*100*199*4)

using short8  = __attribute__((ext_vector_type(8))) short;
using floatx4 = __attribute__((ext_vector_type(4))) float;

__device__ __forceinline__ ushort f2b(float f) {
    unsigned u = __float_as_uint(f);
    unsigned r = (u + 0x7FFFu + ((u >> 16) & 1u)) >> 16;
    return (ushort)r;
}
__device__ __forceinline__ float b2f(ushort h) {
    return __uint_as_float(((unsigned)h) << 16);
}
__device__ __forceinline__ uint4 pack8(const ushort* o) {
    uint4 u;
    u.x = (unsigned)o[0] | ((unsigned)o[1] << 16);
    u.y = (unsigned)o[2] | ((unsigned)o[3] << 16);
    u.z = (unsigned)o[4] | ((unsigned)o[5] << 16);
    u.w = (unsigned)o[6] | ((unsigned)o[7] << 16);
    return u;
}

// ---------- mask dtype sniffing ----------
__global__ void k_maskflag(const int* mi, int* flag) {
    __shared__ int notInt, notFloat;
    if (threadIdx.x == 0) { notInt = 0; notFloat = 0; }
    __syncthreads();
    int v = mi[threadIdx.x];
    if (v != 0 && v != 1) atomicOr(&notInt, 1);
    if (v != 0 && v != 0x3F800000) atomicOr(&notFloat, 1);
    __syncthreads();
    if (threadIdx.x == 0) flag[0] = (!notInt) ? 0 : ((!notFloat) ? 2 : 1);
}

__global__ void k_masknorm(const void* msk, const int* flag, int* mski) {
    int i = blockIdx.x * blockDim.x + threadIdx.x;
    if (i >= PTS) return;
    int f = flag[0];
    int v;
    if (f == 0)      v = ((const int*)msk)[i] != 0;
    else if (f == 2) v = ((const float*)msk)[i] != 0.0f;
    else             v = ((const unsigned char*)msk)[i] != 0;
    mski[i] = v;
}

// ---------- weight prep: fp32 [k][n] -> bf16 transposed [n][k] (GHConv weights) ----------
__global__ __launch_bounds__(256) void k_wprep(
    const float* s0, const float* s1, const float* s2,
    const float* s3, const float* s4, const float* s5,
    ushort* d0, ushort* d1, ushort* d2, ushort* d3, ushort* d4, ushort* d5)
{
    __shared__ float Ls[64 * 65];
    const float* src; ushort* dst;
    switch (blockIdx.y) {
        case 0: src = s0; dst = d0; break;
        case 1: src = s1; dst = d1; break;
        case 2: src = s2; dst = d2; break;
        case 3: src = s3; dst = d3; break;
        case 4: src = s4; dst = d4; break;
        default: src = s5; dst = d5; break;
    }
    int t = blockIdx.x;
    int kb = (t & 3) * 64, nb = (t >> 2) * 64;
    int tid = threadIdx.x;
    for (int q = 0; q < 4; ++q) {
        int g = q * 256 + tid;
        int kl = g >> 4, f4 = g & 15;
        float4 v = *(const float4*)(src + (size_t)(kb + kl) * 256 + nb + f4 * 4);
        Ls[kl * 65 + f4 * 4 + 0] = v.x;
        Ls[kl * 65 + f4 * 4 + 1] = v.y;
        Ls[kl * 65 + f4 * 4 + 2] = v.z;
        Ls[kl * 65 + f4 * 4 + 3] = v.w;
    }
    __syncthreads();
    for (int q = 0; q < 2; ++q) {
        int g = q * 256 + tid;
        int nl = g >> 3, wg = g & 7;
        ushort o[8];
        #pragma unroll
        for (int c = 0; c < 8; ++c) o[c] = f2b(Ls[(wg * 8 + c) * 65 + nl]);
        *(uint4*)(dst + (size_t)(nb + nl) * 256 + kb + wg * 8) = pack8(o);
    }
}

// ---------- split-weight prep: fp32 [K][srcN] -> hi/lo bf16 transposed [N][K] ----------
__global__ __launch_bounds__(256) void k_wsplit(const float* __restrict__ src, int K, int N,
                                               int srcN, int nvalid,
                                               ushort* __restrict__ dh, ushort* __restrict__ dl) {
    __shared__ float Ls[64 * 65];
    int tilesN = N >> 6;
    int kb = (blockIdx.x / tilesN) * 64, nb = (blockIdx.x % tilesN) * 64;
    int tid = threadIdx.x;
    for (int q = 0; q < 4; ++q) {
        int g = q * 256 + tid;
        int kl = g >> 4, c4 = (g & 15) * 4;
        #pragma unroll
        for (int j = 0; j < 4; ++j) {
            int n = nb + c4 + j;
            float v = (n < nvalid) ? src[(size_t)(kb + kl) * srcN + n] : 0.f;
            Ls[kl * 65 + c4 + j] = v;
        }
    }
    __syncthreads();
    for (int q = 0; q < 2; ++q) {
        int g = q * 256 + tid;
        int nl = g >> 3, wg = g & 7;
        ushort oh[8], ol[8];
        #pragma unroll
        for (int c = 0; c < 8; ++c) {
            float v = Ls[(wg * 8 + c) * 65 + nl];
            ushort h = f2b(v);
            oh[c] = h;
            ol[c] = f2b(v - b2f(h));
        }
        *(uint4*)(dh + (size_t)(nb + nl) * K + kb + wg * 8) = pack8(oh);
        *(uint4*)(dl + (size_t)(nb + nl) * K + kb + wg * 8) = pack8(ol);
    }
}

// ---------- MFMA LDS helpers (layout verified in rounds 2-10) ----------
// async staging: linear LDS dest (wave-uniform base + lane*16) with the XOR
// swizzle folded into the per-lane GLOBAL source chunk (involution: dst = src^(row&7)).
__device__ __forceinline__ void stage_async(const ushort* __restrict__ src, size_t pitch,
                                            const int* __restrict__ rowmap, int rowbase, size_t kbase,
                                            ushort* lds, int nrows, int tid) {
    int lane = tid & 63, wid = tid >> 6;
    int total = nrows * 8;
    for (int b0 = 0; b0 < total; b0 += 512) {
        int g = b0 + wid * 64 + lane;
        int row = g >> 3;
        int ck = (g & 7) ^ (row & 7);
        size_t srow = rowmap ? (size_t)rowmap[rowbase + row] : (size_t)(rowbase + row);
        const ushort* gp = src + srow * pitch + kbase + ck * 8;
        ushort* lp = lds + (size_t)(b0 + wid * 64) * 8;   // wave-uniform
        __builtin_amdgcn_global_load_lds(
            (const __attribute__((address_space(1))) unsigned int*)gp,
            (__attribute__((address_space(3))) unsigned int*)lp, 16, 0, 0);
    }
}

__device__ __forceinline__ short8 frag_ld(const ushort* lds, int row, int kc, int lane) {
    int w0 = (kc * 16 + ((lane >> 4) << 2)) ^ ((row & 7) << 2);
    return *(const short8*)((const char*)lds + row * 128 + w0 * 4);
}

// ---------- stage 1 v4: fused LN + FFN + rot via split-bf16 MFMA ----------
// 32 points/block, 512 threads, 64KB LDS -> 2 blocks/CU.
__global__ __launch_bounds__(512, 4) void k_stage1(
    const float* __restrict__ x, const float* __restrict__ g, const float* __restrict__ be,
    const float* __restrict__ b1, const float* __restrict__ b2,
    const ushort* __restrict__ w1h, const ushort* __restrict__ w1l,
    const ushort* __restrict__ w2h, const ushort* __restrict__ w2l,
    const ushort* __restrict__ rth, const ushort* __restrict__ rtl,
    const int* __restrict__ mski,
    ushort* __restrict__ xn_out, ushort* __restrict__ xdh_out, ushort* __restrict__ xdl_out,
    int* __restrict__ bin_out, int* __restrict__ fixlist, int* __restrict__ fixcnt)
{
    __shared__ ushort lXh[4 * 2048];   // 16KB : 4 k-slabs x [32 rows][64 k]
    __shared__ ushort lXl[4 * 2048];   // 16KB
    __shared__ ushort lWh[8192];       // 16KB : single weight slab [128][64]
    __shared__ ushort lWl[8192];       // 16KB
    int tid = threadIdx.x, lane = tid & 63, wid = tid >> 6;
    int base = blockIdx.x * 32;
    int l15 = lane & 15;
    int r4 = (lane >> 4) * 4;

    stage_async(w1h, 256, nullptr, 0, 0, lWh, 128, tid);
    stage_async(w1l, 256, nullptr, 0, 0, lWl, 128, tid);

    {   // ---- phase 0: LN (16 threads/point, 16 features each) ----
        int row = tid >> 4, sub = tid & 15;
        const float* xr = x + (size_t)(base + row) * FF + sub * 16;
        float v[16];
        float s = 0.f;
        #pragma unroll
        for (int q = 0; q < 4; ++q) {
            float4 f = *(const float4*)(xr + q * 4);
            v[q*4+0] = f.x; v[q*4+1] = f.y; v[q*4+2] = f.z; v[q*4+3] = f.w;
            s += f.x + f.y + f.z + f.w;
        }
        s += __shfl_xor(s, 1, 16); s += __shfl_xor(s, 2, 16);
        s += __shfl_xor(s, 4, 16); s += __shfl_xor(s, 8, 16);
        float mu = s * (1.f / 256.f);
        float s2 = 0.f;
        #pragma unroll
        for (int q = 0; q < 16; ++q) { float d = v[q] - mu; s2 += d * d; }
        s2 += __shfl_xor(s2, 1, 16); s2 += __shfl_xor(s2, 2, 16);
        s2 += __shfl_xor(s2, 4, 16); s2 += __shfl_xor(s2, 8, 16);
        float rs = 1.0f / sqrtf(s2 * (1.f / 256.f) + 1e-6f);
        ushort* xo = xn_out + (size_t)(base + row) * FF + sub * 16;
        #pragma unroll
        for (int j = 0; j < 2; ++j) {
            int i0 = sub * 16 + j * 8;
            float4 g0 = *(const float4*)(g + i0);
            float4 g1 = *(const float4*)(g + i0 + 4);
            float4 e0 = *(const float4*)(be + i0);
            float4 e1 = *(const float4*)(be + i0 + 4);
            float gv[8] = {g0.x,g0.y,g0.z,g0.w,g1.x,g1.y,g1.z,g1.w};
            float ev[8] = {e0.x,e0.y,e0.z,e0.w,e1.x,e1.y,e1.z,e1.w};
            ushort hh[8], ll[8];
            #pragma unroll
            for (int c = 0; c < 8; ++c) {
                float xv = (v[j*8+c] - mu) * rs * gv[c] + ev[c];
                ushort h = f2b(xv);
                hh[c] = h;
                ll[c] = f2b(xv - b2f(h));
            }
            uint4 uh = pack8(hh), ul = pack8(ll);
            *(uint4*)(xo + j * 8) = uh;
            int kb = i0 >> 6;
            int wg = (i0 & 63) >> 3;
            int w0 = (wg * 4) ^ ((row & 7) << 2);
            *(uint4*)((char*)lXh + kb * 4096 + row * 128 + w0 * 4) = uh;
            *(uint4*)((char*)lXl + kb * 4096 + row * 128 + w0 * 4) = ul;
        }
    }
    __syncthreads();

    int mg = wid >> 2, ng = wid & 3;
    int wm = mg * 16, wn = ng * 32;
    floatx4 zf = {0.f, 0.f, 0.f, 0.f};

    // ---- GEMM1: h = elu(xn @ w1 + b1), M=32 N=128 K=256 ----
    floatx4 acc[2];
    acc[0] = zf; acc[1] = zf;
    for (int kb = 0; kb < 4; ++kb) {
        #pragma unroll
        for (int kc = 0; kc < 2; ++kc) {
            short8 ah, al, bh[2], bl[2];
            ah = frag_ld(lXh + kb * 2048, wm + l15, kc, lane);
            al = frag_ld(lXl + kb * 2048, wm + l15, kc, lane);
            #pragma unroll
            for (int n = 0; n < 2; n++) {
                bh[n] = frag_ld(lWh, wn + n * 16 + l15, kc, lane);
                bl[n] = frag_ld(lWl, wn + n * 16 + l15, kc, lane);
            }
            #pragma unroll
            for (int n = 0; n < 2; n++) {
                acc[n] = __builtin_amdgcn_mfma_f32_16x16x32_bf16(ah, bh[n], acc[n], 0, 0, 0);
                acc[n] = __builtin_amdgcn_mfma_f32_16x16x32_bf16(ah, bl[n], acc[n], 0, 0, 0);
                acc[n] = __builtin_amdgcn_mfma_f32_16x16x32_bf16(al, bh[n], acc[n], 0, 0, 0);
            }
        }
        __syncthreads();
        if (kb < 3) {
            stage_async(w1h, 256, nullptr, 0, (size_t)(kb + 1) * 64, lWh, 128, tid);
            stage_async(w1l, 256, nullptr, 0, (size_t)(kb + 1) * 64, lWl, 128, tid);
            __syncthreads();
        }
    }
    stage_async(w2h, 128, nullptr, 0, 0, lWh, 128, tid);
    stage_async(w2l, 128, nullptr, 0, 0, lWl, 128, tid);
    {
        #pragma unroll
        for (int n = 0; n < 2; n++) {
            int cg = wn + n * 16 + l15;
            float b1v = b1[cg];
            int slab = cg >> 6, c64 = cg & 63;
            int wg = c64 >> 3, e = c64 & 7;
            #pragma unroll
            for (int i = 0; i < 4; i++) {
                int r = wm + r4 + i;
                float hv = acc[n][i] + b1v;
                hv = (hv > 0.f) ? hv : expm1f(hv);
                ushort h = f2b(hv);
                int w0 = (wg * 4) ^ ((r & 7) << 2);
                int idx = slab * 2048 + r * 64 + w0 * 2 + e;
                lXh[idx] = h;
                lXl[idx] = f2b(hv - b2f(h));
            }
        }
    }
    __syncthreads();

    // ---- GEMM2: xd = h @ w2 + b2, M=32 N=128 K=128 ----
    floatx4 acc2[2];
    acc2[0] = zf; acc2[1] = zf;
    for (int kb = 0; kb < 2; ++kb) {
        #pragma unroll
        for (int kc = 0; kc < 2; ++kc) {
            short8 ah, al, bh[2], bl[2];
            ah = frag_ld(lXh + kb * 2048, wm + l15, kc, lane);
            al = frag_ld(lXl + kb * 2048, wm + l15, kc, lane);
            #pragma unroll
            for (int n = 0; n < 2; n++) {
                bh[n] = frag_ld(lWh, wn + n * 16 + l15, kc, lane);
                bl[n] = frag_ld(lWl, wn + n * 16 + l15, kc, lane);
            }
            #pragma unroll
            for (int n = 0; n < 2; n++) {
                acc2[n] = __builtin_amdgcn_mfma_f32_16x16x32_bf16(ah, bh[n], acc2[n], 0, 0, 0);
                acc2[n] = __builtin_amdgcn_mfma_f32_16x16x32_bf16(ah, bl[n], acc2[n], 0, 0, 0);
                acc2[n] = __builtin_amdgcn_mfma_f32_16x16x32_bf16(al, bh[n], acc2[n], 0, 0, 0);
            }
        }
        __syncthreads();
        if (kb == 0) {
            stage_async(w2h, 128, nullptr, 0, 64, lWh, 128, tid);
            stage_async(w2l, 128, nullptr, 0, 64, lWl, 128, tid);
            __syncthreads();
        }
    }
    stage_async(rth, 128, nullptr, 0, 0, lWh, 64, tid);
    stage_async(rtl, 128, nullptr, 0, 0, lWl, 64, tid);
    stage_async(rth, 128, nullptr, 0, 64, lWh + 4096, 64, tid);
    stage_async(rtl, 128, nullptr, 0, 64, lWl + 4096, 64, tid);
    {
        #pragma unroll
        for (int n = 0; n < 2; n++) {
            int cg = wn + n * 16 + l15;
            float b2v = b2[cg];
            int slab = 2 + (cg >> 6), c64 = cg & 63;
            int wg = c64 >> 3, e = c64 & 7;
            #pragma unroll
            for (int i = 0; i < 4; i++) {
                int r = wm + r4 + i;
                float xv = acc2[n][i] + b2v;
                ushort h = f2b(xv);
                ushort lo = f2b(xv - b2f(h));
                size_t go = (size_t)(base + r) * DDIM + cg;
                xdh_out[go] = h;
                xdl_out[go] = lo;
                int w0 = (wg * 4) ^ ((r & 7) << 2);
                int idx = slab * 2048 + r * 64 + w0 * 2 + e;
                lXh[idx] = h;
                lXl[idx] = lo;
            }
        }
    }
    __syncthreads();

    // ---- GEMM3: mul = xd @ rot, M=32 N=64 K=128 ----
    floatx4 acc3 = zf;
    int wn3 = ng * 16;
    for (int kb = 0; kb < 2; ++kb) {
        #pragma unroll
        for (int kc = 0; kc < 2; ++kc) {
            short8 ah, al, bh, bl;
            ah = frag_ld(lXh + (2 + kb) * 2048, wm + l15, kc, lane);
            al = frag_ld(lXl + (2 + kb) * 2048, wm + l15, kc, lane);
            bh = frag_ld(lWh + kb * 4096, wn3 + l15, kc, lane);
            bl = frag_ld(lWl + kb * 4096, wn3 + l15, kc, lane);
            acc3 = __builtin_amdgcn_mfma_f32_16x16x32_bf16(ah, bh, acc3, 0, 0, 0);
            acc3 = __builtin_amdgcn_mfma_f32_16x16x32_bf16(ah, bl, acc3, 0, 0, 0);
            acc3 = __builtin_amdgcn_mfma_f32_16x16x32_bf16(al, bh, acc3, 0, 0, 0);
        }
    }
    __syncthreads();
    float* lMul = (float*)lXh;
    {
        #pragma unroll
        for (int i = 0; i < 4; i++) {
            int r = wm + r4 + i;
            lMul[r * 65 + wn3 + l15] = acc3[i];
        }
    }
    __syncthreads();

    {   // ---- top-2 argmax over [mul, -mul], margin flag (16 thr/pt) ----
        int p = tid >> 4, q = tid & 15;
        float v1 = -1e30f, v2 = -1e30f; int i1 = 1 << 29;
        #pragma unroll
        for (int j = 0; j < 4; ++j) {
            int c = q * 4 + j;
            if (c < 50) {
                float m = lMul[p * 65 + c];
                float wv, lv; int wi, li;
                if (m >= 0.f) { wv = m; wi = c; lv = -m; li = 50 + c; }
                else          { wv = -m; wi = 50 + c; lv = m; li = c; }
                if (wv > v1 || (wv == v1 && wi < i1)) { v2 = v1; v1 = wv; i1 = wi; }
                else if (wv > v2) v2 = wv;
                if (lv > v1 || (lv == v1 && li < i1)) { v2 = v1; v1 = lv; i1 = li; }
                else if (lv > v2) v2 = lv;
            }
        }
        #pragma unroll
        for (int off = 1; off < 16; off <<= 1) {
            float o1 = __shfl_xor(v1, off, 16);
            int   oi = __shfl_xor(i1, off, 16);
            float o2 = __shfl_xor(v2, off, 16);
            bool take = (o1 > v1) || (o1 == v1 && oi < i1);
            float small = take ? v1 : o1;
            if (take) { v1 = o1; i1 = oi; }
            v2 = fmaxf(fmaxf(v2, o2), small);
        }
        if (q == 0) {
            int pt = base + p;
            bin_out[pt] = i1 + (mski[pt] ? 0 : (NBINS - 1));
            float tau = 3e-4f + 1.5e-3f * v1;
            if (v1 - v2 < tau) {
                int pos = atomicAdd(fixcnt, 1);
                fixlist[pos] = pt;
            }
        }
    }
}

// ---------- fp64 fixup for margin-flagged points ----------
__global__ __launch_bounds__(64) void k_fixup(
    const float* __restrict__ x, const float* __restrict__ g, const float* __restrict__ be,
    const float* __restrict__ w1, const float* __restrict__ b1,
    const float* __restrict__ w2, const float* __restrict__ b2,
    const float* __restrict__ rot, const int* __restrict__ mski,
    const int* __restrict__ fixlist, const int* __restrict__ fixcnt,
    int* __restrict__ bin_out)
{
    __shared__ double xn_s[256];
    __shared__ double h_s[128];
    __shared__ double xd_s[128];
    int lane = threadIdx.x;
    int n = fixcnt[0];
    for (int e = blockIdx.x; e < n; e += gridDim.x) {
        int pt = fixlist[e];
        const float* xr = x + (size_t)pt * FF;
        double s = 0.0, xv[4];
        #pragma unroll
        for (int q = 0; q < 4; q++) { xv[q] = (double)xr[lane + q * 64]; s += xv[q]; }
        #pragma unroll
        for (int off = 1; off < 64; off <<= 1) s += __shfl_xor(s, off, 64);
        double mu = s * (1.0 / 256.0);
        double s2 = 0.0;
        #pragma unroll
        for (int q = 0; q < 4; q++) { double d = xv[q] - mu; s2 += d * d; }
        #pragma unroll
        for (int off = 1; off < 64; off <<= 1) s2 += __shfl_xor(s2, off, 64);
        double rs = 1.0 / sqrt(s2 * (1.0 / 256.0) + 1e-6);
        #pragma unroll
        for (int q = 0; q < 4; q++) {
            int i = lane + q * 64;
            xn_s[i] = (xv[q] - mu) * rs * (double)g[i] + (double)be[i];
        }
        __syncthreads();
        #pragma unroll
        for (int q = 0; q < 2; q++) {
            int j = lane + q * 64;
            double a0 = 0.0, a1 = 0.0;
            for (int k = 0; k < FF; k += 2) {
                a0 += xn_s[k] * (double)w1[k * DDIM + j];
                a1 += xn_s[k + 1] * (double)w1[(k + 1) * DDIM + j];
            }
            double a = (double)b1[j] + a0 + a1;
            h_s[j] = (a > 0.0) ? a : expm1(a);
        }
        __syncthreads();
        #pragma unroll
        for (int q = 0; q < 2; q++) {
            int j = lane + q * 64;
            double a0 = 0.0, a1 = 0.0;
            for (int k = 0; k < DDIM; k += 2) {
                a0 += h_s[k] * (double)w2[k * DDIM + j];
                a1 += h_s[k + 1] * (double)w2[(k + 1) * DDIM + j];
            }
            xd_s[j] = (double)b2[j] + a0 + a1;
        }
        __syncthreads();
        double v; int idx;
        if (lane < NROT) {
            double m = 0.0;
            for (int k = 0; k < DDIM; k++) m += xd_s[k] * (double)rot[k * 100 + lane];
            if (m >= 0.0) { v = m; idx = lane; } else { v = -m; idx = 50 + lane; }
        } else { v = -1e300; idx = 1 << 29; }
        #pragma unroll
        for (int off = 1; off < 64; off <<= 1) {
            double ov = __shfl_xor(v, off, 64);
            int oi = __shfl_xor(idx, off, 64);
            if (ov > v || (ov == v && oi < idx)) { v = ov; idx = oi; }
        }
        if (lane == 0) bin_out[pt] = idx + (mski[pt] ? 0 : (NBINS - 1));
        __syncthreads();
    }
}

// ---------- binning: stable counting sort ----------
__global__ void k_count(const int* __restrict__ bin, int* __restrict__ hist) {
    int c = blockIdx.x % 100, b = blockIdx.x / 100;
    int t = threadIdx.x;
    int v = bin[b * NN + c * BSIZE + t];
    atomicAdd(&hist[(b * 100 + c) * NIDS + v], 1);
}

__global__ void k_offsets(const int* __restrict__ hist, int* __restrict__ offs) {
    __shared__ int tot[NIDS];
    __shared__ int start[NIDS];
    int b = blockIdx.x, v = threadIdx.x;
    if (v < NIDS) {
        int s = 0;
        for (int c = 0; c < 100; c++) s += hist[(b * 100 + c) * NIDS + v];
        tot[v] = s;
    }
    __syncthreads();
    if (threadIdx.x == 0) {
        int run = 0;
        for (int i = 0; i < NIDS; i++) { start[i] = run; run += tot[i]; }
    }
    __syncthreads();
    if (v < NIDS) {
        int run = start[v];
        for (int c = 0; c < 100; c++) {
            offs[(b * 100 + c) * NIDS + v] = run;
            run += hist[(b * 100 + c) * NIDS + v];
        }
    }
}

__global__ void k_scatter(const int* __restrict__ bin, const int* __restrict__ offs,
                          const int* __restrict__ mski, int* __restrict__ flat,
                          float* __restrict__ mf) {
    __shared__ int sv[BSIZE];
    int c = blockIdx.x % 100, b = blockIdx.x / 100;
    int t = threadIdx.x;
    int n = c * BSIZE + t;
    int v = bin[b * NN + n];
    sv[t] = v;
    __syncthreads();
    int rank = 0;
    for (int u = 0; u < t; u++) rank += (sv[u] == v);
    int r = offs[(b * 100 + c) * NIDS + v] + rank;
    flat[b * NN + r] = b * NN + n;
    mf[b * NN + r] = mski[b * NN + n] ? 1.0f : 0.0f;
}

// ---------- k_dm v2: per-bin Gram matrix via split-bf16 MFMA, async gather staging ----------
// 800 blocks x 512 threads, 64KB+small LDS -> 2 blocks/CU.
__global__ __launch_bounds__(512, 4) void k_dm(const ushort* __restrict__ xdh, const ushort* __restrict__ xdl,
                                               const int* __restrict__ flat, const float* __restrict__ mf,
                                               ushort* __restrict__ dmb, float* __restrict__ norm) {
    __shared__ ushort lX[32768];   // Xh slabs at [0),[8192); Xl at [16384),[24576); bounce aliases [0..17408)
    __shared__ float na[128];
    __shared__ float ml[128];
    __shared__ float ps[512];
    int tid = threadIdx.x, lane = tid & 63, wid = tid >> 6;
    int g = blockIdx.x;
    int rowbase = g * 128;
    int l15 = lane & 15;
    int r4 = (lane >> 4) * 4;
    int mg = wid >> 2, ng = wid & 3;
    int wm = mg * 64, wn = ng * 32;
    floatx4 zf = {0.f, 0.f, 0.f, 0.f};

    stage_async(xdh, 128, flat, rowbase, 0, lX, 128, tid);
    stage_async(xdh, 128, flat, rowbase, 64, lX + 8192, 128, tid);
    stage_async(xdl, 128, flat, rowbase, 0, lX + 16384, 128, tid);
    stage_async(xdl, 128, flat, rowbase, 64, lX + 24576, 128, tid);
    if (tid < 128) ml[tid] = mf[rowbase + tid];
    __syncthreads();

    {   // na pass: na[r] = sum_k (h+l)^2  (swizzle permutes within-row only -> sum invariant)
        int row = tid >> 2, part = tid & 3;
        float s = 0.f;
        #pragma unroll
        for (int kb = 0; kb < 2; ++kb) {
            const ushort* ph = lX + kb * 8192 + row * 64 + part * 16;
            #pragma unroll
            for (int q = 0; q < 2; ++q) {
                uint4 uh = *(const uint4*)(ph + q * 8);
                uint4 ul = *(const uint4*)(ph + 16384 + q * 8);
                const unsigned* wh_ = (const unsigned*)&uh;
                const unsigned* wl_ = (const unsigned*)&ul;
                #pragma unroll
                for (int w = 0; w < 4; ++w) {
                    float x0 = b2f((ushort)(wh_[w] & 0xFFFFu)) + b2f((ushort)(wl_[w] & 0xFFFFu));
                    float x1 = b2f((ushort)(wh_[w] >> 16)) + b2f((ushort)(wl_[w] >> 16));
                    s = fmaf(x0, x0, s);
                    s = fmaf(x1, x1, s);
                }
            }
        }
        s += __shfl_xor(s, 1, 4);
        s += __shfl_xor(s, 2, 4);
        if (part == 0) na[row] = s;
    }

    // Gram GEMM: S = Xh.Xh^T + Xh.Xl^T + Xl.Xh^T  (M=128 N=128 K=128)
    floatx4 acc[4][2];
    #pragma unroll
    for (int m = 0; m < 4; m++) { acc[m][0] = zf; acc[m][1] = zf; }
    for (int kb = 0; kb < 2; ++kb) {
        #pragma unroll
        for (int kc = 0; kc < 2; ++kc) {
            short8 ah[4], al[4], bh[2], bl[2];
            #pragma unroll
            for (int m = 0; m < 4; m++) {
                ah[m] = frag_ld(lX + kb * 8192, wm + m * 16 + l15, kc, lane);
                al[m] = frag_ld(lX + 16384 + kb * 8192, wm + m * 16 + l15, kc, lane);
            }
            #pragma unroll
            for (int n = 0; n < 2; n++) {
                bh[n] = frag_ld(lX + kb * 8192, wn + n * 16 + l15, kc, lane);
                bl[n] = frag_ld(lX + 16384 + kb * 8192, wn + n * 16 + l15, kc, lane);
            }
            #pragma unroll
            for (int m = 0; m < 4; m++)
                #pragma unroll
                for (int n = 0; n < 2; n++) {
                    acc[m][n] = __builtin_amdgcn_mfma_f32_16x16x32_bf16(ah[m], bh[n], acc[m][n], 0, 0, 0);
                    acc[m][n] = __builtin_amdgcn_mfma_f32_16x16x32_bf16(ah[m], bl[n], acc[m][n], 0, 0, 0);
                    acc[m][n] = __builtin_amdgcn_mfma_f32_16x16x32_bf16(al[m], bh[n], acc[m][n], 0, 0, 0);
                }
        }
    }
    __syncthreads();   // na visible to all; lX reads done -> bounce overwrite safe

    // epilogue: dv = exp(-0.1*sqrt(max(D2,1e-6)))*m_r*m_c ; bounce [128][136]; row-sum partials
    ushort* Ls = lX;
    for (int m = 0; m < 4; ++m) {
        int r0 = wm + m * 16 + r4;
        float rs[4] = {0.f, 0.f, 0.f, 0.f};
        #pragma unroll
        for (int n = 0; n < 2; ++n) {
            int c = wn + n * 16 + l15;
            float nac = na[c], mlc = ml[c];
            #pragma unroll
            for (int i = 0; i < 4; ++i) {
                int r = r0 + i;
                float D2 = na[r] - 2.f * acc[m][n][i] + nac;
                float dv = expf(-0.1f * sqrtf(fmaxf(D2, 1e-6f)));
                dv *= ml[r] * mlc;
                rs[i] += dv;
                Ls[r * 136 + c] = f2b(dv);
            }
        }
        #pragma unroll
        for (int off = 1; off < 16; off <<= 1) {
            #pragma unroll
            for (int i = 0; i < 4; ++i) rs[i] += __shfl_xor(rs[i], off, 16);
        }
        if (l15 == 0) {
            #pragma unroll
            for (int i = 0; i < 4; ++i) ps[(r0 + i) * 4 + ng] = rs[i];
        }
    }
    __syncthreads();

    // coalesced dm store + norm
    #pragma unroll
    for (int it = 0; it < 4; ++it) {
        int gi = it * 512 + tid;
        int row = gi >> 4, ch = gi & 15;
        uint4 v = *(const uint4*)(Ls + row * 136 + ch * 8);
        *(uint4*)(dmb + (size_t)g * 16384 + row * 128 + ch * 8) = v;
    }
    if (tid < 128) {
        float deg = ps[tid * 4 + 0] + ps[tid * 4 + 1] + ps[tid * 4 + 2] + ps[tid * 4 + 3];
        deg = fminf(deg, 1000.0f);
        norm[rowbase + tid] = (1.0f / sqrtf(deg + 1e-6f)) * ml[tid];
    }
}

// ---------- fused per-layer graph conv v2: merged triple GEMM, 80KB LDS, 2 blocks/CU ----------
// 1-D grid 3200 with XCD-locality remap: id = grp*32 + nh*8 + gsub -> g = grp*8+gsub.
template<int LAYER>
__global__ __launch_bounds__(512, 4) void k_layer(
    const ushort* __restrict__ A, const int* __restrict__ rowmap,
    const ushort* __restrict__ ThT, const ushort* __restrict__ WhT, const ushort* __restrict__ WtT,
    const float* __restrict__ bt, const ushort* __restrict__ dmb,
    const float* __restrict__ norm, const float* __restrict__ mf,
    ushort* __restrict__ outb, float* __restrict__ outf, const int* __restrict__ flatscat)
{
    __shared__ char smem[81920];
    ushort* lAbuf = (ushort*)smem;                 // 2 x 16KB A ping
    ushort* lB    = (ushort*)(smem + 32768);       // 6 x 8KB: th0 th1 wh0 wh1 wt0 wt1
    ushort* lT    = (ushort*)smem;                 // post-GEMM: 2 x 8KB T^T j-slabs
    ushort* ldm   = (ushort*)(smem + 32768);       // post-GEMM: 2 x 16KB dm slabs

    int tid = threadIdx.x, lane = tid & 63, wid = tid >> 6;
    int bid = blockIdx.x;
    int grp = bid >> 5, within = bid & 31;
    int nh = within >> 3, g = grp * 8 + (within & 7);
    int rowbase = g * 128, nbase = nh * 64;
    int l15 = lane & 15;
    int r4 = (lane >> 4) * 4;
    int wm = (wid >> 1) * 32, wn = (wid & 1) * 32;
    const ushort* dmg = dmb + (size_t)g * 16384;
    floatx4 zf = {0.f, 0.f, 0.f, 0.f};

    stage_async(A, 256, rowmap, rowbase, 0, lAbuf, 128, tid);
    stage_async(ThT, 256, nullptr, nbase, 0, lB + 0 * 4096, 64, tid);
    stage_async(WhT, 256, nullptr, nbase, 0, lB + 2 * 4096, 64, tid);
    stage_async(WtT, 256, nullptr, nbase, 0, lB + 4 * 4096, 64, tid);
    __syncthreads();

    // ---- merged GEMM: T = A@Th, H = A@Wh, G = A@Wt  (M=128, N=64, K=256) ----
    floatx4 accT[2][2], accH[2][2], accG[2][2];
    #pragma unroll
    for (int m = 0; m < 2; m++)
        #pragma unroll
        for (int n = 0; n < 2; n++) { accT[m][n] = zf; accH[m][n] = zf; accG[m][n] = zf; }
    for (int kb = 0; kb < 4; ++kb) {
        if (kb < 3) {
            int pp = (kb + 1) & 1;
            stage_async(A, 256, rowmap, rowbase, (size_t)(kb + 1) * 64, lAbuf + pp * 8192, 128, tid);
            stage_async(ThT, 256, nullptr, nbase, (size_t)(kb + 1) * 64, lB + (0 + pp) * 4096, 64, tid);
            stage_async(WhT, 256, nullptr, nbase, (size_t)(kb + 1) * 64, lB + (2 + pp) * 4096, 64, tid);
            stage_async(WtT, 256, nullptr, nbase, (size_t)(kb + 1) * 64, lB + (4 + pp) * 4096, 64, tid);
        }
        const ushort* lA = lAbuf + (kb & 1) * 8192;
        const ushort* sTh = lB + (0 + (kb & 1)) * 4096;
        const ushort* sWh = lB + (2 + (kb & 1)) * 4096;
        const ushort* sWt = lB + (4 + (kb & 1)) * 4096;
        #pragma unroll
        for (int kc = 0; kc < 2; ++kc) {
            short8 a[2], bt_[2], bh_[2], bg_[2];
            #pragma unroll
            for (int m = 0; m < 2; m++) a[m] = frag_ld(lA, wm + m * 16 + l15, kc, lane);
            #pragma unroll
            for (int n = 0; n < 2; n++) {
                bt_[n] = frag_ld(sTh, wn + n * 16 + l15, kc, lane);
                bh_[n] = frag_ld(sWh, wn + n * 16 + l15, kc, lane);
                bg_[n] = frag_ld(sWt, wn + n * 16 + l15, kc, lane);
            }
            #pragma unroll
            for (int m = 0; m < 2; m++)
                #pragma unroll
                for (int n = 0; n < 2; n++) {
                    accT[m][n] = __builtin_amdgcn_mfma_f32_16x16x32_bf16(a[m], bt_[n], accT[m][n], 0, 0, 0);
                    accH[m][n] = __builtin_amdgcn_mfma_f32_16x16x32_bf16(a[m], bh_[n], accH[m][n], 0, 0, 0);
                    accG[m][n] = __builtin_amdgcn_mfma_f32_16x16x32_bf16(a[m], bg_[n], accG[m][n], 0, 0, 0);
                }
        }
        __syncthreads();
    }

    stage_async(dmg, 128, nullptr, 0, 0, ldm, 128, tid);
    stage_async(dmg, 128, nullptr, 0, 64, ldm + 8192, 128, tid);

    {   // T^T (scaled by norm, bf16, frag-swizzled) into lT j-slabs
        #pragma unroll
        for (int m = 0; m < 2; m++) {
            float4 nv = *(const float4*)(norm + rowbase + wm + m * 16 + r4);
            float nvv[4] = {nv.x, nv.y, nv.z, nv.w};
            int jloc0 = wm + m * 16 + r4;
            int jb = jloc0 >> 6, jj = jloc0 & 63;
            #pragma unroll
            for (int n = 0; n < 2; n++) {
                int cloc = wn + n * 16 + l15;
                char* bp = (char*)(lT + jb * 4096) + cloc * 128;
                int cx = (cloc & 7) << 2;
                ushort t0 = f2b(accT[m][n][0] * nvv[0]);
                ushort t1 = f2b(accT[m][n][1] * nvv[1]);
                ushort t2 = f2b(accT[m][n][2] * nvv[2]);
                ushort t3 = f2b(accT[m][n][3] * nvv[3]);
                *(unsigned*)(bp + ((((jj >> 1) + 0) ^ cx) << 2)) = (unsigned)t0 | ((unsigned)t1 << 16);
                *(unsigned*)(bp + ((((jj >> 1) + 1) ^ cx) << 2)) = (unsigned)t2 | ((unsigned)t3 << 16);
            }
        }
    }
    __syncthreads();

    // ---- phase A: FH = dm @ T  (M=128, N=64, K=128) ----
    floatx4 accFH[2][2];
    #pragma unroll
    for (int m = 0; m < 2; m++) { accFH[m][0] = zf; accFH[m][1] = zf; }
    for (int kb = 0; kb < 2; ++kb) {
        #pragma unroll
        for (int kc = 0; kc < 2; ++kc) {
            short8 a[2], b[2];
            #pragma unroll
            for (int m = 0; m < 2; m++) a[m] = frag_ld(ldm + kb * 8192, wm + m * 16 + l15, kc, lane);
            #pragma unroll
            for (int n = 0; n < 2; n++) b[n] = frag_ld(lT + kb * 4096, wn + n * 16 + l15, kc, lane);
            #pragma unroll
            for (int m = 0; m < 2; m++)
                #pragma unroll
                for (int n = 0; n < 2; n++)
                    accFH[m][n] = __builtin_amdgcn_mfma_f32_16x16x32_bf16(a[m], b[n], accFH[m][n], 0, 0, 0);
        }
    }
    __syncthreads();

    // ---- epilogue: gate/elu combine + coalesced store (wave-local bounce) ----
    for (int m = 0; m < 2; m++) {
        int r0l = wm + m * 16 + r4;
        int r0g = rowbase + r0l;
        float4 mv = *(const float4*)(mf + r0g);
        float4 nv = *(const float4*)(norm + r0g);
        float mvv[4] = {mv.x, mv.y, mv.z, mv.w};
        float nvv[4] = {nv.x, nv.y, nv.z, nv.w};
        float vals[2][4];
        #pragma unroll
        for (int n = 0; n < 2; n++) {
            int cg = nbase + wn + n * 16 + l15;
            float btc = bt[cg];
            #pragma unroll
            for (int i = 0; i < 4; i++) {
                float gate = 1.f / (1.f + expf(-(accG[m][n][i] + btc)));
                float fh = accFH[m][n][i] * nvv[i];
                float het = mvv[i] * accH[m][n][i];
                float o = gate * fh + (1.f - gate) * het;
                o = (o > 0.f) ? o : expm1f(o);
                vals[n][i] = o * mvv[i];
            }
        }
        if (LAYER == 0) {
            ushort* Ls = (ushort*)smem;
            int bbase = wid * 512;
            #pragma unroll
            for (int n = 0; n < 2; n++)
                #pragma unroll
                for (int i = 0; i < 4; i++)
                    Ls[bbase + (r4 + i) * 32 + n * 16 + l15] = f2b(vals[n][i]);
            __builtin_amdgcn_s_waitcnt(0);
            #pragma unroll
            for (int it = 0; it < 2; ++it) {
                int lr = (lane >> 3) + it * 8;
                int lc4 = (lane & 7) * 4;
                ushort4 tv = *(const ushort4*)(Ls + bbase + lr * 32 + lc4);
                int rg = rowbase + wm + m * 16 + lr;
                *(ushort4*)(outb + (size_t)rg * 256 + nbase + wn + lc4) = tv;
            }
        } else {
            float* Ls = (float*)smem;
            int bbase = wid * 512;
            #pragma unroll
            for (int n = 0; n < 2; n++)
                #pragma unroll
                for (int i = 0; i < 4; i++)
                    Ls[bbase + (r4 + i) * 32 + n * 16 + l15] = vals[n][i];
            __builtin_amdgcn_s_waitcnt(0);
            #pragma unroll
            for (int it = 0; it < 2; ++it) {
                int lr = (lane >> 3) + it * 8;
                int lc4 = (lane & 7) * 4;
                float4 tv = *(const float4*)(Ls + bbase + lr * 32 + lc4);
                int rg = rowbase + wm + m * 16 + lr;
                int dst = flatscat[rg];
                *(float4*)(outf + (size_t)dst * 256 + nbase + wn + lc4) = tv;
            }
        }
    }
}

extern "C" void kernel_launch(void* const* d_in, const int* in_sizes, int n_in,
                              void* d_out, int out_size, void* d_ws, size_t ws_size,
                              hipStream_t stream) {
    const float* x    = (const float*)d_in[0];
    const void*  msk  = d_in[1];
    const float* ln_g = (const float*)d_in[2];
    const float* ln_b = (const float*)d_in[3];
    const float* w1   = (const float*)d_in[4];
    const float* b1   = (const float*)d_in[5];
    const float* w2   = (const float*)d_in[6];
    const float* b2   = (const float*)d_in[7];
    const float* rot  = (const float*)d_in[8];
    const float* th0  = (const float*)d_in[9];
    const float* wh0  = (const float*)d_in[10];
    const float* wt0  = (const float*)d_in[11];
    const float* bt0  = (const float*)d_in[12];
    const float* th1  = (const float*)d_in[13];
    const float* wh1  = (const float*)d_in[14];
    const float* wt1  = (const float*)d_in[15];
    const float* bt1  = (const float*)d_in[16];

    char* ws = (char*)d_ws;
    ushort* out0 = (ushort*)(ws + OFF_OUT0);
    ushort* dmb  = (ushort*)(ws + OFF_DMB);
    ushort* wb   = (ushort*)(ws + OFF_WB);
    ushort* wbth0 = wb + 0 * 65536;
    ushort* wbwh0 = wb + 1 * 65536;
    ushort* wbwt0 = wb + 2 * 65536;
    ushort* wbth1 = wb + 3 * 65536;
    ushort* wbwh1 = wb + 4 * 65536;
    ushort* wbwt1 = wb + 5 * 65536;
    float* norm = (float*)(ws + OFF_NORM);
    float* mf   = (float*)(ws + OFF_MF);
    int*   bin  = (int*)(ws + OFF_BIN);
    int*   flat = (int*)(ws + OFF_FLAT);
    int*   mski = (int*)(ws + OFF_MSKI);
    int*   hist = (int*)(ws + OFF_HIST);
    int*   offs = (int*)(ws + OFF_OFFS);
    int*   flag = (int*)(ws + OFF_FLAG);
    int*   fixcnt = (int*)(ws + OFF_CNT);
    int*   fixlist = (int*)(ws + OFF_LIST);
    ushort* w1h = (ushort*)(ws + OFF_W1H);
    ushort* w1l = (ushort*)(ws + OFF_W1L);
    ushort* w2h = (ushort*)(ws + OFF_W2H);
    ushort* w2l = (ushort*)(ws + OFF_W2L);
    ushort* rth = (ushort*)(ws + OFF_RH);
    ushort* rtl = (ushort*)(ws + OFF_RL);
    // d_out scratch: xdh [0,26MB), xdl [26,52MB), xn bf16 [52,104MB); all dead
    // before layer1's final scattered fp32 output overwrites d_out.
    ushort* xdh = (ushort*)d_out;
    ushort* xdl = xdh + (size_t)PTS * DDIM;
    ushort* xnb = (ushort*)((char*)d_out + (size_t)PTS * DDIM * 4);

    hipMemsetAsync(hist, 0, HISTBYTES, stream);
    hipMemsetAsync(fixcnt, 0, 4, stream);
    k_maskflag<<<1, 256, 0, stream>>>((const int*)msk, flag);
    k_masknorm<<<PTS / 256, 256, 0, stream>>>(msk, flag, mski);
    k_wprep<<<dim3(16, 6), 256, 0, stream>>>(th0, wh0, wt0, th1, wh1, wt1,
                                             wbth0, wbwh0, wbwt0, wbth1, wbwh1, wbwt1);
    k_wsplit<<<8, 256, 0, stream>>>(w1, 256, 128, 128, 128, w1h, w1l);
    k_wsplit<<<4, 256, 0, stream>>>(w2, 128, 128, 128, 128, w2h, w2l);
    k_wsplit<<<2, 256, 0, stream>>>(rot, 128, 64, 100, 50, rth, rtl);
    k_stage1<<<PTS / 32, 512, 0, stream>>>(x, ln_g, ln_b, b1, b2,
                                           w1h, w1l, w2h, w2l, rth, rtl, mski,
                                           xnb, xdh, xdl, bin, fixlist, fixcnt);
    k_fixup<<<4096, 64, 0, stream>>>(x, ln_g, ln_b, w1, b1, w2, b2, rot, mski,
                                     fixlist, fixcnt, bin);
    k_count<<<800, 128, 0, stream>>>(bin, hist);
    k_offsets<<<8, 256, 0, stream>>>(hist, offs);
    k_scatter<<<800, 128, 0, stream>>>(bin, offs, mski, flat, mf);
    k_dm<<<800, 512, 0, stream>>>(xdh, xdl, flat, mf, dmb, norm);
    // layer 0 (fused, XCD-locality remapped 1-D grid)
    k_layer<0><<<3200, 512, 0, stream>>>(xnb, flat, wbth0, wbwh0, wbwt0, bt0,
                                         dmb, norm, mf, out0, nullptr, nullptr);
    // layer 1 (fused, scattered fp32 output)
    k_layer<1><<<3200, 512, 0, stream>>>(out0, nullptr, wbth1, wbwh1, wbwt1, bt1,
                                         dmb, norm, mf, nullptr, (float*)d_out, flat);
}